// Round 9
// baseline (1588.599 us; speedup 1.0000x reference)
//
#include <hip/hip_runtime.h>

#define Nn 4096
#define KK 20
#define BN 16384   // B*N, B=4

typedef __attribute__((ext_vector_type(8))) short bf16x8;
typedef __attribute__((ext_vector_type(4))) float f32x4;

__device__ __forceinline__ unsigned short f2bf(float f) {
  unsigned int x = __float_as_uint(f);
  return (unsigned short)((x + 0x7fffu + ((x >> 16) & 1u)) >> 16);
}
__device__ __forceinline__ float bf2f(unsigned short u) {
  return __uint_as_float(((unsigned int)u) << 16);
}

// 5-deep insert (val,idx) into descending list
#define INS5(dd, tt)                                                         \
  if (dd > m5) {                                                             \
    if (dd > m3) {                                                           \
      if (dd > m1) { m5=m4;t5=t4; m4=m3;t4=t3; m3=m2;t3=t2; m2=m1;t2=t1; m1=dd;t1=tt; } \
      else if (dd > m2) { m5=m4;t5=t4; m4=m3;t4=t3; m3=m2;t3=t2; m2=dd;t2=tt; } \
      else { m5=m4;t5=t4; m4=m3;t4=t3; m3=dd;t3=tt; }                        \
    } else if (dd > m4) { m5=m4;t5=t4; m4=dd;t4=tt; }                        \
    else { m5=dd; t5=tt; }                                                   \
  }

// ---------------- extract pts = x[:,:,:3] ---------------------------------
__global__ void k_pts(const float* __restrict__ x, float* __restrict__ pts) {
  int i = blockIdx.x * 256 + threadIdx.x;
  if (i < BN * 3) {
    int pt = i / 3, c = i - 3 * pt;
    pts[i] = x[pt * 6 + c];
  }
}

// ---------------- weight convert+transpose to bf16 ------------------------
__global__ void k_cvtT(const float* __restrict__ src, unsigned short* __restrict__ dst,
                       int N, int K, int ldn, int row0) {
  int i = blockIdx.x * 256 + threadIdx.x;
  if (i >= N * K) return;
  int n = i / K, k = i - n * K;
  dst[i] = f2bf(src[(size_t)(row0 + k) * ldn + n]);
}

// ---------------- transpose + 3-way bf16 split ----------------------------
__global__ void k_cvtT3(const float* __restrict__ src, unsigned short* __restrict__ h,
                        unsigned short* __restrict__ m, unsigned short* __restrict__ l,
                        int N, int K, int ldn) {
  int i = blockIdx.x * 256 + threadIdx.x;
  if (i >= N * K) return;
  int n = i / K, k = i - n * K;
  float x = src[(size_t)k * ldn + n];
  unsigned short hh = f2bf(x); float xh = bf2f(hh);
  unsigned short mm = f2bf(x - xh); float xm = bf2f(mm);
  unsigned short ll = f2bf(x - xh - xm);
  h[i] = hh; m[i] = mm; l[i] = ll;
}

// ---------------- maxreduce(32)+bias+relu -> 3-split, rows 4..15 zero -----
__global__ void k_tv3(const float* __restrict__ part, const float* __restrict__ bias,
                      unsigned short* __restrict__ h, unsigned short* __restrict__ m,
                      unsigned short* __restrict__ l) {
  int i = blockIdx.x * 256 + threadIdx.x;   // < 16*1024
  if (i >= 16 * 1024) return;
  int row = i >> 10, col = i & 1023;
  float v = 0.f;
  if (row < 4) {
    float mx = -INFINITY;
#pragma unroll 8
    for (int s = 0; s < 32; ++s) mx = fmaxf(mx, part[((size_t)row * 32 + s) * 1024 + col]);
    v = fmaxf(mx + bias[col], 0.f);
  }
  unsigned short hh = f2bf(v); float xh = bf2f(hh);
  unsigned short mm = f2bf(v - xh); float xm = bf2f(mm);
  unsigned short ll = f2bf(v - xh - xm);
  h[i] = hh; m[i] = mm; l[i] = ll;
}

// ---------------- zero-padded 3-split of [rows][cols] to [16][cols] -------
__global__ void k_pad3(const float* __restrict__ src, int rows, int cols,
                       unsigned short* __restrict__ h, unsigned short* __restrict__ m,
                       unsigned short* __restrict__ l) {
  int i = blockIdx.x * 256 + threadIdx.x;
  if (i >= 16 * cols) return;
  int row = i / cols, col = i - row * cols;
  float v = (row < rows) ? src[(size_t)row * cols + col] : 0.f;
  unsigned short hh = f2bf(v); float xh = bf2f(hh);
  unsigned short mm = f2bf(v - xh); float xm = bf2f(mm);
  unsigned short ll = f2bf(v - xh - xm);
  h[i] = hh; m[i] = mm; l[i] = ll;
}

// ---------------- split-K small MFMA GEMM: partial[seg][4][N] -------------
template <int N, int K, int SEG>
__global__ __launch_bounds__(256) void k_gemmSK(const unsigned short* __restrict__ Ah,
                                                const unsigned short* __restrict__ Am,
                                                const unsigned short* __restrict__ Al,
                                                const unsigned short* __restrict__ Bh,
                                                const unsigned short* __restrict__ Bm,
                                                const unsigned short* __restrict__ Bl,
                                                float* __restrict__ partial) {
  constexpr int KSEG = K / SEG;
  constexpr int KS = KSEG / 32;
  int t = threadIdx.x;
  int wv = t >> 6, lane = t & 63;
  int quad = lane >> 4, l16 = lane & 15;
  int bx = blockIdx.x;
  int nb = bx / SEG, seg = bx - nb * SEG;
  int col = nb * 64 + wv * 16 + l16;
  int k0 = seg * KSEG;
  size_t wo = (size_t)col * K + k0 + quad * 8;
  size_t ao = (size_t)l16 * K + k0 + quad * 8;
  f32x4 acc = {0.f, 0.f, 0.f, 0.f};
#pragma unroll
  for (int s = 0; s < KS; ++s) {
    bf16x8 xh = *(const bf16x8*)(Ah + ao + s * 32);
    bf16x8 xm = *(const bf16x8*)(Am + ao + s * 32);
    bf16x8 xl = *(const bf16x8*)(Al + ao + s * 32);
    bf16x8 wh = *(const bf16x8*)(Bh + wo + s * 32);
    bf16x8 wm = *(const bf16x8*)(Bm + wo + s * 32);
    bf16x8 wl = *(const bf16x8*)(Bl + wo + s * 32);
    acc = __builtin_amdgcn_mfma_f32_16x16x32_bf16(xh, wh, acc, 0, 0, 0);
    acc = __builtin_amdgcn_mfma_f32_16x16x32_bf16(xh, wm, acc, 0, 0, 0);
    acc = __builtin_amdgcn_mfma_f32_16x16x32_bf16(xm, wh, acc, 0, 0, 0);
    acc = __builtin_amdgcn_mfma_f32_16x16x32_bf16(xh, wl, acc, 0, 0, 0);
    acc = __builtin_amdgcn_mfma_f32_16x16x32_bf16(xl, wh, acc, 0, 0, 0);
    acc = __builtin_amdgcn_mfma_f32_16x16x32_bf16(xm, wm, acc, 0, 0, 0);
  }
  if (quad == 0) {
#pragma unroll
    for (int r = 0; r < 4; ++r)
      partial[((size_t)seg * 4 + r) * N + col] = acc[r];
  }
}

// ---------------- split-K reduce + bias + relu ----------------------------
__global__ void k_redS(const float* __restrict__ partial, const float* __restrict__ bias,
                       float* __restrict__ outp, int N, int SEG, int relu) {
  int i = blockIdx.x * 256 + threadIdx.x;
  if (i >= 4 * N) return;
  int r = i / N, c = i - r * N;
  float s = 0.f;
  for (int seg = 0; seg < SEG; ++seg) s += partial[((size_t)seg * 4 + r) * N + c];
  if (bias) s += bias[c];
  if (relu) s = fmaxf(s, 0.f);
  outp[(size_t)r * N + c] = s;
}

// ---------------- fc3 (256->9) + apply p = pts @ xf -----------------------
__global__ __launch_bounds__(256) void k_fc3p(const float* __restrict__ h2, const float* __restrict__ txw,
                                              const float* __restrict__ txb, const float* __restrict__ pts,
                                              float* __restrict__ p) {
  __shared__ float sh2[256];
  __shared__ float sxf[9];
  int t = threadIdx.x;
  int b = blockIdx.x;
  sh2[t] = h2[(size_t)b * 256 + t];
  __syncthreads();
  if (t < 9) {
    float acc = txb[t];
    for (int j = 0; j < 256; ++j) acc = fmaf(sh2[j], txw[j * 9 + t], acc);
    sxf[t] = acc;
  }
  __syncthreads();
  for (int n = t; n < Nn; n += 256) {
    const float* pr = pts + ((size_t)b * Nn + n) * 3;
    float a0 = pr[0], a1 = pr[1], a2 = pr[2];
    float* po = p + ((size_t)b * Nn + n) * 3;
#pragma unroll
    for (int d = 0; d < 3; ++d) po[d] = a0 * sxf[d] + a1 * sxf[3 + d] + a2 * sxf[6 + d];
  }
}

// ---------------- shared distance helper ----------------------------------
__device__ __forceinline__ float dist4(const float4* __restrict__ tile4, int c,
                                       float qx, float qy, float qz, float qsq) {
  float4 v = tile4[c];
  float dot = fmaf(qx, v.x, fmaf(qy, v.y, qz * v.z));
  return 2.0f * dot - qsq - v.w;
}

// ---------------- kNN, C=3: 1024 thr = 16 waves = 16 queries --------------
__global__ __launch_bounds__(1024) void k_knn3(const float* __restrict__ src, int* __restrict__ idx) {
  __shared__ float4 tile4[Nn];   // 64 KB
  int t = threadIdx.x;
  int wave = t >> 6, lane = t & 63;
  int g = blockIdx.x * 16 + wave;
  int b = g >> 12, n = g & (Nn - 1);
  const float* base = src + (size_t)b * Nn * 3;
  for (int e = t; e < Nn; e += 1024) {
    float x = base[e * 3], y = base[e * 3 + 1], z = base[e * 3 + 2];
    tile4[e] = make_float4(x, y, z, fmaf(x, x, fmaf(y, y, z * z)));
  }
  __syncthreads();
  float4 q4 = tile4[n];
  float qx = q4.x, qy = q4.y, qz = q4.z, qsq = q4.w;
  float m1 = -INFINITY, m2 = -INFINITY, m3 = -INFINITY, m4 = -INFINITY, m5 = -INFINITY;
  int t1 = 0, t2 = 0, t3 = 0, t4 = 0, t5 = 0;
#pragma unroll 4
  for (int tt = 0; tt < 64; ++tt) {
    float dd = dist4(tile4, (tt << 6) + lane, qx, qy, qz, qsq);
    INS5(dd, tt)
  }
  unsigned long long removed = 0ull;
  int cnt = 5;
  int sel = 0;
#pragma unroll 1
  for (int k = 0; k < 20; ++k) {
    float v = m1; int ci = (t1 << 6) | lane;
    float mx = v;
#pragma unroll
    for (int off = 32; off; off >>= 1) mx = fmaxf(mx, __shfl_xor(mx, off, 64));
    int cand = (v == mx) ? ci : 0x7FFFFFFF;
#pragma unroll
    for (int off = 32; off; off >>= 1) cand = min(cand, __shfl_xor(cand, off, 64));
    if (k == lane) sel = cand;
    if (cand == ci) {
      removed |= 1ull << t1;
      if (cnt > 1) { m1 = m2; t1 = t2; m2 = m3; t2 = t3; m3 = m4; t3 = t4; m4 = m5; t4 = t5; --cnt; }
      else {
        m1 = -INFINITY; m2 = -INFINITY; m3 = -INFINITY; m4 = -INFINITY; m5 = -INFINITY;
        t1 = 0; t2 = 0; t3 = 0; t4 = 0; t5 = 0;
#pragma unroll 1
        for (int tt = 0; tt < 64; ++tt) {
          if ((removed >> tt) & 1ull) continue;
          float dd = dist4(tile4, (tt << 6) + lane, qx, qy, qz, qsq);
          INS5(dd, tt)
        }
        cnt = 5;
      }
    }
  }
  if (lane < 20) idx[(size_t)g * KK + lane] = sel;
}

// ---------------- sq norms ------------------------------------------------
__global__ void k_sqnorm(const float* __restrict__ src, float* __restrict__ out) {
  int g = blockIdx.x * 256 + threadIdx.x;
  if (g >= BN) return;
  const float4* r = (const float4*)(src + (size_t)g * 64);
  float s = 0.f;
#pragma unroll
  for (int j = 0; j < 16; ++j) { float4 v = r[j]; s += v.x * v.x + v.y * v.y + v.z * v.z + v.w * v.w; }
  out[g] = s;
}

// ---------------- pass 1: distance quarter + per-quarter top-20 -----------
// Block = 8 waves (512 thr) owns 8 query rows x 1024-col quarter.
// LDS 8x1028 f32 = 32.9 KB -> 4 blocks/CU = 32 waves/CU (FULL occupancy;
// R8's 82KB/1-block design ran 4 waves/SIMD and was 85% stall: MfmaUtil 7%,
// VALUBusy 30%, HBM 1%). One barrier instead of 8. MFMA A rows 8..15 are
// duplicates of 0..7 (outputs discarded; quad<2 stores only) - MFMA was at
// 7% util so the 2x waste is free. Distances bit-identical to k_dsel:
// same MFMA ops/order, same epilogue. d[16]/lane, rescan fully unrolled
// (rule #20: compile-time subscripts -> registers). Live set ~50 VGPR fits
// the 8-wave/SIMD 64-reg budget with no allocator fight.
// sD stride 1028%32=4: rows r,r+4 are 16 banks apart -> 32 active store
// lanes cover 32 distinct banks (conflict-free, extends R3 verification).
__global__ __launch_bounds__(512) void k_dq(const unsigned short* __restrict__ Xh,
                                            const unsigned short* __restrict__ Xm,
                                            const unsigned short* __restrict__ Xl,
                                            const float* __restrict__ sq,
                                            float* __restrict__ cval,
                                            int* __restrict__ cidx) {
  __shared__ float sD[8 * 1028];   // 32896 B
  int t = threadIdx.x;
  int wave = t >> 6, lane = t & 63;
  int quad = lane >> 4, l16 = lane & 15;
  int blk = blockIdx.x;            // 8192 = 4b * 512 strips * 4 quarters
  int b = blk >> 11, rs = (blk >> 2) & 511, qtr = blk & 3;
  int r0 = rs * 8, q0 = qtr * 1024;
  const size_t base = (size_t)b * Nn * 64;
  const float* sqb = sq + b * Nn;
  bf16x8 ah[2], am[2], al[2];
#pragma unroll
  for (int ks = 0; ks < 2; ++ks) {
    size_t ra = base + (size_t)(r0 + (l16 & 7)) * 64 + ks * 32 + quad * 8;
    ah[ks] = *(const bf16x8*)(Xh + ra);
    am[ks] = *(const bf16x8*)(Xm + ra);
    al[ks] = *(const bf16x8*)(Xl + ra);
  }
  float sqr[4];
#pragma unroll
  for (int r = 0; r < 4; ++r) sqr[r] = sqb[r0 + ((quad * 4 + r) & 7)];
#pragma unroll
  for (int tt = 0; tt < 8; ++tt) {
    int cc = wave * 128 + tt * 16;       // col within quarter
    int cb = q0 + cc;                    // global col
    f32x4 acc = {0.f, 0.f, 0.f, 0.f};
#pragma unroll
    for (int ks = 0; ks < 2; ++ks) {
      size_t rb = base + (size_t)(cb + l16) * 64 + ks * 32 + quad * 8;
      bf16x8 bh = *(const bf16x8*)(Xh + rb);
      bf16x8 bm = *(const bf16x8*)(Xm + rb);
      bf16x8 bl = *(const bf16x8*)(Xl + rb);
      acc = __builtin_amdgcn_mfma_f32_16x16x32_bf16(ah[ks], bh, acc, 0, 0, 0);
      acc = __builtin_amdgcn_mfma_f32_16x16x32_bf16(ah[ks], bm, acc, 0, 0, 0);
      acc = __builtin_amdgcn_mfma_f32_16x16x32_bf16(am[ks], bh, acc, 0, 0, 0);
      acc = __builtin_amdgcn_mfma_f32_16x16x32_bf16(ah[ks], bl, acc, 0, 0, 0);
      acc = __builtin_amdgcn_mfma_f32_16x16x32_bf16(al[ks], bh, acc, 0, 0, 0);
      acc = __builtin_amdgcn_mfma_f32_16x16x32_bf16(am[ks], bm, acc, 0, 0, 0);
    }
    float sqc = sqb[cb + l16];
    if (quad < 2) {
#pragma unroll
      for (int r = 0; r < 4; ++r)
        sD[(quad * 4 + r) * 1028 + cc + l16] = 2.0f * acc[r] - sqr[r] - sqc;
    }
  }
  __syncthreads();
  float d[16];
  float m1 = -INFINITY, m2 = -INFINITY, m3 = -INFINITY, m4 = -INFINITY, m5 = -INFINITY;
  int t1 = 0, t2 = 0, t3 = 0, t4 = 0, t5 = 0;
#pragma unroll
  for (int jj = 0; jj < 16; ++jj) {
    float dd = sD[wave * 1028 + jj * 64 + lane];
    d[jj] = dd;
    INS5(dd, jj)
  }
  unsigned removed = 0;
  int cnt = 5;
  float selv = 0.f; int seli = 0;
#pragma unroll 1
  for (int k = 0; k < 20; ++k) {
    float v = m1; int ci = (t1 << 6) | lane;     // local col in [0,1024)
    float mx = v;
#pragma unroll
    for (int off = 32; off; off >>= 1) mx = fmaxf(mx, __shfl_xor(mx, off, 64));
    int cand = (v == mx) ? ci : 0x7FFFFFFF;
#pragma unroll
    for (int off = 32; off; off >>= 1) cand = min(cand, __shfl_xor(cand, off, 64));
    if (k == lane) { selv = mx; seli = cand; }
    if (cand == ci) {
      removed |= 1u << t1;
      if (cnt > 1) { m1 = m2; t1 = t2; m2 = m3; t2 = t3; m3 = m4; t3 = t4; m4 = m5; t4 = t5; --cnt; }
      else {
        m1 = -INFINITY; m2 = -INFINITY; m3 = -INFINITY; m4 = -INFINITY; m5 = -INFINITY;
        t1 = 0; t2 = 0; t3 = 0; t4 = 0; t5 = 0;
#pragma unroll
        for (int tt = 0; tt < 16; ++tt) {
          if (!((removed >> tt) & 1u)) {
            float dd = d[tt];
            INS5(dd, tt)
          }
        }
        cnt = 5;
      }
    }
  }
  if (lane < 20) {
    size_t o = ((size_t)(b * Nn + r0 + wave) * 4 + qtr) * 20 + lane;
    cval[o] = selv;
    cidx[o] = q0 + seli;
  }
}

// ---------------- pass 2: merge 4x20 quarter candidates -> top-20 ---------
// One wave per row; 80 candidates = 2/lane (lane<16 holds 2, rest 1+pad).
// Global top-20 is a subset of the union of quarter-top-20s under the same
// (val desc, idx asc) order -> exact, bit-identical idx output. No rescan
// needed: each lane pops at most its 2 candidates.
__global__ __launch_bounds__(256) void k_dmerge(const float* __restrict__ cval,
                                                const int* __restrict__ cidx,
                                                int* __restrict__ idx) {
  int t = threadIdx.x;
  int wave = t >> 6, lane = t & 63;
  int row = blockIdx.x * 4 + wave;    // global row id (b*Nn + n)
  size_t o = (size_t)row * 80;
  float v0 = cval[o + lane];
  int i0 = cidx[o + lane];
  float v1 = -INFINITY; int i1 = 0x7FFFFFFF;
  if (lane < 16) { v1 = cval[o + 64 + lane]; i1 = cidx[o + 64 + lane]; }
  if (v1 > v0 || (v1 == v0 && i1 < i0)) {
    float tv = v0; v0 = v1; v1 = tv;
    int ti = i0; i0 = i1; i1 = ti;
  }
  int sel = 0;
#pragma unroll 1
  for (int k = 0; k < 20; ++k) {
    float mx = v0;
#pragma unroll
    for (int off = 32; off; off >>= 1) mx = fmaxf(mx, __shfl_xor(mx, off, 64));
    int cand = (v0 == mx) ? i0 : 0x7FFFFFFF;
#pragma unroll
    for (int off = 32; off; off >>= 1) cand = min(cand, __shfl_xor(cand, off, 64));
    if (k == lane) sel = cand;
    if (cand == i0) { v0 = v1; i0 = i1; v1 = -INFINITY; i1 = 0x7FFFFFFF; }
  }
  if (lane < 20) idx[(size_t)row * KK + lane] = sel;
}

// ---------------- u/v from pts (6->64 conv1 factorized) -------------------
__global__ __launch_bounds__(256) void k_uv3(const float* __restrict__ pts, const float* __restrict__ w1,
                                             const float* __restrict__ b1, float* __restrict__ uvb) {
  __shared__ float sw[384];
  __shared__ float sb[64];
  int t = threadIdx.x;
  for (int e = t; e < 384; e += 256) sw[e] = w1[e];
  if (t < 64) sb[t] = b1[t];
  __syncthreads();
  int pl = t >> 6, c = t & 63;
  int p = blockIdx.x * 4 + pl;
  const float* pr = pts + (size_t)p * 3;
  float x0 = pr[0], x1 = pr[1], x2 = pr[2];
  float wb0 = sw[192 + c], wb1 = sw[256 + c], wb2 = sw[320 + c];
  float v = x0 * wb0 + x1 * wb1 + x2 * wb2;
  float u = sb[c] + x0 * (sw[c] - wb0) + x1 * (sw[64 + c] - wb1) + x2 * (sw[128 + c] - wb2);
  uvb[(size_t)p * 128 + c] = u;
  uvb[(size_t)p * 128 + 64 + c] = v;
}

// ---------------- prep: Md[64][128] = [Wa-Wb | Wb] from 128x64 w1 ---------
__global__ void k_prepD(const float* __restrict__ w1, float* __restrict__ Md) {
  int i = blockIdx.x * 256 + threadIdx.x;
  if (i >= 8192) return;
  int j = i >> 7, c = i & 127;
  Md[i] = (c < 64) ? (w1[j * 64 + c] - w1[(64 + j) * 64 + c]) : w1[(64 + j) * 64 + (c - 64)];
}

// ---------------- uv = x @ Md (+bias on u half), 32 rows/block ------------
__global__ __launch_bounds__(256) void k_uv(const float* __restrict__ x2, const float* __restrict__ Md,
                                            const float* __restrict__ bias, float* __restrict__ uv) {
  __shared__ float sM[8192];     // 64x128
  __shared__ float sx[32 * 68];
  int t = threadIdx.x;
  for (int e = t; e < 8192; e += 256) sM[e] = Md[e];
  int p0 = blockIdx.x * 32;
  for (int e = t; e < 512; e += 256) {
    int r = e >> 4, c4 = e & 15;
    *(float4*)(sx + r * 68 + c4 * 4) = *(const float4*)(x2 + (size_t)(p0 + r) * 64 + c4 * 4);
  }
  __syncthreads();
  int c = t & 127, rg = t >> 7;
  float badd = (c < 64) ? bias[c] : 0.f;
  float accv[16];
#pragma unroll
  for (int r = 0; r < 16; ++r) accv[r] = 0.f;
#pragma unroll
  for (int jc = 0; jc < 8; ++jc) {
    float mreg[8];
#pragma unroll
    for (int q = 0; q < 8; ++q) mreg[q] = sM[(jc * 8 + q) * 128 + c];
#pragma unroll
    for (int r = 0; r < 16; ++r) {
      const float* xr = sx + (rg * 16 + r) * 68 + jc * 8;
      float4 a = *(const float4*)xr, bb = *(const float4*)(xr + 4);
      float s = accv[r];
      s = fmaf(a.x, mreg[0], s); s = fmaf(a.y, mreg[1], s);
      s = fmaf(a.z, mreg[2], s); s = fmaf(a.w, mreg[3], s);
      s = fmaf(bb.x, mreg[4], s); s = fmaf(bb.y, mreg[5], s);
      s = fmaf(bb.z, mreg[6], s); s = fmaf(bb.w, mreg[7], s);
      accv[r] = s;
    }
  }
#pragma unroll
  for (int r = 0; r < 16; ++r)
    uv[(size_t)(p0 + rg * 16 + r) * 128 + c] = accv[r] + badd;
}

// ---------------- per-edge conv2: column-owning waves, weights in regs ----
template <int NOUT, bool WRITEF, bool SPLIT3, bool CAT>
__global__ __launch_bounds__(256, 4) void k_econv(const float* __restrict__ uv,
                                                  const int* __restrict__ idx,
                                                  const unsigned short* __restrict__ W2h,
                                                  const unsigned short* __restrict__ W2m,
                                                  const unsigned short* __restrict__ W2l,
                                                  const float* __restrict__ b2,
                                                  float* __restrict__ outF,
                                                  unsigned short* __restrict__ oh,
                                                  unsigned short* __restrict__ om,
                                                  unsigned short* __restrict__ ol,
                                                  unsigned short* __restrict__ ocat,
                                                  int catoff) {
  __shared__ unsigned short y3[4][3][20 * 72];        // 34560 B
  int t = threadIdx.x;
  int wv = t >> 6, lane = t & 63;
  int quad = lane >> 4, l16 = lane & 15;
  int p0 = blockIdx.x * 4;
  int p = p0 + wv;
  size_t nbase = (size_t)(p >> 12) * Nn;
  constexpr int CT = NOUT / 64;   // col-tiles owned per wave
  bf16x8 wfh[CT][2], wfm[CT][2], wfl[CT][2];
#pragma unroll
  for (int ct = 0; ct < CT; ++ct)
#pragma unroll
    for (int ks = 0; ks < 2; ++ks) {
      size_t wo = (size_t)(wv * (CT * 16) + ct * 16 + l16) * 64 + ks * 32 + quad * 8;
      wfh[ct][ks] = *(const bf16x8*)(W2h + wo);
      wfm[ct][ks] = *(const bf16x8*)(W2m + wo);
      wfl[ct][ks] = *(const bf16x8*)(W2l + wo);
    }
  const int* ip = idx + (size_t)p * KK;
  float u = uv[(size_t)p * 128 + lane];
  unsigned short* yh = y3[wv][0];
  unsigned short* ym = y3[wv][1];
  unsigned short* yl = y3[wv][2];
  float vv[20];
#pragma unroll
  for (int k = 0; k < 20; ++k) {
    int nb = ip[k];
    vv[k] = uv[(nbase + nb) * 128 + 64 + lane];
  }
#pragma unroll
  for (int k = 0; k < 20; ++k) {
    float y = fmaxf(u + vv[k], 0.f);
    unsigned short hh = f2bf(y); float fh = bf2f(hh);
    unsigned short mm = f2bf(y - fh); float fm = bf2f(mm);
    unsigned short ll = f2bf(y - fh - fm);
    yh[k * 72 + lane] = hh;
    ym[k * 72 + lane] = mm;
    yl[k * 72 + lane] = ll;
  }
  __syncthreads();
#pragma unroll 1
  for (int pp = 0; pp < 4; ++pp) {
    const unsigned short* ph0 = y3[pp][0];
    const unsigned short* pm0 = y3[pp][1];
    const unsigned short* pl0 = y3[pp][2];
    f32x4 acc[CT][2];
#pragma unroll
    for (int ct = 0; ct < CT; ++ct) {
      acc[ct][0] = (f32x4){0.f, 0.f, 0.f, 0.f};
      acc[ct][1] = (f32x4){0.f, 0.f, 0.f, 0.f};
    }
#pragma unroll
    for (int ks = 0; ks < 2; ++ks) {
      bf16x8 ah[2], am[2], al[2];
#pragma unroll
      for (int mt = 0; mt < 2; ++mt) {
        int row = mt * 16 + l16;
        int rr = (row < 20) ? row : 0;     // clamped; lands in dead regs
        int aoff = rr * 72 + ks * 32 + quad * 8;
        ah[mt] = *(const bf16x8*)(ph0 + aoff);
        am[mt] = *(const bf16x8*)(pm0 + aoff);
        al[mt] = *(const bf16x8*)(pl0 + aoff);
      }
#pragma unroll
      for (int ct = 0; ct < CT; ++ct)
#pragma unroll
        for (int mt = 0; mt < 2; ++mt) {
          f32x4 a = acc[ct][mt];
          a = __builtin_amdgcn_mfma_f32_16x16x32_bf16(ah[mt], wfh[ct][ks], a, 0, 0, 0);
          a = __builtin_amdgcn_mfma_f32_16x16x32_bf16(ah[mt], wfm[ct][ks], a, 0, 0, 0);
          a = __builtin_amdgcn_mfma_f32_16x16x32_bf16(am[mt], wfh[ct][ks], a, 0, 0, 0);
          a = __builtin_amdgcn_mfma_f32_16x16x32_bf16(ah[mt], wfl[ct][ks], a, 0, 0, 0);
          a = __builtin_amdgcn_mfma_f32_16x16x32_bf16(al[mt], wfh[ct][ks], a, 0, 0, 0);
          a = __builtin_amdgcn_mfma_f32_16x16x32_bf16(am[mt], wfm[ct][ks], a, 0, 0, 0);
          acc[ct][mt] = a;
        }
    }
    int pt = p0 + pp;
#pragma unroll
    for (int ct = 0; ct < CT; ++ct) {
      int col = wv * (CT * 16) + ct * 16 + l16;
      float m0 = fmaxf(fmaxf(acc[ct][0][0], acc[ct][0][1]), fmaxf(acc[ct][0][2], acc[ct][0][3]));
      float m1v = (quad == 0)
                      ? fmaxf(fmaxf(acc[ct][1][0], acc[ct][1][1]), fmaxf(acc[ct][1][2], acc[ct][1][3]))
                      : -INFINITY;
      float m = fmaxf(m0, m1v);
      m = fmaxf(m, __shfl_xor(m, 16, 64));
      m = fmaxf(m, __shfl_xor(m, 32, 64));
      if (quad == 0) {
        float v = fmaxf(m + b2[col], 0.f);
        if (WRITEF) outF[(size_t)pt * NOUT + col] = v;
        if (SPLIT3) {
          unsigned short hh = f2bf(v); float fh = bf2f(hh);
          unsigned short mm2 = f2bf(v - fh); float fm = bf2f(mm2);
          unsigned short ll = f2bf(v - fh - fm);
          oh[(size_t)pt * NOUT + col] = hh;
          om[(size_t)pt * NOUT + col] = mm2;
          ol[(size_t)pt * NOUT + col] = ll;
        }
        if (CAT) ocat[(size_t)pt * 192 + catoff + col] = f2bf(v);
      }
    }
  }
}

// ---------------- x3 = relu(u + max_k v_nk) -> xcat cols 128..191 ---------
__global__ __launch_bounds__(256) void k_gmax(const float* __restrict__ uv, const int* __restrict__ idx,
                                              unsigned short* __restrict__ ocat) {
  __shared__ int sidx[4][20];
  int t = threadIdx.x;
  int pl = t >> 6, c = t & 63;
  int p0 = blockIdx.x * 4;
  if (t < 80) sidx[t / 20][t % 20] = idx[(size_t)(p0 + t / 20) * KK + (t % 20)];
  __syncthreads();
  int p = p0 + pl;
  size_t nbase = (size_t)(p >> 12) * Nn;
  float u = uv[(size_t)p * 128 + c];
  float m = -INFINITY;
#pragma unroll
  for (int k = 0; k < 20; ++k) m = fmaxf(m, uv[(nbase + sidx[pl][k]) * 128 + 64 + c]);
  ocat[(size_t)p * 192 + 128 + c] = f2bf(fmaxf(u + m, 0.f));
}

// ---------------- MFMA max-GEMM (bf16, post-kNN path), 32 row-segments ----
template <int K>
__global__ __launch_bounds__(256) void k_mgemm(const unsigned short* __restrict__ A,
                                               const unsigned short* __restrict__ WT,
                                               float* __restrict__ outp) {
  constexpr int KS = K / 32;
  int t = threadIdx.x;
  int wv = t >> 6, lane = t & 63;
  int quad = lane >> 4, l16 = lane & 15;
  int blk = blockIdx.x;                    // 4 * 16 * 32 = 2048 blocks
  int b = blk >> 9, cb = (blk >> 5) & 15, ns = blk & 31;
  int n0 = cb * 64 + wv * 16;
  bf16x8 bfr[KS];
  const unsigned short* wrow = WT + (size_t)(n0 + l16) * K + quad * 8;
#pragma unroll
  for (int s = 0; s < KS; ++s) bfr[s] = *(const bf16x8*)(wrow + s * 32);
  const unsigned short* Ab = A + ((size_t)b * Nn + ns * 128 + l16) * K + quad * 8;
  float rmax = -INFINITY;
#pragma unroll 2
  for (int mt = 0; mt < 8; ++mt) {
    const unsigned short* ar = Ab + (size_t)mt * 16 * K;
    f32x4 acc = {0.f, 0.f, 0.f, 0.f};
#pragma unroll
    for (int s = 0; s < KS; ++s) {
      bf16x8 af = *(const bf16x8*)(ar + s * 32);
      acc = __builtin_amdgcn_mfma_f32_16x16x32_bf16(af, bfr[s], acc, 0, 0, 0);
    }
    rmax = fmaxf(rmax, fmaxf(fmaxf(acc[0], acc[1]), fmaxf(acc[2], acc[3])));
  }
  rmax = fmaxf(rmax, __shfl_xor(rmax, 16, 64));
  rmax = fmaxf(rmax, __shfl_xor(rmax, 32, 64));
  if (quad == 0) outp[((size_t)b * 32 + ns) * 1024 + n0 + l16] = rmax;
}

// ---------------- MFMA max-GEMM, 3-split exact, 32 row-segments -----------
template <int K>
__global__ __launch_bounds__(256) void k_mgemm3s(const unsigned short* __restrict__ Ah,
                                                 const unsigned short* __restrict__ Am,
                                                 const unsigned short* __restrict__ Al,
                                                 const unsigned short* __restrict__ Bh,
                                                 const unsigned short* __restrict__ Bm,
                                                 const unsigned short* __restrict__ Bl,
                                                 float* __restrict__ outp) {
  constexpr int KS = K / 32;
  int t = threadIdx.x;
  int wv = t >> 6, lane = t & 63;
  int quad = lane >> 4, l16 = lane & 15;
  int blk = blockIdx.x;                    // 2048 blocks
  int b = blk >> 9, cb = (blk >> 5) & 15, ns = blk & 31;
  int n0 = cb * 64 + wv * 16;
  bf16x8 wh[KS], wm[KS], wl[KS];
  size_t wo = (size_t)(n0 + l16) * K + quad * 8;
#pragma unroll
  for (int s = 0; s < KS; ++s) {
    wh[s] = *(const bf16x8*)(Bh + wo + s * 32);
    wm[s] = *(const bf16x8*)(Bm + wo + s * 32);
    wl[s] = *(const bf16x8*)(Bl + wo + s * 32);
  }
  size_t ao = ((size_t)b * Nn + ns * 128 + l16) * K + quad * 8;
  float rmax = -INFINITY;
#pragma unroll 1
  for (int mt = 0; mt < 8; ++mt) {
    size_t ar = ao + (size_t)mt * 16 * K;
    f32x4 acc = {0.f, 0.f, 0.f, 0.f};
#pragma unroll
    for (int s = 0; s < KS; ++s) {
      bf16x8 xh = *(const bf16x8*)(Ah + ar + s * 32);
      bf16x8 xm = *(const bf16x8*)(Am + ar + s * 32);
      bf16x8 xl = *(const bf16x8*)(Al + ar + s * 32);
      acc = __builtin_amdgcn_mfma_f32_16x16x32_bf16(xh, wh[s], acc, 0, 0, 0);
      acc = __builtin_amdgcn_mfma_f32_16x16x32_bf16(xh, wm[s], acc, 0, 0, 0);
      acc = __builtin_amdgcn_mfma_f32_16x16x32_bf16(xm, wh[s], acc, 0, 0, 0);
      acc = __builtin_amdgcn_mfma_f32_16x16x32_bf16(xh, wl[s], acc, 0, 0, 0);
      acc = __builtin_amdgcn_mfma_f32_16x16x32_bf16(xl, wh[s], acc, 0, 0, 0);
      acc = __builtin_amdgcn_mfma_f32_16x16x32_bf16(xm, wm[s], acc, 0, 0, 0);
    }
    rmax = fmaxf(rmax, fmaxf(fmaxf(acc[0], acc[1]), fmaxf(acc[2], acc[3])));
  }
  rmax = fmaxf(rmax, __shfl_xor(rmax, 16, 64));
  rmax = fmaxf(rmax, __shfl_xor(rmax, 32, 64));
  if (quad == 0) outp[((size_t)b * 32 + ns) * 1024 + n0 + l16] = rmax;
}

// ---------------- fused MFMA head: 192->512->256->2 per 16 points ---------
__global__ __launch_bounds__(256) void k_final(const unsigned short* __restrict__ xcat,
                                               const float* __restrict__ gc,
                                               const float* __restrict__ c2b,
                                               const unsigned short* __restrict__ c2wT,
                                               const unsigned short* __restrict__ c3wT,
                                               const float* __restrict__ c3b,
                                               const float* __restrict__ c4w, const float* __restrict__ c4b,
                                               float* __restrict__ out) {
  __shared__ unsigned short z5[16 * 520];
  __shared__ float z2[16 * 260];
  int t = threadIdx.x;
  int wv = t >> 6, lane = t & 63;
  int quad = lane >> 4, l16 = lane & 15;
  int p0 = blockIdx.x * 16;
  int b = p0 >> 12;
  bf16x8 a1[6];
  const unsigned short* ar = xcat + (size_t)(p0 + l16) * 192 + quad * 8;
#pragma unroll
  for (int s = 0; s < 6; ++s) a1[s] = *(const bf16x8*)(ar + s * 32);
#pragma unroll 1
  for (int ntw = 0; ntw < 8; ++ntw) {
    int col = wv * 128 + ntw * 16 + l16;
    float bias = gc[(size_t)b * 512 + col] + c2b[col];
    f32x4 acc = {bias, bias, bias, bias};
    const unsigned short* wr = c2wT + (size_t)col * 192 + quad * 8;
#pragma unroll
    for (int s = 0; s < 6; ++s) {
      bf16x8 bfr = *(const bf16x8*)(wr + s * 32);
      acc = __builtin_amdgcn_mfma_f32_16x16x32_bf16(a1[s], bfr, acc, 0, 0, 0);
    }
#pragma unroll
    for (int r = 0; r < 4; ++r)
      z5[(quad * 4 + r) * 520 + col] = f2bf(fmaxf(acc[r], 0.f));
  }
  __syncthreads();
  bf16x8 a2[16];
#pragma unroll
  for (int s = 0; s < 16; ++s) a2[s] = *(const bf16x8*)(z5 + l16 * 520 + s * 32 + quad * 8);
#pragma unroll 1
  for (int ntw = 0; ntw < 4; ++ntw) {
    int col = wv * 64 + ntw * 16 + l16;
    float bias = c3b[col];
    f32x4 acc = {bias, bias, bias, bias};
    const unsigned short* wr = c3wT + (size_t)col * 512 + quad * 8;
#pragma unroll
    for (int s = 0; s < 16; ++s) {
      bf16x8 bfr = *(const bf16x8*)(wr + s * 32);
      acc = __builtin_amdgcn_mfma_f32_16x16x32_bf16(a2[s], bfr, acc, 0, 0, 0);
    }
#pragma unroll
    for (int r = 0; r < 4; ++r)
      z2[(quad * 4 + r) * 260 + col] = fmaxf(acc[r], 0.f);
  }
  __syncthreads();
  if (t < 32) {
    int m = t >> 1, e = t & 1;
    float acc = c4b[e];
    const float* zr = z2 + m * 260;
    for (int j = 0; j < 256; ++j) acc = fmaf(zr[j], c4w[j * 2 + e], acc);
    out[(size_t)(p0 + m) * 2 + e] = acc;
  }
}

// ===========================================================================
extern "C" void kernel_launch(void* const* d_in, const int* in_sizes, int n_in,
                              void* d_out, int out_size, void* d_ws, size_t ws_size,
                              hipStream_t stream) {
  const float* xin = (const float*)d_in[0];
  const float* W[30];
  for (int i = 0; i < 30; ++i) W[i] = (const float*)d_in[i + 1];

  float* ws = (float*)d_ws;
  size_t off = 0;
  float* pts   = ws + off; off += (size_t)BN * 3;
  float* p     = ws + off; off += (size_t)BN * 3;
  int*   idx   = (int*)(ws + off); off += (size_t)BN * KK;
  float* sq    = ws + off; off += BN;
  float* dpart = ws + off; off += 4 * 32 * 1024;
  float* h1    = ws + off; off += 4 * 512;
  float* h2b   = ws + off; off += 4 * 256;
  float* x1    = ws + off; off += (size_t)BN * 64;
  float* x2    = ws + off; off += (size_t)BN * 64;
  float* gpart = ws + off; off += 4 * 32 * 1024;
  float* gc    = ws + off; off += 4 * 512;
  float* uvb   = ws + off; off += (size_t)BN * 128;
  float* partial = ws + off; off += 16 * 4 * 512;
  unsigned short* xcat = (unsigned short*)(ws + off); off += (size_t)BN * 96;
  unsigned short* c1wT = (unsigned short*)(ws + off); off += 98304;
  unsigned short* c2wT = (unsigned short*)(ws + off); off += 49152;
  unsigned short* c3wT = (unsigned short*)(ws + off); off += 65536;
  unsigned short* w3Th = (unsigned short*)(ws + off); off += 65536;
  unsigned short* w3Tm = (unsigned short*)(ws + off); off += 65536;
  unsigned short* w3Tl = (unsigned short*)(ws + off); off += 65536;
  unsigned short* tw2h = (unsigned short*)(ws + off); off += 4096;
  unsigned short* tw2m = (unsigned short*)(ws + off); off += 4096;
  unsigned short* tw2l = (unsigned short*)(ws + off); off += 4096;
  unsigned short* e1h  = (unsigned short*)(ws + off); off += 2048;
  unsigned short* e1m  = (unsigned short*)(ws + off); off += 2048;
  unsigned short* e1l  = (unsigned short*)(ws + off); off += 2048;
  unsigned short* e2h  = (unsigned short*)(ws + off); off += 2048;
  unsigned short* e2m  = (unsigned short*)(ws + off); off += 2048;
  unsigned short* e2l  = (unsigned short*)(ws + off); off += 2048;
  unsigned short* xsh  = (unsigned short*)(ws + off); off += 524288;
  unsigned short* xsm  = (unsigned short*)(ws + off); off += 524288;
  unsigned short* xsl  = (unsigned short*)(ws + off); off += 524288;
  float* MdC   = ws + off; off += 8192;
  float* MdD   = ws + off; off += 8192;
  unsigned short* fw1h = (unsigned short*)(ws + off); off += 262144;  // 512x1024 bf16
  unsigned short* fw1m = (unsigned short*)(ws + off); off += 262144;
  unsigned short* fw1l = (unsigned short*)(ws + off); off += 262144;
  unsigned short* cw2h = (unsigned short*)(ws + off); off += 262144;  // 512x1024 (c2w[:1024])
  unsigned short* cw2m = (unsigned short*)(ws + off); off += 262144;
  unsigned short* cw2l = (unsigned short*)(ws + off); off += 262144;
  unsigned short* fw2h = (unsigned short*)(ws + off); off += 65536;   // 256x512 bf16
  unsigned short* fw2m = (unsigned short*)(ws + off); off += 65536;
  unsigned short* fw2l = (unsigned short*)(ws + off); off += 65536;
  unsigned short* tvh  = (unsigned short*)(ws + off); off += 8192;    // 16x1024 bf16
  unsigned short* tvm  = (unsigned short*)(ws + off); off += 8192;
  unsigned short* tvl  = (unsigned short*)(ws + off); off += 8192;
  unsigned short* h13h = (unsigned short*)(ws + off); off += 4096;    // 16x512 bf16
  unsigned short* h13m = (unsigned short*)(ws + off); off += 4096;
  unsigned short* h13l = (unsigned short*)(ws + off); off += 4096;
  float* Dbuf  = ws + off; off += (size_t)Nn * Nn;   // aliased below
  unsigned short* t3h = (unsigned short*)Dbuf;       // stage-1 only
  unsigned short* t3m = t3h + (size_t)BN * 128;
  unsigned short* t3l = t3m + (size_t)BN * 128;
  float* cval  = Dbuf;                               // stage-2: 16384*80 f32
  int*   cidxb = (int*)(Dbuf + (size_t)BN * 80);     // 16384*80 int

  // weight prep
  k_cvtT<<<dim3(768), dim3(256), 0, stream>>>(W[22], c1wT, 1024, 192, 1024, 0);
  k_cvtT<<<dim3(384), dim3(256), 0, stream>>>(W[24], c2wT, 512, 192, 512, 1024);
  k_cvtT<<<dim3(512), dim3(256), 0, stream>>>(W[26], c3wT, 256, 512, 256, 0);
  k_cvtT3<<<dim3(512), dim3(256), 0, stream>>>(W[4], w3Th, w3Tm, w3Tl, 1024, 128, 1024);
  k_cvtT3<<<dim3(32), dim3(256), 0, stream>>>(W[2], tw2h, tw2m, tw2l, 128, 64, 128);
  k_cvtT3<<<dim3(16), dim3(256), 0, stream>>>(W[14], e1h, e1m, e1l, 64, 64, 64);
  k_cvtT3<<<dim3(16), dim3(256), 0, stream>>>(W[18], e2h, e2m, e2l, 64, 64, 64);
  k_cvtT3<<<dim3(2048), dim3(256), 0, stream>>>(W[6], fw1h, fw1m, fw1l, 512, 1024, 512);
  k_cvtT3<<<dim3(2048), dim3(256), 0, stream>>>(W[24], cw2h, cw2m, cw2l, 512, 1024, 512);
  k_cvtT3<<<dim3(512), dim3(256), 0, stream>>>(W[8], fw2h, fw2m, fw2l, 256, 512, 256);
  k_prepD<<<dim3(32), dim3(256), 0, stream>>>(W[16], MdC);
  k_prepD<<<dim3(32), dim3(256), 0, stream>>>(W[20], MdD);

  k_pts<<<dim3(192), dim3(256), 0, stream>>>(xin, pts);

  // stage 1: transform branch
  k_knn3<<<dim3(1024), dim3(1024), 0, stream>>>(pts, idx);
  k_uv3<<<dim3(4096), dim3(256), 0, stream>>>(pts, W[0], W[1], uvb);
  k_econv<128, false, true, false><<<dim3(4096), dim3(256), 0, stream>>>(
      uvb, idx, tw2h, tw2m, tw2l, W[3], nullptr, t3h, t3m, t3l, nullptr, 0);
  k_mgemm3s<128><<<dim3(2048), dim3(256), 0, stream>>>(t3h, t3m, t3l, w3Th, w3Tm, w3Tl, dpart);
  // fc1 via small MFMA: tv = relu(max+tb3) -> h1 = relu(tv@tfw1+tfb1)
  k_tv3<<<dim3(64), dim3(256), 0, stream>>>(dpart, W[5], tvh, tvm, tvl);
  k_gemmSK<512, 1024, 16><<<dim3(128), dim3(256), 0, stream>>>(tvh, tvm, tvl, fw1h, fw1m, fw1l, partial);
  k_redS<<<dim3(8), dim3(256), 0, stream>>>(partial, W[7], h1, 512, 16, 1);
  // fc2 via small MFMA, then fc3+apply
  k_pad3<<<dim3(32), dim3(256), 0, stream>>>(h1, 4, 512, h13h, h13m, h13l);
  k_gemmSK<256, 512, 8><<<dim3(32), dim3(256), 0, stream>>>(h13h, h13m, h13l, fw2h, fw2m, fw2l, partial);
  k_redS<<<dim3(4), dim3(256), 0, stream>>>(partial, W[9], h2b, 256, 8, 1);
  k_fc3p<<<dim3(4), dim3(256), 0, stream>>>(h2b, W[10], W[11], pts, p);

  // stage 2
  k_knn3<<<dim3(1024), dim3(1024), 0, stream>>>(p, idx);
  k_uv3<<<dim3(4096), dim3(256), 0, stream>>>(p, W[12], W[13], uvb);
  k_econv<64, true, true, true><<<dim3(4096), dim3(256), 0, stream>>>(
      uvb, idx, e1h, e1m, e1l, W[15], x1, xsh, xsm, xsl, xcat, 0);
  k_sqnorm<<<dim3(64), dim3(256), 0, stream>>>(x1, sq);
  k_dq<<<dim3(8192), dim3(512), 0, stream>>>(xsh, xsm, xsl, sq, cval, cidxb);
  k_dmerge<<<dim3(4096), dim3(256), 0, stream>>>(cval, cidxb, idx);
  k_uv<<<dim3(512), dim3(256), 0, stream>>>(x1, MdC, W[17], uvb);
  k_econv<64, true, true, true><<<dim3(4096), dim3(256), 0, stream>>>(
      uvb, idx, e2h, e2m, e2l, W[19], x2, xsh, xsm, xsl, xcat, 64);
  k_sqnorm<<<dim3(64), dim3(256), 0, stream>>>(x2, sq);
  k_dq<<<dim3(8192), dim3(512), 0, stream>>>(xsh, xsm, xsl, sq, cval, cidxb);
  k_dmerge<<<dim3(4096), dim3(256), 0, stream>>>(cval, cidxb, idx);
  // edgeD via u/v factorization (bias folded into u); writes xcat[128:192]
  k_uv<<<dim3(512), dim3(256), 0, stream>>>(x2, MdD, W[21], uvb);
  k_gmax<<<dim3(4096), dim3(256), 0, stream>>>(uvb, idx, xcat);

  // stage 3
  k_mgemm<192><<<dim3(2048), dim3(256), 0, stream>>>(xcat, c1wT, gpart);
  // j2 via small MFMA: g = relu(max+c1b) -> gc = g @ c2w[:1024]
  k_tv3<<<dim3(64), dim3(256), 0, stream>>>(gpart, W[23], tvh, tvm, tvl);
  k_gemmSK<512, 1024, 16><<<dim3(128), dim3(256), 0, stream>>>(tvh, tvm, tvl, cw2h, cw2m, cw2l, partial);
  k_redS<<<dim3(8), dim3(256), 0, stream>>>(partial, nullptr, gc, 512, 16, 0);
  k_final<<<dim3(1024), dim3(256), 0, stream>>>(xcat, gc, W[25], c2wT, c3wT,
                                                W[27], W[28], W[29], (float*)d_out);
}

// Round 10
// 1389.483 us; speedup vs baseline: 1.1433x; 1.1433x over previous
//
#include <hip/hip_runtime.h>

#define Nn 4096
#define KK 20
#define BN 16384   // B*N, B=4
#define FCAP 2048  // flagged-row capacity (expected ~40)

typedef __attribute__((ext_vector_type(8))) short bf16x8;
typedef __attribute__((ext_vector_type(4))) float f32x4;

__device__ __forceinline__ unsigned short f2bf(float f) {
  unsigned int x = __float_as_uint(f);
  return (unsigned short)((x + 0x7fffu + ((x >> 16) & 1u)) >> 16);
}
__device__ __forceinline__ float bf2f(unsigned short u) {
  return __uint_as_float(((unsigned int)u) << 16);
}

// 5-deep insert (val,idx) into descending list
#define INS5(dd, tt)                                                         \
  if (dd > m5) {                                                             \
    if (dd > m3) {                                                           \
      if (dd > m1) { m5=m4;t5=t4; m4=m3;t4=t3; m3=m2;t3=t2; m2=m1;t2=t1; m1=dd;t1=tt; } \
      else if (dd > m2) { m5=m4;t5=t4; m4=m3;t4=t3; m3=m2;t3=t2; m2=dd;t2=tt; } \
      else { m5=m4;t5=t4; m4=m3;t4=t3; m3=dd;t3=tt; }                        \
    } else if (dd > m4) { m5=m4;t5=t4; m4=dd;t4=tt; }                        \
    else { m5=dd; t5=tt; }                                                   \
  }

// ---------------- extract pts = x[:,:,:3] ---------------------------------
__global__ void k_pts(const float* __restrict__ x, float* __restrict__ pts) {
  int i = blockIdx.x * 256 + threadIdx.x;
  if (i < BN * 3) {
    int pt = i / 3, c = i - 3 * pt;
    pts[i] = x[pt * 6 + c];
  }
}

// ---------------- weight convert+transpose to bf16 ------------------------
__global__ void k_cvtT(const float* __restrict__ src, unsigned short* __restrict__ dst,
                       int N, int K, int ldn, int row0) {
  int i = blockIdx.x * 256 + threadIdx.x;
  if (i >= N * K) return;
  int n = i / K, k = i - n * K;
  dst[i] = f2bf(src[(size_t)(row0 + k) * ldn + n]);
}

// ---------------- transpose + 3-way bf16 split ----------------------------
__global__ void k_cvtT3(const float* __restrict__ src, unsigned short* __restrict__ h,
                        unsigned short* __restrict__ m, unsigned short* __restrict__ l,
                        int N, int K, int ldn) {
  int i = blockIdx.x * 256 + threadIdx.x;
  if (i >= N * K) return;
  int n = i / K, k = i - n * K;
  float x = src[(size_t)k * ldn + n];
  unsigned short hh = f2bf(x); float xh = bf2f(hh);
  unsigned short mm = f2bf(x - xh); float xm = bf2f(mm);
  unsigned short ll = f2bf(x - xh - xm);
  h[i] = hh; m[i] = mm; l[i] = ll;
}

// ---------------- maxreduce(32)+bias+relu -> 3-split, rows 4..15 zero -----
__global__ void k_tv3(const float* __restrict__ part, const float* __restrict__ bias,
                      unsigned short* __restrict__ h, unsigned short* __restrict__ m,
                      unsigned short* __restrict__ l) {
  int i = blockIdx.x * 256 + threadIdx.x;   // < 16*1024
  if (i >= 16 * 1024) return;
  int row = i >> 10, col = i & 1023;
  float v = 0.f;
  if (row < 4) {
    float mx = -INFINITY;
#pragma unroll 8
    for (int s = 0; s < 32; ++s) mx = fmaxf(mx, part[((size_t)row * 32 + s) * 1024 + col]);
    v = fmaxf(mx + bias[col], 0.f);
  }
  unsigned short hh = f2bf(v); float xh = bf2f(hh);
  unsigned short mm = f2bf(v - xh); float xm = bf2f(mm);
  unsigned short ll = f2bf(v - xh - xm);
  h[i] = hh; m[i] = mm; l[i] = ll;
}

// ---------------- zero-padded 3-split of [rows][cols] to [16][cols] -------
__global__ void k_pad3(const float* __restrict__ src, int rows, int cols,
                       unsigned short* __restrict__ h, unsigned short* __restrict__ m,
                       unsigned short* __restrict__ l) {
  int i = blockIdx.x * 256 + threadIdx.x;
  if (i >= 16 * cols) return;
  int row = i / cols, col = i - row * cols;
  float v = (row < rows) ? src[(size_t)row * cols + col] : 0.f;
  unsigned short hh = f2bf(v); float xh = bf2f(hh);
  unsigned short mm = f2bf(v - xh); float xm = bf2f(mm);
  unsigned short ll = f2bf(v - xh - xm);
  h[i] = hh; m[i] = mm; l[i] = ll;
}

// ---------------- split-K small MFMA GEMM: partial[seg][4][N] -------------
template <int N, int K, int SEG>
__global__ __launch_bounds__(256) void k_gemmSK(const unsigned short* __restrict__ Ah,
                                                const unsigned short* __restrict__ Am,
                                                const unsigned short* __restrict__ Al,
                                                const unsigned short* __restrict__ Bh,
                                                const unsigned short* __restrict__ Bm,
                                                const unsigned short* __restrict__ Bl,
                                                float* __restrict__ partial) {
  constexpr int KSEG = K / SEG;
  constexpr int KS = KSEG / 32;
  int t = threadIdx.x;
  int wv = t >> 6, lane = t & 63;
  int quad = lane >> 4, l16 = lane & 15;
  int bx = blockIdx.x;
  int nb = bx / SEG, seg = bx - nb * SEG;
  int col = nb * 64 + wv * 16 + l16;
  int k0 = seg * KSEG;
  size_t wo = (size_t)col * K + k0 + quad * 8;
  size_t ao = (size_t)l16 * K + k0 + quad * 8;
  f32x4 acc = {0.f, 0.f, 0.f, 0.f};
#pragma unroll
  for (int s = 0; s < KS; ++s) {
    bf16x8 xh = *(const bf16x8*)(Ah + ao + s * 32);
    bf16x8 xm = *(const bf16x8*)(Am + ao + s * 32);
    bf16x8 xl = *(const bf16x8*)(Al + ao + s * 32);
    bf16x8 wh = *(const bf16x8*)(Bh + wo + s * 32);
    bf16x8 wm = *(const bf16x8*)(Bm + wo + s * 32);
    bf16x8 wl = *(const bf16x8*)(Bl + wo + s * 32);
    acc = __builtin_amdgcn_mfma_f32_16x16x32_bf16(xh, wh, acc, 0, 0, 0);
    acc = __builtin_amdgcn_mfma_f32_16x16x32_bf16(xh, wm, acc, 0, 0, 0);
    acc = __builtin_amdgcn_mfma_f32_16x16x32_bf16(xm, wh, acc, 0, 0, 0);
    acc = __builtin_amdgcn_mfma_f32_16x16x32_bf16(xh, wl, acc, 0, 0, 0);
    acc = __builtin_amdgcn_mfma_f32_16x16x32_bf16(xl, wh, acc, 0, 0, 0);
    acc = __builtin_amdgcn_mfma_f32_16x16x32_bf16(xm, wm, acc, 0, 0, 0);
  }
  if (quad == 0) {
#pragma unroll
    for (int r = 0; r < 4; ++r)
      partial[((size_t)seg * 4 + r) * N + col] = acc[r];
  }
}

// ---------------- split-K reduce + bias + relu ----------------------------
__global__ void k_redS(const float* __restrict__ partial, const float* __restrict__ bias,
                       float* __restrict__ outp, int N, int SEG, int relu) {
  int i = blockIdx.x * 256 + threadIdx.x;
  if (i >= 4 * N) return;
  int r = i / N, c = i - r * N;
  float s = 0.f;
  for (int seg = 0; seg < SEG; ++seg) s += partial[((size_t)seg * 4 + r) * N + c];
  if (bias) s += bias[c];
  if (relu) s = fmaxf(s, 0.f);
  outp[(size_t)r * N + c] = s;
}

// ---------------- fc3 (256->9) + apply p = pts @ xf -----------------------
__global__ __launch_bounds__(256) void k_fc3p(const float* __restrict__ h2, const float* __restrict__ txw,
                                              const float* __restrict__ txb, const float* __restrict__ pts,
                                              float* __restrict__ p) {
  __shared__ float sh2[256];
  __shared__ float sxf[9];
  int t = threadIdx.x;
  int b = blockIdx.x;
  sh2[t] = h2[(size_t)b * 256 + t];
  __syncthreads();
  if (t < 9) {
    float acc = txb[t];
    for (int j = 0; j < 256; ++j) acc = fmaf(sh2[j], txw[j * 9 + t], acc);
    sxf[t] = acc;
  }
  __syncthreads();
  for (int n = t; n < Nn; n += 256) {
    const float* pr = pts + ((size_t)b * Nn + n) * 3;
    float a0 = pr[0], a1 = pr[1], a2 = pr[2];
    float* po = p + ((size_t)b * Nn + n) * 3;
#pragma unroll
    for (int d = 0; d < 3; ++d) po[d] = a0 * sxf[d] + a1 * sxf[3 + d] + a2 * sxf[6 + d];
  }
}

// ---------------- shared distance helper ----------------------------------
__device__ __forceinline__ float dist4(const float4* __restrict__ tile4, int c,
                                       float qx, float qy, float qz, float qsq) {
  float4 v = tile4[c];
  float dot = fmaf(qx, v.x, fmaf(qy, v.y, qz * v.z));
  return 2.0f * dot - qsq - v.w;
}

// ---------------- kNN, C=3: 1024 thr = 16 waves = 16 queries --------------
__global__ __launch_bounds__(1024) void k_knn3(const float* __restrict__ src, int* __restrict__ idx) {
  __shared__ float4 tile4[Nn];   // 64 KB
  int t = threadIdx.x;
  int wave = t >> 6, lane = t & 63;
  int g = blockIdx.x * 16 + wave;
  int b = g >> 12, n = g & (Nn - 1);
  const float* base = src + (size_t)b * Nn * 3;
  for (int e = t; e < Nn; e += 1024) {
    float x = base[e * 3], y = base[e * 3 + 1], z = base[e * 3 + 2];
    tile4[e] = make_float4(x, y, z, fmaf(x, x, fmaf(y, y, z * z)));
  }
  __syncthreads();
  float4 q4 = tile4[n];
  float qx = q4.x, qy = q4.y, qz = q4.z, qsq = q4.w;
  float m1 = -INFINITY, m2 = -INFINITY, m3 = -INFINITY, m4 = -INFINITY, m5 = -INFINITY;
  int t1 = 0, t2 = 0, t3 = 0, t4 = 0, t5 = 0;
#pragma unroll 4
  for (int tt = 0; tt < 64; ++tt) {
    float dd = dist4(tile4, (tt << 6) + lane, qx, qy, qz, qsq);
    INS5(dd, tt)
  }
  unsigned long long removed = 0ull;
  int cnt = 5;
  int sel = 0;
#pragma unroll 1
  for (int k = 0; k < 20; ++k) {
    float v = m1; int ci = (t1 << 6) | lane;
    float mx = v;
#pragma unroll
    for (int off = 32; off; off >>= 1) mx = fmaxf(mx, __shfl_xor(mx, off, 64));
    int cand = (v == mx) ? ci : 0x7FFFFFFF;
#pragma unroll
    for (int off = 32; off; off >>= 1) cand = min(cand, __shfl_xor(cand, off, 64));
    if (k == lane) sel = cand;
    if (cand == ci) {
      removed |= 1ull << t1;
      if (cnt > 1) { m1 = m2; t1 = t2; m2 = m3; t2 = t3; m3 = m4; t3 = t4; m4 = m5; t4 = t5; --cnt; }
      else {
        m1 = -INFINITY; m2 = -INFINITY; m3 = -INFINITY; m4 = -INFINITY; m5 = -INFINITY;
        t1 = 0; t2 = 0; t3 = 0; t4 = 0; t5 = 0;
#pragma unroll 1
        for (int tt = 0; tt < 64; ++tt) {
          if ((removed >> tt) & 1ull) continue;
          float dd = dist4(tile4, (tt << 6) + lane, qx, qy, qz, qsq);
          INS5(dd, tt)
        }
        cnt = 5;
      }
    }
  }
  if (lane < 20) idx[(size_t)g * KK + lane] = sel;
}

// ---------------- sq norms ------------------------------------------------
__global__ void k_sqnorm(const float* __restrict__ src, float* __restrict__ out) {
  int g = blockIdx.x * 256 + threadIdx.x;
  if (g >= BN) return;
  const float4* r = (const float4*)(src + (size_t)g * 64);
  float s = 0.f;
#pragma unroll
  for (int j = 0; j < 16; ++j) { float4 v = r[j]; s += v.x * v.x + v.y * v.y + v.z * v.z + v.w * v.w; }
  out[g] = s;
}

// ---------------- fast distance+top20: no d[] cache, flag rare rescans ----
// R8 structure (16 waves own 16-row strip, full 4096 cols, 4 LDS chunks,
// 20 pops/row) with the two remaining taxes removed:
//  - d[64] deleted: per-lane top-5 built on the fly. A lane exhausting its
//    5 candidates (P ~ 2e-3/row) FLAGS the row (atomicAdd) and yields
//    (m1=-INF); k_dfix recomputes flagged rows exactly. R8 kept d[] in
//    AGPRs -> accvgpr traffic + 128-reg footprint -> 82KB-LDS/1-block/CU.
//  - LDS back to 16x1028 f32 = 65.8 KB -> 2 blocks/CU, 2x occupancy.
// Non-flagged rows follow R8's exact compare sequence -> identical output.
__global__ __launch_bounds__(1024) void k_dself(const unsigned short* __restrict__ Xh,
                                                const unsigned short* __restrict__ Xm,
                                                const unsigned short* __restrict__ Xl,
                                                const float* __restrict__ sq,
                                                int* __restrict__ flagc,
                                                int* __restrict__ flagr,
                                                int* __restrict__ idx) {
  __shared__ float sD[16 * 1028];   // 65792 B, stride 1028: conflict-free (R3)
  int t = threadIdx.x;
  int wave = t >> 6, lane = t & 63;
  int quad = lane >> 4, l16 = lane & 15;
  int blk = blockIdx.x;             // 1024 = 4 batches * 256 strips
  int b = blk >> 8, rs = blk & 255;
  int r0 = rs * 16;
  const size_t base = (size_t)b * Nn * 64;
  const float* sqb = sq + b * Nn;
  bf16x8 ah[2], am[2], al[2];
#pragma unroll
  for (int ks = 0; ks < 2; ++ks) {
    size_t ra = base + (size_t)(r0 + l16) * 64 + ks * 32 + quad * 8;
    ah[ks] = *(const bf16x8*)(Xh + ra);
    am[ks] = *(const bf16x8*)(Xm + ra);
    al[ks] = *(const bf16x8*)(Xl + ra);
  }
  float sqr[4];
#pragma unroll
  for (int r = 0; r < 4; ++r) sqr[r] = sqb[r0 + quad * 4 + r];
  float m1 = -INFINITY, m2 = -INFINITY, m3 = -INFINITY, m4 = -INFINITY, m5 = -INFINITY;
  int t1 = 0, t2 = 0, t3 = 0, t4 = 0, t5 = 0;
#pragma unroll
  for (int ch = 0; ch < 4; ++ch) {
#pragma unroll
    for (int tt = 0; tt < 4; ++tt) {
      int cc = wave * 64 + tt * 16;
      int cb = ch * 1024 + cc;
      f32x4 acc = {0.f, 0.f, 0.f, 0.f};
#pragma unroll
      for (int ks = 0; ks < 2; ++ks) {
        size_t rb = base + (size_t)(cb + l16) * 64 + ks * 32 + quad * 8;
        bf16x8 bh = *(const bf16x8*)(Xh + rb);
        bf16x8 bm = *(const bf16x8*)(Xm + rb);
        bf16x8 bl = *(const bf16x8*)(Xl + rb);
        acc = __builtin_amdgcn_mfma_f32_16x16x32_bf16(ah[ks], bh, acc, 0, 0, 0);
        acc = __builtin_amdgcn_mfma_f32_16x16x32_bf16(ah[ks], bm, acc, 0, 0, 0);
        acc = __builtin_amdgcn_mfma_f32_16x16x32_bf16(am[ks], bh, acc, 0, 0, 0);
        acc = __builtin_amdgcn_mfma_f32_16x16x32_bf16(ah[ks], bl, acc, 0, 0, 0);
        acc = __builtin_amdgcn_mfma_f32_16x16x32_bf16(al[ks], bh, acc, 0, 0, 0);
        acc = __builtin_amdgcn_mfma_f32_16x16x32_bf16(am[ks], bm, acc, 0, 0, 0);
      }
      float sqc = sqb[cb + l16];
#pragma unroll
      for (int r = 0; r < 4; ++r)
        sD[(quad * 4 + r) * 1028 + cc + l16] = 2.0f * acc[r] - sqr[r] - sqc;
    }
    __syncthreads();
#pragma unroll
    for (int jj = 0; jj < 16; ++jj) {
      int tt = ch * 16 + jj;
      float dd = sD[wave * 1028 + jj * 64 + lane];
      INS5(dd, tt)
    }
    __syncthreads();
  }
  int cnt = 5;
  int sel = 0;
  bool fail = false;
#pragma unroll 1
  for (int k = 0; k < 20; ++k) {
    float v = m1; int ci = (t1 << 6) | lane;
    float mx = v;
#pragma unroll
    for (int off = 32; off; off >>= 1) mx = fmaxf(mx, __shfl_xor(mx, off, 64));
    int cand = (v == mx) ? ci : 0x7FFFFFFF;
#pragma unroll
    for (int off = 32; off; off >>= 1) cand = min(cand, __shfl_xor(cand, off, 64));
    if (k == lane) sel = cand;
    if (cand == ci) {
      if (cnt > 1) { m1 = m2; t1 = t2; m2 = m3; t2 = t3; m3 = m4; t3 = t4; m4 = m5; t4 = t5; --cnt; }
      else { fail = true; m1 = -INFINITY; }   // yield; row gets fixed later
    }
  }
  int row = b * Nn + r0 + wave;
  if (lane < 20) idx[(size_t)row * KK + lane] = sel;
  unsigned long long fm = __ballot(fail);
  if (fm != 0ull && lane == 0) {
    int p = atomicAdd(flagc, 1);
    if (p < FCAP) flagr[p] = row;
  }
}

// ---------------- exact fixup for flagged rows (rare: ~40/dispatch) -------
// One block per flagged row. Recomputes the row's distances with the SAME
// MFMA op chain (per-element accumulation depends only on this row/col's
// inputs and chain order -> bit-identical values), stages the row in LDS
// (indexable -> rescan exact), and runs the full pop-with-rescan.
__global__ __launch_bounds__(1024) void k_dfix(const unsigned short* __restrict__ Xh,
                                               const unsigned short* __restrict__ Xm,
                                               const unsigned short* __restrict__ Xl,
                                               const float* __restrict__ sq,
                                               const int* __restrict__ flagc,
                                               const int* __restrict__ flagr,
                                               int* __restrict__ idx) {
  __shared__ float sRow[Nn];   // 16 KB
  int nf = flagc[0]; if (nf > FCAP) nf = FCAP;
  if ((int)blockIdx.x >= nf) return;
  int row = flagr[blockIdx.x];
  int b = row >> 12, r = row & (Nn - 1);
  int t = threadIdx.x;
  int wave = t >> 6, lane = t & 63;
  int quad = lane >> 4, l16 = lane & 15;
  const size_t base = (size_t)b * Nn * 64;
  const float* sqb = sq + b * Nn;
  bf16x8 ah[2], am[2], al[2];
#pragma unroll
  for (int ks = 0; ks < 2; ++ks) {
    size_t ra = base + (size_t)r * 64 + ks * 32 + quad * 8;   // same row all slots
    ah[ks] = *(const bf16x8*)(Xh + ra);
    am[ks] = *(const bf16x8*)(Xm + ra);
    al[ks] = *(const bf16x8*)(Xl + ra);
  }
  float sqr = sqb[r];
#pragma unroll 1
  for (int tt = 0; tt < 16; ++tt) {
    int cb = wave * 256 + tt * 16;
    f32x4 acc = {0.f, 0.f, 0.f, 0.f};
#pragma unroll
    for (int ks = 0; ks < 2; ++ks) {
      size_t rb = base + (size_t)(cb + l16) * 64 + ks * 32 + quad * 8;
      bf16x8 bh = *(const bf16x8*)(Xh + rb);
      bf16x8 bm = *(const bf16x8*)(Xm + rb);
      bf16x8 bl = *(const bf16x8*)(Xl + rb);
      acc = __builtin_amdgcn_mfma_f32_16x16x32_bf16(ah[ks], bh, acc, 0, 0, 0);
      acc = __builtin_amdgcn_mfma_f32_16x16x32_bf16(ah[ks], bm, acc, 0, 0, 0);
      acc = __builtin_amdgcn_mfma_f32_16x16x32_bf16(am[ks], bh, acc, 0, 0, 0);
      acc = __builtin_amdgcn_mfma_f32_16x16x32_bf16(ah[ks], bl, acc, 0, 0, 0);
      acc = __builtin_amdgcn_mfma_f32_16x16x32_bf16(al[ks], bh, acc, 0, 0, 0);
      acc = __builtin_amdgcn_mfma_f32_16x16x32_bf16(am[ks], bm, acc, 0, 0, 0);
    }
    if (quad == 0) sRow[cb + l16] = 2.0f * acc[0] - sqr - sqb[cb + l16];
  }
  __syncthreads();
  if (wave != 0) return;
  float m1 = -INFINITY, m2 = -INFINITY, m3 = -INFINITY, m4 = -INFINITY, m5 = -INFINITY;
  int t1 = 0, t2 = 0, t3 = 0, t4 = 0, t5 = 0;
#pragma unroll 1
  for (int tt = 0; tt < 64; ++tt) {
    float dd = sRow[(tt << 6) | lane];
    INS5(dd, tt)
  }
  unsigned long long removed = 0ull;
  int cnt = 5;
  int sel = 0;
#pragma unroll 1
  for (int k = 0; k < 20; ++k) {
    float v = m1; int ci = (t1 << 6) | lane;
    float mx = v;
#pragma unroll
    for (int off = 32; off; off >>= 1) mx = fmaxf(mx, __shfl_xor(mx, off, 64));
    int cand = (v == mx) ? ci : 0x7FFFFFFF;
#pragma unroll
    for (int off = 32; off; off >>= 1) cand = min(cand, __shfl_xor(cand, off, 64));
    if (k == lane) sel = cand;
    if (cand == ci) {
      removed |= 1ull << t1;
      if (cnt > 1) { m1 = m2; t1 = t2; m2 = m3; t2 = t3; m3 = m4; t3 = t4; m4 = m5; t4 = t5; --cnt; }
      else {
        m1 = -INFINITY; m2 = -INFINITY; m3 = -INFINITY; m4 = -INFINITY; m5 = -INFINITY;
        t1 = 0; t2 = 0; t3 = 0; t4 = 0; t5 = 0;
#pragma unroll 1
        for (int tt = 0; tt < 64; ++tt) {
          if ((removed >> tt) & 1ull) continue;
          float dd = sRow[(tt << 6) | lane];
          INS5(dd, tt)
        }
        cnt = 5;
      }
    }
  }
  if (lane < 20) idx[(size_t)row * KK + lane] = sel;
}

// ---------------- u/v from pts (6->64 conv1 factorized) -------------------
__global__ __launch_bounds__(256) void k_uv3(const float* __restrict__ pts, const float* __restrict__ w1,
                                             const float* __restrict__ b1, float* __restrict__ uvb) {
  __shared__ float sw[384];
  __shared__ float sb[64];
  int t = threadIdx.x;
  for (int e = t; e < 384; e += 256) sw[e] = w1[e];
  if (t < 64) sb[t] = b1[t];
  __syncthreads();
  int pl = t >> 6, c = t & 63;
  int p = blockIdx.x * 4 + pl;
  const float* pr = pts + (size_t)p * 3;
  float x0 = pr[0], x1 = pr[1], x2 = pr[2];
  float wb0 = sw[192 + c], wb1 = sw[256 + c], wb2 = sw[320 + c];
  float v = x0 * wb0 + x1 * wb1 + x2 * wb2;
  float u = sb[c] + x0 * (sw[c] - wb0) + x1 * (sw[64 + c] - wb1) + x2 * (sw[128 + c] - wb2);
  uvb[(size_t)p * 128 + c] = u;
  uvb[(size_t)p * 128 + 64 + c] = v;
}

// ---------------- prep: Md[64][128] = [Wa-Wb | Wb] from 128x64 w1 ---------
__global__ void k_prepD(const float* __restrict__ w1, float* __restrict__ Md) {
  int i = blockIdx.x * 256 + threadIdx.x;
  if (i >= 8192) return;
  int j = i >> 7, c = i & 127;
  Md[i] = (c < 64) ? (w1[j * 64 + c] - w1[(64 + j) * 64 + c]) : w1[(64 + j) * 64 + (c - 64)];
}

// ---------------- uv = x @ Md (+bias on u half), 32 rows/block ------------
__global__ __launch_bounds__(256) void k_uv(const float* __restrict__ x2, const float* __restrict__ Md,
                                            const float* __restrict__ bias, float* __restrict__ uv) {
  __shared__ float sM[8192];     // 64x128
  __shared__ float sx[32 * 68];
  int t = threadIdx.x;
  for (int e = t; e < 8192; e += 256) sM[e] = Md[e];
  int p0 = blockIdx.x * 32;
  for (int e = t; e < 512; e += 256) {
    int r = e >> 4, c4 = e & 15;
    *(float4*)(sx + r * 68 + c4 * 4) = *(const float4*)(x2 + (size_t)(p0 + r) * 64 + c4 * 4);
  }
  __syncthreads();
  int c = t & 127, rg = t >> 7;
  float badd = (c < 64) ? bias[c] : 0.f;
  float accv[16];
#pragma unroll
  for (int r = 0; r < 16; ++r) accv[r] = 0.f;
#pragma unroll
  for (int jc = 0; jc < 8; ++jc) {
    float mreg[8];
#pragma unroll
    for (int q = 0; q < 8; ++q) mreg[q] = sM[(jc * 8 + q) * 128 + c];
#pragma unroll
    for (int r = 0; r < 16; ++r) {
      const float* xr = sx + (rg * 16 + r) * 68 + jc * 8;
      float4 a = *(const float4*)xr, bb = *(const float4*)(xr + 4);
      float s = accv[r];
      s = fmaf(a.x, mreg[0], s); s = fmaf(a.y, mreg[1], s);
      s = fmaf(a.z, mreg[2], s); s = fmaf(a.w, mreg[3], s);
      s = fmaf(bb.x, mreg[4], s); s = fmaf(bb.y, mreg[5], s);
      s = fmaf(bb.z, mreg[6], s); s = fmaf(bb.w, mreg[7], s);
      accv[r] = s;
    }
  }
#pragma unroll
  for (int r = 0; r < 16; ++r)
    uv[(size_t)(p0 + rg * 16 + r) * 128 + c] = accv[r] + badd;
}

// ---------------- per-edge conv2: column-owning waves, weights in regs ----
template <int NOUT, bool WRITEF, bool SPLIT3, bool CAT>
__global__ __launch_bounds__(256, 4) void k_econv(const float* __restrict__ uv,
                                                  const int* __restrict__ idx,
                                                  const unsigned short* __restrict__ W2h,
                                                  const unsigned short* __restrict__ W2m,
                                                  const unsigned short* __restrict__ W2l,
                                                  const float* __restrict__ b2,
                                                  float* __restrict__ outF,
                                                  unsigned short* __restrict__ oh,
                                                  unsigned short* __restrict__ om,
                                                  unsigned short* __restrict__ ol,
                                                  unsigned short* __restrict__ ocat,
                                                  int catoff) {
  __shared__ unsigned short y3[4][3][20 * 72];        // 34560 B
  int t = threadIdx.x;
  int wv = t >> 6, lane = t & 63;
  int quad = lane >> 4, l16 = lane & 15;
  int p0 = blockIdx.x * 4;
  int p = p0 + wv;
  size_t nbase = (size_t)(p >> 12) * Nn;
  constexpr int CT = NOUT / 64;   // col-tiles owned per wave
  bf16x8 wfh[CT][2], wfm[CT][2], wfl[CT][2];
#pragma unroll
  for (int ct = 0; ct < CT; ++ct)
#pragma unroll
    for (int ks = 0; ks < 2; ++ks) {
      size_t wo = (size_t)(wv * (CT * 16) + ct * 16 + l16) * 64 + ks * 32 + quad * 8;
      wfh[ct][ks] = *(const bf16x8*)(W2h + wo);
      wfm[ct][ks] = *(const bf16x8*)(W2m + wo);
      wfl[ct][ks] = *(const bf16x8*)(W2l + wo);
    }
  const int* ip = idx + (size_t)p * KK;
  float u = uv[(size_t)p * 128 + lane];
  unsigned short* yh = y3[wv][0];
  unsigned short* ym = y3[wv][1];
  unsigned short* yl = y3[wv][2];
  float vv[20];
#pragma unroll
  for (int k = 0; k < 20; ++k) {
    int nb = ip[k];
    vv[k] = uv[(nbase + nb) * 128 + 64 + lane];
  }
#pragma unroll
  for (int k = 0; k < 20; ++k) {
    float y = fmaxf(u + vv[k], 0.f);
    unsigned short hh = f2bf(y); float fh = bf2f(hh);
    unsigned short mm = f2bf(y - fh); float fm = bf2f(mm);
    unsigned short ll = f2bf(y - fh - fm);
    yh[k * 72 + lane] = hh;
    ym[k * 72 + lane] = mm;
    yl[k * 72 + lane] = ll;
  }
  __syncthreads();
#pragma unroll 1
  for (int pp = 0; pp < 4; ++pp) {
    const unsigned short* ph0 = y3[pp][0];
    const unsigned short* pm0 = y3[pp][1];
    const unsigned short* pl0 = y3[pp][2];
    f32x4 acc[CT][2];
#pragma unroll
    for (int ct = 0; ct < CT; ++ct) {
      acc[ct][0] = (f32x4){0.f, 0.f, 0.f, 0.f};
      acc[ct][1] = (f32x4){0.f, 0.f, 0.f, 0.f};
    }
#pragma unroll
    for (int ks = 0; ks < 2; ++ks) {
      bf16x8 ah[2], am[2], al[2];
#pragma unroll
      for (int mt = 0; mt < 2; ++mt) {
        int row = mt * 16 + l16;
        int rr = (row < 20) ? row : 0;     // clamped; lands in dead regs
        int aoff = rr * 72 + ks * 32 + quad * 8;
        ah[mt] = *(const bf16x8*)(ph0 + aoff);
        am[mt] = *(const bf16x8*)(pm0 + aoff);
        al[mt] = *(const bf16x8*)(pl0 + aoff);
      }
#pragma unroll
      for (int ct = 0; ct < CT; ++ct)
#pragma unroll
        for (int mt = 0; mt < 2; ++mt) {
          f32x4 a = acc[ct][mt];
          a = __builtin_amdgcn_mfma_f32_16x16x32_bf16(ah[mt], wfh[ct][ks], a, 0, 0, 0);
          a = __builtin_amdgcn_mfma_f32_16x16x32_bf16(ah[mt], wfm[ct][ks], a, 0, 0, 0);
          a = __builtin_amdgcn_mfma_f32_16x16x32_bf16(am[mt], wfh[ct][ks], a, 0, 0, 0);
          a = __builtin_amdgcn_mfma_f32_16x16x32_bf16(ah[mt], wfl[ct][ks], a, 0, 0, 0);
          a = __builtin_amdgcn_mfma_f32_16x16x32_bf16(al[mt], wfh[ct][ks], a, 0, 0, 0);
          a = __builtin_amdgcn_mfma_f32_16x16x32_bf16(am[mt], wfm[ct][ks], a, 0, 0, 0);
          acc[ct][mt] = a;
        }
    }
    int pt = p0 + pp;
#pragma unroll
    for (int ct = 0; ct < CT; ++ct) {
      int col = wv * (CT * 16) + ct * 16 + l16;
      float m0 = fmaxf(fmaxf(acc[ct][0][0], acc[ct][0][1]), fmaxf(acc[ct][0][2], acc[ct][0][3]));
      float m1v = (quad == 0)
                      ? fmaxf(fmaxf(acc[ct][1][0], acc[ct][1][1]), fmaxf(acc[ct][1][2], acc[ct][1][3]))
                      : -INFINITY;
      float m = fmaxf(m0, m1v);
      m = fmaxf(m, __shfl_xor(m, 16, 64));
      m = fmaxf(m, __shfl_xor(m, 32, 64));
      if (quad == 0) {
        float v = fmaxf(m + b2[col], 0.f);
        if (WRITEF) outF[(size_t)pt * NOUT + col] = v;
        if (SPLIT3) {
          unsigned short hh = f2bf(v); float fh = bf2f(hh);
          unsigned short mm2 = f2bf(v - fh); float fm = bf2f(mm2);
          unsigned short ll = f2bf(v - fh - fm);
          oh[(size_t)pt * NOUT + col] = hh;
          om[(size_t)pt * NOUT + col] = mm2;
          ol[(size_t)pt * NOUT + col] = ll;
        }
        if (CAT) ocat[(size_t)pt * 192 + catoff + col] = f2bf(v);
      }
    }
  }
}

// ---------------- x3 = relu(u + max_k v_nk) -> xcat cols 128..191 ---------
__global__ __launch_bounds__(256) void k_gmax(const float* __restrict__ uv, const int* __restrict__ idx,
                                              unsigned short* __restrict__ ocat) {
  __shared__ int sidx[4][20];
  int t = threadIdx.x;
  int pl = t >> 6, c = t & 63;
  int p0 = blockIdx.x * 4;
  if (t < 80) sidx[t / 20][t % 20] = idx[(size_t)(p0 + t / 20) * KK + (t % 20)];
  __syncthreads();
  int p = p0 + pl;
  size_t nbase = (size_t)(p >> 12) * Nn;
  float u = uv[(size_t)p * 128 + c];
  float m = -INFINITY;
#pragma unroll
  for (int k = 0; k < 20; ++k) m = fmaxf(m, uv[(nbase + sidx[pl][k]) * 128 + 64 + c]);
  ocat[(size_t)p * 192 + 128 + c] = f2bf(fmaxf(u + m, 0.f));
}

// ---------------- MFMA max-GEMM (bf16, post-kNN path), 32 row-segments ----
template <int K>
__global__ __launch_bounds__(256) void k_mgemm(const unsigned short* __restrict__ A,
                                               const unsigned short* __restrict__ WT,
                                               float* __restrict__ outp) {
  constexpr int KS = K / 32;
  int t = threadIdx.x;
  int wv = t >> 6, lane = t & 63;
  int quad = lane >> 4, l16 = lane & 15;
  int blk = blockIdx.x;                    // 4 * 16 * 32 = 2048 blocks
  int b = blk >> 9, cb = (blk >> 5) & 15, ns = blk & 31;
  int n0 = cb * 64 + wv * 16;
  bf16x8 bfr[KS];
  const unsigned short* wrow = WT + (size_t)(n0 + l16) * K + quad * 8;
#pragma unroll
  for (int s = 0; s < KS; ++s) bfr[s] = *(const bf16x8*)(wrow + s * 32);
  const unsigned short* Ab = A + ((size_t)b * Nn + ns * 128 + l16) * K + quad * 8;
  float rmax = -INFINITY;
#pragma unroll 2
  for (int mt = 0; mt < 8; ++mt) {
    const unsigned short* ar = Ab + (size_t)mt * 16 * K;
    f32x4 acc = {0.f, 0.f, 0.f, 0.f};
#pragma unroll
    for (int s = 0; s < KS; ++s) {
      bf16x8 af = *(const bf16x8*)(ar + s * 32);
      acc = __builtin_amdgcn_mfma_f32_16x16x32_bf16(af, bfr[s], acc, 0, 0, 0);
    }
    rmax = fmaxf(rmax, fmaxf(fmaxf(acc[0], acc[1]), fmaxf(acc[2], acc[3])));
  }
  rmax = fmaxf(rmax, __shfl_xor(rmax, 16, 64));
  rmax = fmaxf(rmax, __shfl_xor(rmax, 32, 64));
  if (quad == 0) outp[((size_t)b * 32 + ns) * 1024 + n0 + l16] = rmax;
}

// ---------------- MFMA max-GEMM, 3-split exact, 32 row-segments -----------
template <int K>
__global__ __launch_bounds__(256) void k_mgemm3s(const unsigned short* __restrict__ Ah,
                                                 const unsigned short* __restrict__ Am,
                                                 const unsigned short* __restrict__ Al,
                                                 const unsigned short* __restrict__ Bh,
                                                 const unsigned short* __restrict__ Bm,
                                                 const unsigned short* __restrict__ Bl,
                                                 float* __restrict__ outp) {
  constexpr int KS = K / 32;
  int t = threadIdx.x;
  int wv = t >> 6, lane = t & 63;
  int quad = lane >> 4, l16 = lane & 15;
  int blk = blockIdx.x;                    // 2048 blocks
  int b = blk >> 9, cb = (blk >> 5) & 15, ns = blk & 31;
  int n0 = cb * 64 + wv * 16;
  bf16x8 wh[KS], wm[KS], wl[KS];
  size_t wo = (size_t)(n0 + l16) * K + quad * 8;
#pragma unroll
  for (int s = 0; s < KS; ++s) {
    wh[s] = *(const bf16x8*)(Bh + wo + s * 32);
    wm[s] = *(const bf16x8*)(Bm + wo + s * 32);
    wl[s] = *(const bf16x8*)(Bl + wo + s * 32);
  }
  size_t ao = ((size_t)b * Nn + ns * 128 + l16) * K + quad * 8;
  float rmax = -INFINITY;
#pragma unroll 1
  for (int mt = 0; mt < 8; ++mt) {
    size_t ar = ao + (size_t)mt * 16 * K;
    f32x4 acc = {0.f, 0.f, 0.f, 0.f};
#pragma unroll
    for (int s = 0; s < KS; ++s) {
      bf16x8 xh = *(const bf16x8*)(Ah + ar + s * 32);
      bf16x8 xm = *(const bf16x8*)(Am + ar + s * 32);
      bf16x8 xl = *(const bf16x8*)(Al + ar + s * 32);
      acc = __builtin_amdgcn_mfma_f32_16x16x32_bf16(xh, wh[s], acc, 0, 0, 0);
      acc = __builtin_amdgcn_mfma_f32_16x16x32_bf16(xh, wm[s], acc, 0, 0, 0);
      acc = __builtin_amdgcn_mfma_f32_16x16x32_bf16(xm, wh[s], acc, 0, 0, 0);
      acc = __builtin_amdgcn_mfma_f32_16x16x32_bf16(xh, wl[s], acc, 0, 0, 0);
      acc = __builtin_amdgcn_mfma_f32_16x16x32_bf16(xl, wh[s], acc, 0, 0, 0);
      acc = __builtin_amdgcn_mfma_f32_16x16x32_bf16(xm, wm[s], acc, 0, 0, 0);
    }
    rmax = fmaxf(rmax, fmaxf(fmaxf(acc[0], acc[1]), fmaxf(acc[2], acc[3])));
  }
  rmax = fmaxf(rmax, __shfl_xor(rmax, 16, 64));
  rmax = fmaxf(rmax, __shfl_xor(rmax, 32, 64));
  if (quad == 0) outp[((size_t)b * 32 + ns) * 1024 + n0 + l16] = rmax;
}

// ---------------- fused MFMA head: 192->512->256->2 per 16 points ---------
__global__ __launch_bounds__(256) void k_final(const unsigned short* __restrict__ xcat,
                                               const float* __restrict__ gc,
                                               const float* __restrict__ c2b,
                                               const unsigned short* __restrict__ c2wT,
                                               const unsigned short* __restrict__ c3wT,
                                               const float* __restrict__ c3b,
                                               const float* __restrict__ c4w, const float* __restrict__ c4b,
                                               float* __restrict__ out) {
  __shared__ unsigned short z5[16 * 520];
  __shared__ float z2[16 * 260];
  int t = threadIdx.x;
  int wv = t >> 6, lane = t & 63;
  int quad = lane >> 4, l16 = lane & 15;
  int p0 = blockIdx.x * 16;
  int b = p0 >> 12;
  bf16x8 a1[6];
  const unsigned short* ar = xcat + (size_t)(p0 + l16) * 192 + quad * 8;
#pragma unroll
  for (int s = 0; s < 6; ++s) a1[s] = *(const bf16x8*)(ar + s * 32);
#pragma unroll 1
  for (int ntw = 0; ntw < 8; ++ntw) {
    int col = wv * 128 + ntw * 16 + l16;
    float bias = gc[(size_t)b * 512 + col] + c2b[col];
    f32x4 acc = {bias, bias, bias, bias};
    const unsigned short* wr = c2wT + (size_t)col * 192 + quad * 8;
#pragma unroll
    for (int s = 0; s < 6; ++s) {
      bf16x8 bfr = *(const bf16x8*)(wr + s * 32);
      acc = __builtin_amdgcn_mfma_f32_16x16x32_bf16(a1[s], bfr, acc, 0, 0, 0);
    }
#pragma unroll
    for (int r = 0; r < 4; ++r)
      z5[(quad * 4 + r) * 520 + col] = f2bf(fmaxf(acc[r], 0.f));
  }
  __syncthreads();
  bf16x8 a2[16];
#pragma unroll
  for (int s = 0; s < 16; ++s) a2[s] = *(const bf16x8*)(z5 + l16 * 520 + s * 32 + quad * 8);
#pragma unroll 1
  for (int ntw = 0; ntw < 4; ++ntw) {
    int col = wv * 64 + ntw * 16 + l16;
    float bias = c3b[col];
    f32x4 acc = {bias, bias, bias, bias};
    const unsigned short* wr = c3wT + (size_t)col * 512 + quad * 8;
#pragma unroll
    for (int s = 0; s < 16; ++s) {
      bf16x8 bfr = *(const bf16x8*)(wr + s * 32);
      acc = __builtin_amdgcn_mfma_f32_16x16x32_bf16(a2[s], bfr, acc, 0, 0, 0);
    }
#pragma unroll
    for (int r = 0; r < 4; ++r)
      z2[(quad * 4 + r) * 260 + col] = fmaxf(acc[r], 0.f);
  }
  __syncthreads();
  if (t < 32) {
    int m = t >> 1, e = t & 1;
    float acc = c4b[e];
    const float* zr = z2 + m * 260;
    for (int j = 0; j < 256; ++j) acc = fmaf(zr[j], c4w[j * 2 + e], acc);
    out[(size_t)(p0 + m) * 2 + e] = acc;
  }
}

// ===========================================================================
extern "C" void kernel_launch(void* const* d_in, const int* in_sizes, int n_in,
                              void* d_out, int out_size, void* d_ws, size_t ws_size,
                              hipStream_t stream) {
  const float* xin = (const float*)d_in[0];
  const float* W[30];
  for (int i = 0; i < 30; ++i) W[i] = (const float*)d_in[i + 1];

  float* ws = (float*)d_ws;
  size_t off = 0;
  float* pts   = ws + off; off += (size_t)BN * 3;
  float* p     = ws + off; off += (size_t)BN * 3;
  int*   idx   = (int*)(ws + off); off += (size_t)BN * KK;
  float* sq    = ws + off; off += BN;
  float* dpart = ws + off; off += 4 * 32 * 1024;
  float* h1    = ws + off; off += 4 * 512;
  float* h2b   = ws + off; off += 4 * 256;
  float* x1    = ws + off; off += (size_t)BN * 64;
  float* x2    = ws + off; off += (size_t)BN * 64;
  float* gpart = ws + off; off += 4 * 32 * 1024;
  float* gc    = ws + off; off += 4 * 512;
  float* uvb   = ws + off; off += (size_t)BN * 128;
  float* partial = ws + off; off += 16 * 4 * 512;
  int*   flagc = (int*)(ws + off); off += 16;          // counter (padded)
  int*   flagr = (int*)(ws + off); off += FCAP;        // flagged rows
  unsigned short* xcat = (unsigned short*)(ws + off); off += (size_t)BN * 96;
  unsigned short* c1wT = (unsigned short*)(ws + off); off += 98304;
  unsigned short* c2wT = (unsigned short*)(ws + off); off += 49152;
  unsigned short* c3wT = (unsigned short*)(ws + off); off += 65536;
  unsigned short* w3Th = (unsigned short*)(ws + off); off += 65536;
  unsigned short* w3Tm = (unsigned short*)(ws + off); off += 65536;
  unsigned short* w3Tl = (unsigned short*)(ws + off); off += 65536;
  unsigned short* tw2h = (unsigned short*)(ws + off); off += 4096;
  unsigned short* tw2m = (unsigned short*)(ws + off); off += 4096;
  unsigned short* tw2l = (unsigned short*)(ws + off); off += 4096;
  unsigned short* e1h  = (unsigned short*)(ws + off); off += 2048;
  unsigned short* e1m  = (unsigned short*)(ws + off); off += 2048;
  unsigned short* e1l  = (unsigned short*)(ws + off); off += 2048;
  unsigned short* e2h  = (unsigned short*)(ws + off); off += 2048;
  unsigned short* e2m  = (unsigned short*)(ws + off); off += 2048;
  unsigned short* e2l  = (unsigned short*)(ws + off); off += 2048;
  unsigned short* xsh  = (unsigned short*)(ws + off); off += 524288;
  unsigned short* xsm  = (unsigned short*)(ws + off); off += 524288;
  unsigned short* xsl  = (unsigned short*)(ws + off); off += 524288;
  float* MdC   = ws + off; off += 8192;
  float* MdD   = ws + off; off += 8192;
  unsigned short* fw1h = (unsigned short*)(ws + off); off += 262144;  // 512x1024 bf16
  unsigned short* fw1m = (unsigned short*)(ws + off); off += 262144;
  unsigned short* fw1l = (unsigned short*)(ws + off); off += 262144;
  unsigned short* cw2h = (unsigned short*)(ws + off); off += 262144;  // 512x1024 (c2w[:1024])
  unsigned short* cw2m = (unsigned short*)(ws + off); off += 262144;
  unsigned short* cw2l = (unsigned short*)(ws + off); off += 262144;
  unsigned short* fw2h = (unsigned short*)(ws + off); off += 65536;   // 256x512 bf16
  unsigned short* fw2m = (unsigned short*)(ws + off); off += 65536;
  unsigned short* fw2l = (unsigned short*)(ws + off); off += 65536;
  unsigned short* tvh  = (unsigned short*)(ws + off); off += 8192;    // 16x1024 bf16
  unsigned short* tvm  = (unsigned short*)(ws + off); off += 8192;
  unsigned short* tvl  = (unsigned short*)(ws + off); off += 8192;
  unsigned short* h13h = (unsigned short*)(ws + off); off += 4096;    // 16x512 bf16
  unsigned short* h13m = (unsigned short*)(ws + off); off += 4096;
  unsigned short* h13l = (unsigned short*)(ws + off); off += 4096;
  float* Dbuf  = ws + off; off += (size_t)Nn * Nn;   // kept: t3h/m/l alias
  unsigned short* t3h = (unsigned short*)Dbuf;       // stage-1 only
  unsigned short* t3m = t3h + (size_t)BN * 128;
  unsigned short* t3l = t3m + (size_t)BN * 128;

  // weight prep
  k_cvtT<<<dim3(768), dim3(256), 0, stream>>>(W[22], c1wT, 1024, 192, 1024, 0);
  k_cvtT<<<dim3(384), dim3(256), 0, stream>>>(W[24], c2wT, 512, 192, 512, 1024);
  k_cvtT<<<dim3(512), dim3(256), 0, stream>>>(W[26], c3wT, 256, 512, 256, 0);
  k_cvtT3<<<dim3(512), dim3(256), 0, stream>>>(W[4], w3Th, w3Tm, w3Tl, 1024, 128, 1024);
  k_cvtT3<<<dim3(32), dim3(256), 0, stream>>>(W[2], tw2h, tw2m, tw2l, 128, 64, 128);
  k_cvtT3<<<dim3(16), dim3(256), 0, stream>>>(W[14], e1h, e1m, e1l, 64, 64, 64);
  k_cvtT3<<<dim3(16), dim3(256), 0, stream>>>(W[18], e2h, e2m, e2l, 64, 64, 64);
  k_cvtT3<<<dim3(2048), dim3(256), 0, stream>>>(W[6], fw1h, fw1m, fw1l, 512, 1024, 512);
  k_cvtT3<<<dim3(2048), dim3(256), 0, stream>>>(W[24], cw2h, cw2m, cw2l, 512, 1024, 512);
  k_cvtT3<<<dim3(512), dim3(256), 0, stream>>>(W[8], fw2h, fw2m, fw2l, 256, 512, 256);
  k_prepD<<<dim3(32), dim3(256), 0, stream>>>(W[16], MdC);
  k_prepD<<<dim3(32), dim3(256), 0, stream>>>(W[20], MdD);

  k_pts<<<dim3(192), dim3(256), 0, stream>>>(xin, pts);

  // stage 1: transform branch
  k_knn3<<<dim3(1024), dim3(1024), 0, stream>>>(pts, idx);
  k_uv3<<<dim3(4096), dim3(256), 0, stream>>>(pts, W[0], W[1], uvb);
  k_econv<128, false, true, false><<<dim3(4096), dim3(256), 0, stream>>>(
      uvb, idx, tw2h, tw2m, tw2l, W[3], nullptr, t3h, t3m, t3l, nullptr, 0);
  k_mgemm3s<128><<<dim3(2048), dim3(256), 0, stream>>>(t3h, t3m, t3l, w3Th, w3Tm, w3Tl, dpart);
  // fc1 via small MFMA: tv = relu(max+tb3) -> h1 = relu(tv@tfw1+tfb1)
  k_tv3<<<dim3(64), dim3(256), 0, stream>>>(dpart, W[5], tvh, tvm, tvl);
  k_gemmSK<512, 1024, 16><<<dim3(128), dim3(256), 0, stream>>>(tvh, tvm, tvl, fw1h, fw1m, fw1l, partial);
  k_redS<<<dim3(8), dim3(256), 0, stream>>>(partial, W[7], h1, 512, 16, 1);
  // fc2 via small MFMA, then fc3+apply
  k_pad3<<<dim3(32), dim3(256), 0, stream>>>(h1, 4, 512, h13h, h13m, h13l);
  k_gemmSK<256, 512, 8><<<dim3(32), dim3(256), 0, stream>>>(h13h, h13m, h13l, fw2h, fw2m, fw2l, partial);
  k_redS<<<dim3(4), dim3(256), 0, stream>>>(partial, W[9], h2b, 256, 8, 1);
  k_fc3p<<<dim3(4), dim3(256), 0, stream>>>(h2b, W[10], W[11], pts, p);

  // stage 2
  k_knn3<<<dim3(1024), dim3(1024), 0, stream>>>(p, idx);
  k_uv3<<<dim3(4096), dim3(256), 0, stream>>>(p, W[12], W[13], uvb);
  k_econv<64, true, true, true><<<dim3(4096), dim3(256), 0, stream>>>(
      uvb, idx, e1h, e1m, e1l, W[15], x1, xsh, xsm, xsl, xcat, 0);
  k_sqnorm<<<dim3(64), dim3(256), 0, stream>>>(x1, sq);
  hipMemsetAsync(flagc, 0, sizeof(int), stream);
  k_dself<<<dim3(1024), dim3(1024), 0, stream>>>(xsh, xsm, xsl, sq, flagc, flagr, idx);
  k_dfix<<<dim3(FCAP), dim3(1024), 0, stream>>>(xsh, xsm, xsl, sq, flagc, flagr, idx);
  k_uv<<<dim3(512), dim3(256), 0, stream>>>(x1, MdC, W[17], uvb);
  k_econv<64, true, true, true><<<dim3(4096), dim3(256), 0, stream>>>(
      uvb, idx, e2h, e2m, e2l, W[19], x2, xsh, xsm, xsl, xcat, 64);
  k_sqnorm<<<dim3(64), dim3(256), 0, stream>>>(x2, sq);
  hipMemsetAsync(flagc, 0, sizeof(int), stream);
  k_dself<<<dim3(1024), dim3(1024), 0, stream>>>(xsh, xsm, xsl, sq, flagc, flagr, idx);
  k_dfix<<<dim3(FCAP), dim3(1024), 0, stream>>>(xsh, xsm, xsl, sq, flagc, flagr, idx);
  // edgeD via u/v factorization (bias folded into u); writes xcat[128:192]
  k_uv<<<dim3(512), dim3(256), 0, stream>>>(x2, MdD, W[21], uvb);
  k_gmax<<<dim3(4096), dim3(256), 0, stream>>>(uvb, idx, xcat);

  // stage 3
  k_mgemm<192><<<dim3(2048), dim3(256), 0, stream>>>(xcat, c1wT, gpart);
  // j2 via small MFMA: g = relu(max+c1b) -> gc = g @ c2w[:1024]
  k_tv3<<<dim3(64), dim3(256), 0, stream>>>(gpart, W[23], tvh, tvm, tvl);
  k_gemmSK<512, 1024, 16><<<dim3(128), dim3(256), 0, stream>>>(tvh, tvm, tvl, cw2h, cw2m, cw2l, partial);
  k_redS<<<dim3(8), dim3(256), 0, stream>>>(partial, nullptr, gc, 512, 16, 0);
  k_final<<<dim3(1024), dim3(256), 0, stream>>>(xcat, gc, W[25], c2wT, c3wT,
                                                W[27], W[28], W[29], (float*)d_out);
}

// Round 11
// 1233.642 us; speedup vs baseline: 1.2877x; 1.1263x over previous
//
#include <hip/hip_runtime.h>

#define Nn 4096
#define KK 20
#define BN 16384   // B*N, B=4

typedef __attribute__((ext_vector_type(8))) short bf16x8;
typedef __attribute__((ext_vector_type(4))) float f32x4;

__device__ __forceinline__ unsigned short f2bf(float f) {
  unsigned int x = __float_as_uint(f);
  return (unsigned short)((x + 0x7fffu + ((x >> 16) & 1u)) >> 16);
}
__device__ __forceinline__ float bf2f(unsigned short u) {
  return __uint_as_float(((unsigned int)u) << 16);
}

// 5-deep insert (val,idx) into descending list
#define INS5(dd, tt)                                                         \
  if (dd > m5) {                                                             \
    if (dd > m3) {                                                           \
      if (dd > m1) { m5=m4;t5=t4; m4=m3;t4=t3; m3=m2;t3=t2; m2=m1;t2=t1; m1=dd;t1=tt; } \
      else if (dd > m2) { m5=m4;t5=t4; m4=m3;t4=t3; m3=m2;t3=t2; m2=dd;t2=tt; } \
      else { m5=m4;t5=t4; m4=m3;t4=t3; m3=dd;t3=tt; }                        \
    } else if (dd > m4) { m5=m4;t5=t4; m4=dd;t4=tt; }                        \
    else { m5=dd; t5=tt; }                                                   \
  }

// ---------------- job bodies for fused prep -------------------------------
__device__ __forceinline__ void cvtT_j(const float* __restrict__ src,
                                       unsigned short* __restrict__ dst,
                                       int N, int K, int ldn, int row0, int i) {
  if (i >= N * K) return;
  int n = i / K, k = i - n * K;
  dst[i] = f2bf(src[(size_t)(row0 + k) * ldn + n]);
}
__device__ __forceinline__ void cvtT3_j(const float* __restrict__ src,
                                        unsigned short* __restrict__ h,
                                        unsigned short* __restrict__ m,
                                        unsigned short* __restrict__ l,
                                        int N, int K, int ldn, int i) {
  if (i >= N * K) return;
  int n = i / K, k = i - n * K;
  float x = src[(size_t)k * ldn + n];
  unsigned short hh = f2bf(x); float xh = bf2f(hh);
  unsigned short mm = f2bf(x - xh); float xm = bf2f(mm);
  unsigned short ll = f2bf(x - xh - xm);
  h[i] = hh; m[i] = mm; l[i] = ll;
}
__device__ __forceinline__ void prepD_j(const float* __restrict__ w1,
                                        float* __restrict__ Md, int i) {
  if (i >= 8192) return;
  int j = i >> 7, c = i & 127;
  Md[i] = (c < 64) ? (w1[j * 64 + c] - w1[(64 + j) * 64 + c]) : w1[(64 + j) * 64 + (c - 64)];
}

// ---------------- fused weight prep + pts extract (13 launches -> 1) ------
// All jobs depend only on kernel inputs; identical per-element formulas to
// the old k_cvtT/k_cvtT3/k_prepD/k_pts -> bit-identical outputs. Block-range
// dispatch, uniform branch per block. Grid = 7104 blocks.
__global__ __launch_bounds__(256) void k_prepAll(
    const float* __restrict__ xin, float* __restrict__ pts,
    const float* __restrict__ W22, unsigned short* __restrict__ c1wT,
    const float* __restrict__ W24, unsigned short* __restrict__ c2wT,
    const float* __restrict__ W26, unsigned short* __restrict__ c3wT,
    const float* __restrict__ W4, unsigned short* __restrict__ w3Th,
    unsigned short* __restrict__ w3Tm, unsigned short* __restrict__ w3Tl,
    const float* __restrict__ W2, unsigned short* __restrict__ tw2h,
    unsigned short* __restrict__ tw2m, unsigned short* __restrict__ tw2l,
    const float* __restrict__ W14, unsigned short* __restrict__ e1h,
    unsigned short* __restrict__ e1m, unsigned short* __restrict__ e1l,
    const float* __restrict__ W18, unsigned short* __restrict__ e2h,
    unsigned short* __restrict__ e2m, unsigned short* __restrict__ e2l,
    const float* __restrict__ W6, unsigned short* __restrict__ fw1h,
    unsigned short* __restrict__ fw1m, unsigned short* __restrict__ fw1l,
    unsigned short* __restrict__ cw2h, unsigned short* __restrict__ cw2m,
    unsigned short* __restrict__ cw2l,
    const float* __restrict__ W8, unsigned short* __restrict__ fw2h,
    unsigned short* __restrict__ fw2m, unsigned short* __restrict__ fw2l,
    const float* __restrict__ W16, float* __restrict__ MdC,
    const float* __restrict__ W20, float* __restrict__ MdD) {
  int blk = blockIdx.x, t = threadIdx.x;
  if (blk < 768) { cvtT_j(W22, c1wT, 1024, 192, 1024, 0, blk * 256 + t); return; }
  blk -= 768;
  if (blk < 384) { cvtT_j(W24, c2wT, 512, 192, 512, 1024, blk * 256 + t); return; }
  blk -= 384;
  if (blk < 512) { cvtT_j(W26, c3wT, 256, 512, 256, 0, blk * 256 + t); return; }
  blk -= 512;
  if (blk < 512) { cvtT3_j(W4, w3Th, w3Tm, w3Tl, 1024, 128, 1024, blk * 256 + t); return; }
  blk -= 512;
  if (blk < 32) { cvtT3_j(W2, tw2h, tw2m, tw2l, 128, 64, 128, blk * 256 + t); return; }
  blk -= 32;
  if (blk < 16) { cvtT3_j(W14, e1h, e1m, e1l, 64, 64, 64, blk * 256 + t); return; }
  blk -= 16;
  if (blk < 16) { cvtT3_j(W18, e2h, e2m, e2l, 64, 64, 64, blk * 256 + t); return; }
  blk -= 16;
  if (blk < 2048) { cvtT3_j(W6, fw1h, fw1m, fw1l, 512, 1024, 512, blk * 256 + t); return; }
  blk -= 2048;
  if (blk < 2048) { cvtT3_j(W24, cw2h, cw2m, cw2l, 512, 1024, 512, blk * 256 + t); return; }
  blk -= 2048;
  if (blk < 512) { cvtT3_j(W8, fw2h, fw2m, fw2l, 256, 512, 256, blk * 256 + t); return; }
  blk -= 512;
  if (blk < 32) { prepD_j(W16, MdC, blk * 256 + t); return; }
  blk -= 32;
  if (blk < 32) { prepD_j(W20, MdD, blk * 256 + t); return; }
  blk -= 32;
  { // pts extract: 192 blocks
    int i = blk * 256 + t;
    if (i < BN * 3) {
      int pt = i / 3, c = i - 3 * pt;
      pts[i] = xin[pt * 6 + c];
    }
  }
}

// ---------------- maxreduce(32)+bias+relu -> 3-split, rows 4..15 zero -----
__global__ void k_tv3(const float* __restrict__ part, const float* __restrict__ bias,
                      unsigned short* __restrict__ h, unsigned short* __restrict__ m,
                      unsigned short* __restrict__ l) {
  int i = blockIdx.x * 256 + threadIdx.x;   // < 16*1024
  if (i >= 16 * 1024) return;
  int row = i >> 10, col = i & 1023;
  float v = 0.f;
  if (row < 4) {
    float mx = -INFINITY;
#pragma unroll 8
    for (int s = 0; s < 32; ++s) mx = fmaxf(mx, part[((size_t)row * 32 + s) * 1024 + col]);
    v = fmaxf(mx + bias[col], 0.f);
  }
  unsigned short hh = f2bf(v); float xh = bf2f(hh);
  unsigned short mm = f2bf(v - xh); float xm = bf2f(mm);
  unsigned short ll = f2bf(v - xh - xm);
  h[i] = hh; m[i] = mm; l[i] = ll;
}

// ---------------- zero-padded 3-split of [rows][cols] to [16][cols] -------
__global__ void k_pad3(const float* __restrict__ src, int rows, int cols,
                       unsigned short* __restrict__ h, unsigned short* __restrict__ m,
                       unsigned short* __restrict__ l) {
  int i = blockIdx.x * 256 + threadIdx.x;
  if (i >= 16 * cols) return;
  int row = i / cols, col = i - row * cols;
  float v = (row < rows) ? src[(size_t)row * cols + col] : 0.f;
  unsigned short hh = f2bf(v); float xh = bf2f(hh);
  unsigned short mm = f2bf(v - xh); float xm = bf2f(mm);
  unsigned short ll = f2bf(v - xh - xm);
  h[i] = hh; m[i] = mm; l[i] = ll;
}

// ---------------- split-K small MFMA GEMM: partial[seg][4][N] -------------
template <int N, int K, int SEG>
__global__ __launch_bounds__(256) void k_gemmSK(const unsigned short* __restrict__ Ah,
                                                const unsigned short* __restrict__ Am,
                                                const unsigned short* __restrict__ Al,
                                                const unsigned short* __restrict__ Bh,
                                                const unsigned short* __restrict__ Bm,
                                                const unsigned short* __restrict__ Bl,
                                                float* __restrict__ partial) {
  constexpr int KSEG = K / SEG;
  constexpr int KS = KSEG / 32;
  int t = threadIdx.x;
  int wv = t >> 6, lane = t & 63;
  int quad = lane >> 4, l16 = lane & 15;
  int bx = blockIdx.x;
  int nb = bx / SEG, seg = bx - nb * SEG;
  int col = nb * 64 + wv * 16 + l16;
  int k0 = seg * KSEG;
  size_t wo = (size_t)col * K + k0 + quad * 8;
  size_t ao = (size_t)l16 * K + k0 + quad * 8;
  f32x4 acc = {0.f, 0.f, 0.f, 0.f};
#pragma unroll
  for (int s = 0; s < KS; ++s) {
    bf16x8 xh = *(const bf16x8*)(Ah + ao + s * 32);
    bf16x8 xm = *(const bf16x8*)(Am + ao + s * 32);
    bf16x8 xl = *(const bf16x8*)(Al + ao + s * 32);
    bf16x8 wh = *(const bf16x8*)(Bh + wo + s * 32);
    bf16x8 wm = *(const bf16x8*)(Bm + wo + s * 32);
    bf16x8 wl = *(const bf16x8*)(Bl + wo + s * 32);
    acc = __builtin_amdgcn_mfma_f32_16x16x32_bf16(xh, wh, acc, 0, 0, 0);
    acc = __builtin_amdgcn_mfma_f32_16x16x32_bf16(xh, wm, acc, 0, 0, 0);
    acc = __builtin_amdgcn_mfma_f32_16x16x32_bf16(xm, wh, acc, 0, 0, 0);
    acc = __builtin_amdgcn_mfma_f32_16x16x32_bf16(xh, wl, acc, 0, 0, 0);
    acc = __builtin_amdgcn_mfma_f32_16x16x32_bf16(xl, wh, acc, 0, 0, 0);
    acc = __builtin_amdgcn_mfma_f32_16x16x32_bf16(xm, wm, acc, 0, 0, 0);
  }
  if (quad == 0) {
#pragma unroll
    for (int r = 0; r < 4; ++r)
      partial[((size_t)seg * 4 + r) * N + col] = acc[r];
  }
}

// ---------------- split-K reduce + bias + relu ----------------------------
__global__ void k_redS(const float* __restrict__ partial, const float* __restrict__ bias,
                       float* __restrict__ outp, int N, int SEG, int relu) {
  int i = blockIdx.x * 256 + threadIdx.x;
  if (i >= 4 * N) return;
  int r = i / N, c = i - r * N;
  float s = 0.f;
  for (int seg = 0; seg < SEG; ++seg) s += partial[((size_t)seg * 4 + r) * N + c];
  if (bias) s += bias[c];
  if (relu) s = fmaxf(s, 0.f);
  outp[(size_t)r * N + c] = s;
}

// ---------------- fc3 (256->9) + apply p = pts @ xf -----------------------
__global__ __launch_bounds__(256) void k_fc3p(const float* __restrict__ h2, const float* __restrict__ txw,
                                              const float* __restrict__ txb, const float* __restrict__ pts,
                                              float* __restrict__ p) {
  __shared__ float sh2[256];
  __shared__ float sxf[9];
  int t = threadIdx.x;
  int b = blockIdx.x;
  sh2[t] = h2[(size_t)b * 256 + t];
  __syncthreads();
  if (t < 9) {
    float acc = txb[t];
    for (int j = 0; j < 256; ++j) acc = fmaf(sh2[j], txw[j * 9 + t], acc);
    sxf[t] = acc;
  }
  __syncthreads();
  for (int n = t; n < Nn; n += 256) {
    const float* pr = pts + ((size_t)b * Nn + n) * 3;
    float a0 = pr[0], a1 = pr[1], a2 = pr[2];
    float* po = p + ((size_t)b * Nn + n) * 3;
#pragma unroll
    for (int d = 0; d < 3; ++d) po[d] = a0 * sxf[d] + a1 * sxf[3 + d] + a2 * sxf[6 + d];
  }
}

// ---------------- shared distance helper ----------------------------------
__device__ __forceinline__ float dist4(const float4* __restrict__ tile4, int c,
                                       float qx, float qy, float qz, float qsq) {
  float4 v = tile4[c];
  float dot = fmaf(qx, v.x, fmaf(qy, v.y, qz * v.z));
  return 2.0f * dot - qsq - v.w;
}

// ---------------- kNN, C=3: 1024 thr = 16 waves = 16 queries --------------
__global__ __launch_bounds__(1024) void k_knn3(const float* __restrict__ src, int* __restrict__ idx) {
  __shared__ float4 tile4[Nn];   // 64 KB
  int t = threadIdx.x;
  int wave = t >> 6, lane = t & 63;
  int g = blockIdx.x * 16 + wave;
  int b = g >> 12, n = g & (Nn - 1);
  const float* base = src + (size_t)b * Nn * 3;
  for (int e = t; e < Nn; e += 1024) {
    float x = base[e * 3], y = base[e * 3 + 1], z = base[e * 3 + 2];
    tile4[e] = make_float4(x, y, z, fmaf(x, x, fmaf(y, y, z * z)));
  }
  __syncthreads();
  float4 q4 = tile4[n];
  float qx = q4.x, qy = q4.y, qz = q4.z, qsq = q4.w;
  float m1 = -INFINITY, m2 = -INFINITY, m3 = -INFINITY, m4 = -INFINITY, m5 = -INFINITY;
  int t1 = 0, t2 = 0, t3 = 0, t4 = 0, t5 = 0;
#pragma unroll 4
  for (int tt = 0; tt < 64; ++tt) {
    float dd = dist4(tile4, (tt << 6) + lane, qx, qy, qz, qsq);
    INS5(dd, tt)
  }
  unsigned long long removed = 0ull;
  int cnt = 5;
  int sel = 0;
#pragma unroll 1
  for (int k = 0; k < 20; ++k) {
    float v = m1; int ci = (t1 << 6) | lane;
    float mx = v;
#pragma unroll
    for (int off = 32; off; off >>= 1) mx = fmaxf(mx, __shfl_xor(mx, off, 64));
    int cand = (v == mx) ? ci : 0x7FFFFFFF;
#pragma unroll
    for (int off = 32; off; off >>= 1) cand = min(cand, __shfl_xor(cand, off, 64));
    if (k == lane) sel = cand;
    if (cand == ci) {
      removed |= 1ull << t1;
      if (cnt > 1) { m1 = m2; t1 = t2; m2 = m3; t2 = t3; m3 = m4; t3 = t4; m4 = m5; t4 = t5; --cnt; }
      else {
        m1 = -INFINITY; m2 = -INFINITY; m3 = -INFINITY; m4 = -INFINITY; m5 = -INFINITY;
        t1 = 0; t2 = 0; t3 = 0; t4 = 0; t5 = 0;
#pragma unroll 1
        for (int tt = 0; tt < 64; ++tt) {
          if ((removed >> tt) & 1ull) continue;
          float dd = dist4(tile4, (tt << 6) + lane, qx, qy, qz, qsq);
          INS5(dd, tt)
        }
        cnt = 5;
      }
    }
  }
  if (lane < 20) idx[(size_t)g * KK + lane] = sel;
}

// ---------------- sq norms ------------------------------------------------
__global__ void k_sqnorm(const float* __restrict__ src, float* __restrict__ out) {
  int g = blockIdx.x * 256 + threadIdx.x;
  if (g >= BN) return;
  const float4* r = (const float4*)(src + (size_t)g * 64);
  float s = 0.f;
#pragma unroll
  for (int j = 0; j < 16; ++j) { float4 v = r[j]; s += v.x * v.x + v.y * v.y + v.z * v.z + v.w * v.w; }
  out[g] = s;
}

// ---------------- top-20 from d[64] (top-5 + rare rescan) -----------------
// Rescan fully unrolled: compile-time subscripts keep d[64] in registers
// (rule #20). R8-verified config: 298us, no spill.
__device__ __forceinline__ void topk_d5(const float (&d)[64],
                                        float m1, int t1, float m2, int t2, float m3, int t3,
                                        float m4, int t4, float m5, int t5,
                                        int lane, int* __restrict__ op) {
  unsigned long long removed = 0ull;
  int cnt = 5;
  int sel = 0;
#pragma unroll 1
  for (int k = 0; k < 20; ++k) {
    float v = m1; int ci = (t1 << 6) | lane;
    float mx = v;
#pragma unroll
    for (int off = 32; off; off >>= 1) mx = fmaxf(mx, __shfl_xor(mx, off, 64));
    int cand = (v == mx) ? ci : 0x7FFFFFFF;
#pragma unroll
    for (int off = 32; off; off >>= 1) cand = min(cand, __shfl_xor(cand, off, 64));
    if (k == lane) sel = cand;
    if (cand == ci) {
      removed |= 1ull << t1;
      if (cnt > 1) { m1 = m2; t1 = t2; m2 = m3; t2 = t3; m3 = m4; t3 = t4; m4 = m5; t4 = t5; --cnt; }
      else {
        m1 = -INFINITY; m2 = -INFINITY; m3 = -INFINITY; m4 = -INFINITY; m5 = -INFINITY;
        t1 = 0; t2 = 0; t3 = 0; t4 = 0; t5 = 0;
#pragma unroll
        for (int tt = 0; tt < 64; ++tt) {
          if (!((removed >> tt) & 1ull)) {
            float dd = d[tt];
            INS5(dd, tt)
          }
        }
        cnt = 5;
      }
    }
  }
  if (lane < 20) op[lane] = sel;
}

// ---------------- fused distance GEMM + top-20 (R8 config, best total) ----
// 16 waves own a 16-row strip, full 4096 cols via 4 LDS chunks; d[64] in
// regs; 82.2KB LDS. Six structural variants (R4-R10) all land 290+-25us:
// this is the structure's floor; keep the best-total version.
__global__ __launch_bounds__(1024) void k_dsel(const unsigned short* __restrict__ Xh,
                                               const unsigned short* __restrict__ Xm,
                                               const unsigned short* __restrict__ Xl,
                                               const float* __restrict__ sq,
                                               int* __restrict__ idx) {
  __shared__ float sD[16 * 1284];   // 82176 B
  int t = threadIdx.x;
  int wave = t >> 6, lane = t & 63;
  int quad = lane >> 4, l16 = lane & 15;
  int blk = blockIdx.x;             // 1024 = 4 batches * 256 strips
  int b = blk >> 8, rs = blk & 255;
  int r0 = rs * 16;
  const size_t base = (size_t)b * Nn * 64;
  const float* sqb = sq + b * Nn;
  bf16x8 ah[2], am[2], al[2];
#pragma unroll
  for (int ks = 0; ks < 2; ++ks) {
    size_t ra = base + (size_t)(r0 + l16) * 64 + ks * 32 + quad * 8;
    ah[ks] = *(const bf16x8*)(Xh + ra);
    am[ks] = *(const bf16x8*)(Xm + ra);
    al[ks] = *(const bf16x8*)(Xl + ra);
  }
  float sqr[4];
#pragma unroll
  for (int r = 0; r < 4; ++r) sqr[r] = sqb[r0 + quad * 4 + r];
  float d[64];
  float m1 = -INFINITY, m2 = -INFINITY, m3 = -INFINITY, m4 = -INFINITY, m5 = -INFINITY;
  int t1 = 0, t2 = 0, t3 = 0, t4 = 0, t5 = 0;
#pragma unroll
  for (int ch = 0; ch < 4; ++ch) {
#pragma unroll
    for (int tt = 0; tt < 4; ++tt) {
      int cc = wave * 64 + tt * 16;
      int cb = ch * 1024 + cc;
      f32x4 acc = {0.f, 0.f, 0.f, 0.f};
#pragma unroll
      for (int ks = 0; ks < 2; ++ks) {
        size_t rb = base + (size_t)(cb + l16) * 64 + ks * 32 + quad * 8;
        bf16x8 bh = *(const bf16x8*)(Xh + rb);
        bf16x8 bm = *(const bf16x8*)(Xm + rb);
        bf16x8 bl = *(const bf16x8*)(Xl + rb);
        acc = __builtin_amdgcn_mfma_f32_16x16x32_bf16(ah[ks], bh, acc, 0, 0, 0);
        acc = __builtin_amdgcn_mfma_f32_16x16x32_bf16(ah[ks], bm, acc, 0, 0, 0);
        acc = __builtin_amdgcn_mfma_f32_16x16x32_bf16(am[ks], bh, acc, 0, 0, 0);
        acc = __builtin_amdgcn_mfma_f32_16x16x32_bf16(ah[ks], bl, acc, 0, 0, 0);
        acc = __builtin_amdgcn_mfma_f32_16x16x32_bf16(al[ks], bh, acc, 0, 0, 0);
        acc = __builtin_amdgcn_mfma_f32_16x16x32_bf16(am[ks], bm, acc, 0, 0, 0);
      }
      float sqc = sqb[cb + l16];
#pragma unroll
      for (int r = 0; r < 4; ++r)
        sD[(quad * 4 + r) * 1284 + cc + l16] = 2.0f * acc[r] - sqr[r] - sqc;
    }
    __syncthreads();
#pragma unroll
    for (int jj = 0; jj < 16; ++jj) {
      int tt = ch * 16 + jj;
      float dd = sD[wave * 1284 + jj * 64 + lane];
      d[tt] = dd;
      INS5(dd, tt)
    }
    __syncthreads();
  }
  topk_d5(d, m1, t1, m2, t2, m3, t3, m4, t4, m5, t5, lane,
          idx + (size_t)(b * Nn + r0 + wave) * KK);
}

// ---------------- u/v from pts (6->64 conv1 factorized) -------------------
__global__ __launch_bounds__(256) void k_uv3(const float* __restrict__ pts, const float* __restrict__ w1,
                                             const float* __restrict__ b1, float* __restrict__ uvb) {
  __shared__ float sw[384];
  __shared__ float sb[64];
  int t = threadIdx.x;
  for (int e = t; e < 384; e += 256) sw[e] = w1[e];
  if (t < 64) sb[t] = b1[t];
  __syncthreads();
  int pl = t >> 6, c = t & 63;
  int p = blockIdx.x * 4 + pl;
  const float* pr = pts + (size_t)p * 3;
  float x0 = pr[0], x1 = pr[1], x2 = pr[2];
  float wb0 = sw[192 + c], wb1 = sw[256 + c], wb2 = sw[320 + c];
  float v = x0 * wb0 + x1 * wb1 + x2 * wb2;
  float u = sb[c] + x0 * (sw[c] - wb0) + x1 * (sw[64 + c] - wb1) + x2 * (sw[128 + c] - wb2);
  uvb[(size_t)p * 128 + c] = u;
  uvb[(size_t)p * 128 + 64 + c] = v;
}

// ---------------- uv = x @ Md (+bias on u half), 32 rows/block ------------
__global__ __launch_bounds__(256) void k_uv(const float* __restrict__ x2, const float* __restrict__ Md,
                                            const float* __restrict__ bias, float* __restrict__ uv) {
  __shared__ float sM[8192];     // 64x128
  __shared__ float sx[32 * 68];
  int t = threadIdx.x;
  for (int e = t; e < 8192; e += 256) sM[e] = Md[e];
  int p0 = blockIdx.x * 32;
  for (int e = t; e < 512; e += 256) {
    int r = e >> 4, c4 = e & 15;
    *(float4*)(sx + r * 68 + c4 * 4) = *(const float4*)(x2 + (size_t)(p0 + r) * 64 + c4 * 4);
  }
  __syncthreads();
  int c = t & 127, rg = t >> 7;
  float badd = (c < 64) ? bias[c] : 0.f;
  float accv[16];
#pragma unroll
  for (int r = 0; r < 16; ++r) accv[r] = 0.f;
#pragma unroll
  for (int jc = 0; jc < 8; ++jc) {
    float mreg[8];
#pragma unroll
    for (int q = 0; q < 8; ++q) mreg[q] = sM[(jc * 8 + q) * 128 + c];
#pragma unroll
    for (int r = 0; r < 16; ++r) {
      const float* xr = sx + (rg * 16 + r) * 68 + jc * 8;
      float4 a = *(const float4*)xr, bb = *(const float4*)(xr + 4);
      float s = accv[r];
      s = fmaf(a.x, mreg[0], s); s = fmaf(a.y, mreg[1], s);
      s = fmaf(a.z, mreg[2], s); s = fmaf(a.w, mreg[3], s);
      s = fmaf(bb.x, mreg[4], s); s = fmaf(bb.y, mreg[5], s);
      s = fmaf(bb.z, mreg[6], s); s = fmaf(bb.w, mreg[7], s);
      accv[r] = s;
    }
  }
#pragma unroll
  for (int r = 0; r < 16; ++r)
    uv[(size_t)(p0 + rg * 16 + r) * 128 + c] = accv[r] + badd;
}

// ---------------- per-edge conv2: column-owning waves, weights in regs ----
template <int NOUT, bool WRITEF, bool SPLIT3, bool CAT>
__global__ __launch_bounds__(256, 4) void k_econv(const float* __restrict__ uv,
                                                  const int* __restrict__ idx,
                                                  const unsigned short* __restrict__ W2h,
                                                  const unsigned short* __restrict__ W2m,
                                                  const unsigned short* __restrict__ W2l,
                                                  const float* __restrict__ b2,
                                                  float* __restrict__ outF,
                                                  unsigned short* __restrict__ oh,
                                                  unsigned short* __restrict__ om,
                                                  unsigned short* __restrict__ ol,
                                                  unsigned short* __restrict__ ocat,
                                                  int catoff) {
  __shared__ unsigned short y3[4][3][20 * 72];        // 34560 B
  int t = threadIdx.x;
  int wv = t >> 6, lane = t & 63;
  int quad = lane >> 4, l16 = lane & 15;
  int p0 = blockIdx.x * 4;
  int p = p0 + wv;
  size_t nbase = (size_t)(p >> 12) * Nn;
  constexpr int CT = NOUT / 64;   // col-tiles owned per wave
  bf16x8 wfh[CT][2], wfm[CT][2], wfl[CT][2];
#pragma unroll
  for (int ct = 0; ct < CT; ++ct)
#pragma unroll
    for (int ks = 0; ks < 2; ++ks) {
      size_t wo = (size_t)(wv * (CT * 16) + ct * 16 + l16) * 64 + ks * 32 + quad * 8;
      wfh[ct][ks] = *(const bf16x8*)(W2h + wo);
      wfm[ct][ks] = *(const bf16x8*)(W2m + wo);
      wfl[ct][ks] = *(const bf16x8*)(W2l + wo);
    }
  const int* ip = idx + (size_t)p * KK;
  float u = uv[(size_t)p * 128 + lane];
  unsigned short* yh = y3[wv][0];
  unsigned short* ym = y3[wv][1];
  unsigned short* yl = y3[wv][2];
  float vv[20];
#pragma unroll
  for (int k = 0; k < 20; ++k) {
    int nb = ip[k];
    vv[k] = uv[(nbase + nb) * 128 + 64 + lane];
  }
#pragma unroll
  for (int k = 0; k < 20; ++k) {
    float y = fmaxf(u + vv[k], 0.f);
    unsigned short hh = f2bf(y); float fh = bf2f(hh);
    unsigned short mm = f2bf(y - fh); float fm = bf2f(mm);
    unsigned short ll = f2bf(y - fh - fm);
    yh[k * 72 + lane] = hh;
    ym[k * 72 + lane] = mm;
    yl[k * 72 + lane] = ll;
  }
  __syncthreads();
#pragma unroll 1
  for (int pp = 0; pp < 4; ++pp) {
    const unsigned short* ph0 = y3[pp][0];
    const unsigned short* pm0 = y3[pp][1];
    const unsigned short* pl0 = y3[pp][2];
    f32x4 acc[CT][2];
#pragma unroll
    for (int ct = 0; ct < CT; ++ct) {
      acc[ct][0] = (f32x4){0.f, 0.f, 0.f, 0.f};
      acc[ct][1] = (f32x4){0.f, 0.f, 0.f, 0.f};
    }
#pragma unroll
    for (int ks = 0; ks < 2; ++ks) {
      bf16x8 ah[2], am[2], al[2];
#pragma unroll
      for (int mt = 0; mt < 2; ++mt) {
        int row = mt * 16 + l16;
        int rr = (row < 20) ? row : 0;     // clamped; lands in dead regs
        int aoff = rr * 72 + ks * 32 + quad * 8;
        ah[mt] = *(const bf16x8*)(ph0 + aoff);
        am[mt] = *(const bf16x8*)(pm0 + aoff);
        al[mt] = *(const bf16x8*)(pl0 + aoff);
      }
#pragma unroll
      for (int ct = 0; ct < CT; ++ct)
#pragma unroll
        for (int mt = 0; mt < 2; ++mt) {
          f32x4 a = acc[ct][mt];
          a = __builtin_amdgcn_mfma_f32_16x16x32_bf16(ah[mt], wfh[ct][ks], a, 0, 0, 0);
          a = __builtin_amdgcn_mfma_f32_16x16x32_bf16(ah[mt], wfm[ct][ks], a, 0, 0, 0);
          a = __builtin_amdgcn_mfma_f32_16x16x32_bf16(am[mt], wfh[ct][ks], a, 0, 0, 0);
          a = __builtin_amdgcn_mfma_f32_16x16x32_bf16(ah[mt], wfl[ct][ks], a, 0, 0, 0);
          a = __builtin_amdgcn_mfma_f32_16x16x32_bf16(al[mt], wfh[ct][ks], a, 0, 0, 0);
          a = __builtin_amdgcn_mfma_f32_16x16x32_bf16(am[mt], wfm[ct][ks], a, 0, 0, 0);
          acc[ct][mt] = a;
        }
    }
    int pt = p0 + pp;
#pragma unroll
    for (int ct = 0; ct < CT; ++ct) {
      int col = wv * (CT * 16) + ct * 16 + l16;
      float m0 = fmaxf(fmaxf(acc[ct][0][0], acc[ct][0][1]), fmaxf(acc[ct][0][2], acc[ct][0][3]));
      float m1v = (quad == 0)
                      ? fmaxf(fmaxf(acc[ct][1][0], acc[ct][1][1]), fmaxf(acc[ct][1][2], acc[ct][1][3]))
                      : -INFINITY;
      float m = fmaxf(m0, m1v);
      m = fmaxf(m, __shfl_xor(m, 16, 64));
      m = fmaxf(m, __shfl_xor(m, 32, 64));
      if (quad == 0) {
        float v = fmaxf(m + b2[col], 0.f);
        if (WRITEF) outF[(size_t)pt * NOUT + col] = v;
        if (SPLIT3) {
          unsigned short hh = f2bf(v); float fh = bf2f(hh);
          unsigned short mm2 = f2bf(v - fh); float fm = bf2f(mm2);
          unsigned short ll = f2bf(v - fh - fm);
          oh[(size_t)pt * NOUT + col] = hh;
          om[(size_t)pt * NOUT + col] = mm2;
          ol[(size_t)pt * NOUT + col] = ll;
        }
        if (CAT) ocat[(size_t)pt * 192 + catoff + col] = f2bf(v);
      }
    }
  }
}

// ---------------- x3 = relu(u + max_k v_nk) -> xcat cols 128..191 ---------
__global__ __launch_bounds__(256) void k_gmax(const float* __restrict__ uv, const int* __restrict__ idx,
                                              unsigned short* __restrict__ ocat) {
  __shared__ int sidx[4][20];
  int t = threadIdx.x;
  int pl = t >> 6, c = t & 63;
  int p0 = blockIdx.x * 4;
  if (t < 80) sidx[t / 20][t % 20] = idx[(size_t)(p0 + t / 20) * KK + (t % 20)];
  __syncthreads();
  int p = p0 + pl;
  size_t nbase = (size_t)(p >> 12) * Nn;
  float u = uv[(size_t)p * 128 + c];
  float m = -INFINITY;
#pragma unroll
  for (int k = 0; k < 20; ++k) m = fmaxf(m, uv[(nbase + sidx[pl][k]) * 128 + 64 + c]);
  ocat[(size_t)p * 192 + 128 + c] = f2bf(fmaxf(u + m, 0.f));
}

// ---------------- MFMA max-GEMM (bf16, post-kNN path), 32 row-segments ----
template <int K>
__global__ __launch_bounds__(256) void k_mgemm(const unsigned short* __restrict__ A,
                                               const unsigned short* __restrict__ WT,
                                               float* __restrict__ outp) {
  constexpr int KS = K / 32;
  int t = threadIdx.x;
  int wv = t >> 6, lane = t & 63;
  int quad = lane >> 4, l16 = lane & 15;
  int blk = blockIdx.x;                    // 4 * 16 * 32 = 2048 blocks
  int b = blk >> 9, cb = (blk >> 5) & 15, ns = blk & 31;
  int n0 = cb * 64 + wv * 16;
  bf16x8 bfr[KS];
  const unsigned short* wrow = WT + (size_t)(n0 + l16) * K + quad * 8;
#pragma unroll
  for (int s = 0; s < KS; ++s) bfr[s] = *(const bf16x8*)(wrow + s * 32);
  const unsigned short* Ab = A + ((size_t)b * Nn + ns * 128 + l16) * K + quad * 8;
  float rmax = -INFINITY;
#pragma unroll 2
  for (int mt = 0; mt < 8; ++mt) {
    const unsigned short* ar = Ab + (size_t)mt * 16 * K;
    f32x4 acc = {0.f, 0.f, 0.f, 0.f};
#pragma unroll
    for (int s = 0; s < KS; ++s) {
      bf16x8 af = *(const bf16x8*)(ar + s * 32);
      acc = __builtin_amdgcn_mfma_f32_16x16x32_bf16(af, bfr[s], acc, 0, 0, 0);
    }
    rmax = fmaxf(rmax, fmaxf(fmaxf(acc[0], acc[1]), fmaxf(acc[2], acc[3])));
  }
  rmax = fmaxf(rmax, __shfl_xor(rmax, 16, 64));
  rmax = fmaxf(rmax, __shfl_xor(rmax, 32, 64));
  if (quad == 0) outp[((size_t)b * 32 + ns) * 1024 + n0 + l16] = rmax;
}

// ---------------- MFMA max-GEMM, 3-split exact, 32 row-segments -----------
template <int K>
__global__ __launch_bounds__(256) void k_mgemm3s(const unsigned short* __restrict__ Ah,
                                                 const unsigned short* __restrict__ Am,
                                                 const unsigned short* __restrict__ Al,
                                                 const unsigned short* __restrict__ Bh,
                                                 const unsigned short* __restrict__ Bm,
                                                 const unsigned short* __restrict__ Bl,
                                                 float* __restrict__ outp) {
  constexpr int KS = K / 32;
  int t = threadIdx.x;
  int wv = t >> 6, lane = t & 63;
  int quad = lane >> 4, l16 = lane & 15;
  int blk = blockIdx.x;                    // 2048 blocks
  int b = blk >> 9, cb = (blk >> 5) & 15, ns = blk & 31;
  int n0 = cb * 64 + wv * 16;
  bf16x8 wh[KS], wm[KS], wl[KS];
  size_t wo = (size_t)(n0 + l16) * K + quad * 8;
#pragma unroll
  for (int s = 0; s < KS; ++s) {
    wh[s] = *(const bf16x8*)(Bh + wo + s * 32);
    wm[s] = *(const bf16x8*)(Bm + wo + s * 32);
    wl[s] = *(const bf16x8*)(Bl + wo + s * 32);
  }
  size_t ao = ((size_t)b * Nn + ns * 128 + l16) * K + quad * 8;
  float rmax = -INFINITY;
#pragma unroll 1
  for (int mt = 0; mt < 8; ++mt) {
    size_t ar = ao + (size_t)mt * 16 * K;
    f32x4 acc = {0.f, 0.f, 0.f, 0.f};
#pragma unroll
    for (int s = 0; s < KS; ++s) {
      bf16x8 xh = *(const bf16x8*)(Ah + ar + s * 32);
      bf16x8 xm = *(const bf16x8*)(Am + ar + s * 32);
      bf16x8 xl = *(const bf16x8*)(Al + ar + s * 32);
      acc = __builtin_amdgcn_mfma_f32_16x16x32_bf16(xh, wh[s], acc, 0, 0, 0);
      acc = __builtin_amdgcn_mfma_f32_16x16x32_bf16(xh, wm[s], acc, 0, 0, 0);
      acc = __builtin_amdgcn_mfma_f32_16x16x32_bf16(xm, wh[s], acc, 0, 0, 0);
      acc = __builtin_amdgcn_mfma_f32_16x16x32_bf16(xh, wl[s], acc, 0, 0, 0);
      acc = __builtin_amdgcn_mfma_f32_16x16x32_bf16(xl, wh[s], acc, 0, 0, 0);
      acc = __builtin_amdgcn_mfma_f32_16x16x32_bf16(xm, wm[s], acc, 0, 0, 0);
    }
    rmax = fmaxf(rmax, fmaxf(fmaxf(acc[0], acc[1]), fmaxf(acc[2], acc[3])));
  }
  rmax = fmaxf(rmax, __shfl_xor(rmax, 16, 64));
  rmax = fmaxf(rmax, __shfl_xor(rmax, 32, 64));
  if (quad == 0) outp[((size_t)b * 32 + ns) * 1024 + n0 + l16] = rmax;
}

// ---------------- fused MFMA head: 192->512->256->2 per 16 points ---------
__global__ __launch_bounds__(256) void k_final(const unsigned short* __restrict__ xcat,
                                               const float* __restrict__ gc,
                                               const float* __restrict__ c2b,
                                               const unsigned short* __restrict__ c2wT,
                                               const unsigned short* __restrict__ c3wT,
                                               const float* __restrict__ c3b,
                                               const float* __restrict__ c4w, const float* __restrict__ c4b,
                                               float* __restrict__ out) {
  __shared__ unsigned short z5[16 * 520];
  __shared__ float z2[16 * 260];
  int t = threadIdx.x;
  int wv = t >> 6, lane = t & 63;
  int quad = lane >> 4, l16 = lane & 15;
  int p0 = blockIdx.x * 16;
  int b = p0 >> 12;
  bf16x8 a1[6];
  const unsigned short* ar = xcat + (size_t)(p0 + l16) * 192 + quad * 8;
#pragma unroll
  for (int s = 0; s < 6; ++s) a1[s] = *(const bf16x8*)(ar + s * 32);
#pragma unroll 1
  for (int ntw = 0; ntw < 8; ++ntw) {
    int col = wv * 128 + ntw * 16 + l16;
    float bias = gc[(size_t)b * 512 + col] + c2b[col];
    f32x4 acc = {bias, bias, bias, bias};
    const unsigned short* wr = c2wT + (size_t)col * 192 + quad * 8;
#pragma unroll
    for (int s = 0; s < 6; ++s) {
      bf16x8 bfr = *(const bf16x8*)(wr + s * 32);
      acc = __builtin_amdgcn_mfma_f32_16x16x32_bf16(a1[s], bfr, acc, 0, 0, 0);
    }
#pragma unroll
    for (int r = 0; r < 4; ++r)
      z5[(quad * 4 + r) * 520 + col] = f2bf(fmaxf(acc[r], 0.f));
  }
  __syncthreads();
  bf16x8 a2[16];
#pragma unroll
  for (int s = 0; s < 16; ++s) a2[s] = *(const bf16x8*)(z5 + l16 * 520 + s * 32 + quad * 8);
#pragma unroll 1
  for (int ntw = 0; ntw < 4; ++ntw) {
    int col = wv * 64 + ntw * 16 + l16;
    float bias = c3b[col];
    f32x4 acc = {bias, bias, bias, bias};
    const unsigned short* wr = c3wT + (size_t)col * 512 + quad * 8;
#pragma unroll
    for (int s = 0; s < 16; ++s) {
      bf16x8 bfr = *(const bf16x8*)(wr + s * 32);
      acc = __builtin_amdgcn_mfma_f32_16x16x32_bf16(a2[s], bfr, acc, 0, 0, 0);
    }
#pragma unroll
    for (int r = 0; r < 4; ++r)
      z2[(quad * 4 + r) * 260 + col] = fmaxf(acc[r], 0.f);
  }
  __syncthreads();
  if (t < 32) {
    int m = t >> 1, e = t & 1;
    float acc = c4b[e];
    const float* zr = z2 + m * 260;
    for (int j = 0; j < 256; ++j) acc = fmaf(zr[j], c4w[j * 2 + e], acc);
    out[(size_t)(p0 + m) * 2 + e] = acc;
  }
}

// ===========================================================================
extern "C" void kernel_launch(void* const* d_in, const int* in_sizes, int n_in,
                              void* d_out, int out_size, void* d_ws, size_t ws_size,
                              hipStream_t stream) {
  const float* xin = (const float*)d_in[0];
  const float* W[30];
  for (int i = 0; i < 30; ++i) W[i] = (const float*)d_in[i + 1];

  float* ws = (float*)d_ws;
  size_t off = 0;
  float* pts   = ws + off; off += (size_t)BN * 3;
  float* p     = ws + off; off += (size_t)BN * 3;
  int*   idx   = (int*)(ws + off); off += (size_t)BN * KK;
  float* sq    = ws + off; off += BN;
  float* dpart = ws + off; off += 4 * 32 * 1024;
  float* h1    = ws + off; off += 4 * 512;
  float* h2b   = ws + off; off += 4 * 256;
  float* x1    = ws + off; off += (size_t)BN * 64;
  float* x2    = ws + off; off += (size_t)BN * 64;
  float* gpart = ws + off; off += 4 * 32 * 1024;
  float* gc    = ws + off; off += 4 * 512;
  float* uvb   = ws + off; off += (size_t)BN * 128;
  float* partial = ws + off; off += 16 * 4 * 512;
  unsigned short* xcat = (unsigned short*)(ws + off); off += (size_t)BN * 96;
  unsigned short* c1wT = (unsigned short*)(ws + off); off += 98304;
  unsigned short* c2wT = (unsigned short*)(ws + off); off += 49152;
  unsigned short* c3wT = (unsigned short*)(ws + off); off += 65536;
  unsigned short* w3Th = (unsigned short*)(ws + off); off += 65536;
  unsigned short* w3Tm = (unsigned short*)(ws + off); off += 65536;
  unsigned short* w3Tl = (unsigned short*)(ws + off); off += 65536;
  unsigned short* tw2h = (unsigned short*)(ws + off); off += 4096;
  unsigned short* tw2m = (unsigned short*)(ws + off); off += 4096;
  unsigned short* tw2l = (unsigned short*)(ws + off); off += 4096;
  unsigned short* e1h  = (unsigned short*)(ws + off); off += 2048;
  unsigned short* e1m  = (unsigned short*)(ws + off); off += 2048;
  unsigned short* e1l  = (unsigned short*)(ws + off); off += 2048;
  unsigned short* e2h  = (unsigned short*)(ws + off); off += 2048;
  unsigned short* e2m  = (unsigned short*)(ws + off); off += 2048;
  unsigned short* e2l  = (unsigned short*)(ws + off); off += 2048;
  unsigned short* xsh  = (unsigned short*)(ws + off); off += 524288;
  unsigned short* xsm  = (unsigned short*)(ws + off); off += 524288;
  unsigned short* xsl  = (unsigned short*)(ws + off); off += 524288;
  float* MdC   = ws + off; off += 8192;
  float* MdD   = ws + off; off += 8192;
  unsigned short* fw1h = (unsigned short*)(ws + off); off += 262144;  // 512x1024 bf16
  unsigned short* fw1m = (unsigned short*)(ws + off); off += 262144;
  unsigned short* fw1l = (unsigned short*)(ws + off); off += 262144;
  unsigned short* cw2h = (unsigned short*)(ws + off); off += 262144;  // 512x1024 (c2w[:1024])
  unsigned short* cw2m = (unsigned short*)(ws + off); off += 262144;
  unsigned short* cw2l = (unsigned short*)(ws + off); off += 262144;
  unsigned short* fw2h = (unsigned short*)(ws + off); off += 65536;   // 256x512 bf16
  unsigned short* fw2m = (unsigned short*)(ws + off); off += 65536;
  unsigned short* fw2l = (unsigned short*)(ws + off); off += 65536;
  unsigned short* tvh  = (unsigned short*)(ws + off); off += 8192;    // 16x1024 bf16
  unsigned short* tvm  = (unsigned short*)(ws + off); off += 8192;
  unsigned short* tvl  = (unsigned short*)(ws + off); off += 8192;
  unsigned short* h13h = (unsigned short*)(ws + off); off += 4096;    // 16x512 bf16
  unsigned short* h13m = (unsigned short*)(ws + off); off += 4096;
  unsigned short* h13l = (unsigned short*)(ws + off); off += 4096;
  float* Dbuf  = ws + off; off += (size_t)Nn * Nn;   // kept: t3h/m/l alias
  unsigned short* t3h = (unsigned short*)Dbuf;       // stage-1 only
  unsigned short* t3m = t3h + (size_t)BN * 128;
  unsigned short* t3l = t3m + (size_t)BN * 128;

  // fused weight prep + pts (13 launches -> 1)
  k_prepAll<<<dim3(7104), dim3(256), 0, stream>>>(
      xin, pts,
      W[22], c1wT, W[24], c2wT, W[26], c3wT,
      W[4], w3Th, w3Tm, w3Tl,
      W[2], tw2h, tw2m, tw2l,
      W[14], e1h, e1m, e1l,
      W[18], e2h, e2m, e2l,
      W[6], fw1h, fw1m, fw1l,
      cw2h, cw2m, cw2l,
      W[8], fw2h, fw2m, fw2l,
      W[16], MdC, W[20], MdD);

  // stage 1: transform branch
  k_knn3<<<dim3(1024), dim3(1024), 0, stream>>>(pts, idx);
  k_uv3<<<dim3(4096), dim3(256), 0, stream>>>(pts, W[0], W[1], uvb);
  k_econv<128, false, true, false><<<dim3(4096), dim3(256), 0, stream>>>(
      uvb, idx, tw2h, tw2m, tw2l, W[3], nullptr, t3h, t3m, t3l, nullptr, 0);
  k_mgemm3s<128><<<dim3(2048), dim3(256), 0, stream>>>(t3h, t3m, t3l, w3Th, w3Tm, w3Tl, dpart);
  // fc1 via small MFMA: tv = relu(max+tb3) -> h1 = relu(tv@tfw1+tfb1)
  k_tv3<<<dim3(64), dim3(256), 0, stream>>>(dpart, W[5], tvh, tvm, tvl);
  k_gemmSK<512, 1024, 16><<<dim3(128), dim3(256), 0, stream>>>(tvh, tvm, tvl, fw1h, fw1m, fw1l, partial);
  k_redS<<<dim3(8), dim3(256), 0, stream>>>(partial, W[7], h1, 512, 16, 1);
  // fc2 via small MFMA, then fc3+apply
  k_pad3<<<dim3(32), dim3(256), 0, stream>>>(h1, 4, 512, h13h, h13m, h13l);
  k_gemmSK<256, 512, 8><<<dim3(32), dim3(256), 0, stream>>>(h13h, h13m, h13l, fw2h, fw2m, fw2l, partial);
  k_redS<<<dim3(4), dim3(256), 0, stream>>>(partial, W[9], h2b, 256, 8, 1);
  k_fc3p<<<dim3(4), dim3(256), 0, stream>>>(h2b, W[10], W[11], pts, p);

  // stage 2
  k_knn3<<<dim3(1024), dim3(1024), 0, stream>>>(p, idx);
  k_uv3<<<dim3(4096), dim3(256), 0, stream>>>(p, W[12], W[13], uvb);
  k_econv<64, true, true, true><<<dim3(4096), dim3(256), 0, stream>>>(
      uvb, idx, e1h, e1m, e1l, W[15], x1, xsh, xsm, xsl, xcat, 0);
  k_sqnorm<<<dim3(64), dim3(256), 0, stream>>>(x1, sq);
  k_dsel<<<dim3(1024), dim3(1024), 0, stream>>>(xsh, xsm, xsl, sq, idx);
  k_uv<<<dim3(512), dim3(256), 0, stream>>>(x1, MdC, W[17], uvb);
  k_econv<64, true, true, true><<<dim3(4096), dim3(256), 0, stream>>>(
      uvb, idx, e2h, e2m, e2l, W[19], x2, xsh, xsm, xsl, xcat, 64);
  k_sqnorm<<<dim3(64), dim3(256), 0, stream>>>(x2, sq);
  k_dsel<<<dim3(1024), dim3(1024), 0, stream>>>(xsh, xsm, xsl, sq, idx);
  // edgeD via u/v factorization (bias folded into u); writes xcat[128:192]
  k_uv<<<dim3(512), dim3(256), 0, stream>>>(x2, MdD, W[21], uvb);
  k_gmax<<<dim3(4096), dim3(256), 0, stream>>>(uvb, idx, xcat);

  // stage 3
  k_mgemm<192><<<dim3(2048), dim3(256), 0, stream>>>(xcat, c1wT, gpart);
  // j2 via small MFMA: g = relu(max+c1b) -> gc = g @ c2w[:1024]
  k_tv3<<<dim3(64), dim3(256), 0, stream>>>(gpart, W[23], tvh, tvm, tvl);
  k_gemmSK<512, 1024, 16><<<dim3(128), dim3(256), 0, stream>>>(tvh, tvm, tvl, cw2h, cw2m, cw2l, partial);
  k_redS<<<dim3(8), dim3(256), 0, stream>>>(partial, nullptr, gc, 512, 16, 0);
  k_final<<<dim3(1024), dim3(256), 0, stream>>>(xcat, gc, W[25], c2wT, c3wT,
                                                W[27], W[28], W[29], (float*)d_out);
}

// Round 12
// 1221.453 us; speedup vs baseline: 1.3006x; 1.0100x over previous
//
#include <hip/hip_runtime.h>

#define Nn 4096
#define KK 20
#define BN 16384   // B*N, B=4

typedef __attribute__((ext_vector_type(8))) short bf16x8;
typedef __attribute__((ext_vector_type(4))) float f32x4;

__device__ __forceinline__ unsigned short f2bf(float f) {
  unsigned int x = __float_as_uint(f);
  return (unsigned short)((x + 0x7fffu + ((x >> 16) & 1u)) >> 16);
}
__device__ __forceinline__ float bf2f(unsigned short u) {
  return __uint_as_float(((unsigned int)u) << 16);
}

// 5-deep insert (val,idx) into descending list
#define INS5(dd, tt)                                                         \
  if (dd > m5) {                                                             \
    if (dd > m3) {                                                           \
      if (dd > m1) { m5=m4;t5=t4; m4=m3;t4=t3; m3=m2;t3=t2; m2=m1;t2=t1; m1=dd;t1=tt; } \
      else if (dd > m2) { m5=m4;t5=t4; m4=m3;t4=t3; m3=m2;t3=t2; m2=dd;t2=tt; } \
      else { m5=m4;t5=t4; m4=m3;t4=t3; m3=dd;t3=tt; }                        \
    } else if (dd > m4) { m5=m4;t5=t4; m4=dd;t4=tt; }                        \
    else { m5=dd; t5=tt; }                                                   \
  }

// ---------------- job bodies for fused prep -------------------------------
__device__ __forceinline__ void cvtT_j(const float* __restrict__ src,
                                       unsigned short* __restrict__ dst,
                                       int N, int K, int ldn, int row0, int i) {
  if (i >= N * K) return;
  int n = i / K, k = i - n * K;
  dst[i] = f2bf(src[(size_t)(row0 + k) * ldn + n]);
}
__device__ __forceinline__ void cvtT3_j(const float* __restrict__ src,
                                        unsigned short* __restrict__ h,
                                        unsigned short* __restrict__ m,
                                        unsigned short* __restrict__ l,
                                        int N, int K, int ldn, int i) {
  if (i >= N * K) return;
  int n = i / K, k = i - n * K;
  float x = src[(size_t)k * ldn + n];
  unsigned short hh = f2bf(x); float xh = bf2f(hh);
  unsigned short mm = f2bf(x - xh); float xm = bf2f(mm);
  unsigned short ll = f2bf(x - xh - xm);
  h[i] = hh; m[i] = mm; l[i] = ll;
}
__device__ __forceinline__ void prepD_j(const float* __restrict__ w1,
                                        float* __restrict__ Md, int i) {
  if (i >= 8192) return;
  int j = i >> 7, c = i & 127;
  Md[i] = (c < 64) ? (w1[j * 64 + c] - w1[(64 + j) * 64 + c]) : w1[(64 + j) * 64 + (c - 64)];
}

// ---------------- fused weight prep + pts extract (13 launches -> 1) ------
__global__ __launch_bounds__(256) void k_prepAll(
    const float* __restrict__ xin, float* __restrict__ pts,
    const float* __restrict__ W22, unsigned short* __restrict__ c1wT,
    const float* __restrict__ W24, unsigned short* __restrict__ c2wT,
    const float* __restrict__ W26, unsigned short* __restrict__ c3wT,
    const float* __restrict__ W4, unsigned short* __restrict__ w3Th,
    unsigned short* __restrict__ w3Tm, unsigned short* __restrict__ w3Tl,
    const float* __restrict__ W2, unsigned short* __restrict__ tw2h,
    unsigned short* __restrict__ tw2m, unsigned short* __restrict__ tw2l,
    const float* __restrict__ W14, unsigned short* __restrict__ e1h,
    unsigned short* __restrict__ e1m, unsigned short* __restrict__ e1l,
    const float* __restrict__ W18, unsigned short* __restrict__ e2h,
    unsigned short* __restrict__ e2m, unsigned short* __restrict__ e2l,
    const float* __restrict__ W6, unsigned short* __restrict__ fw1h,
    unsigned short* __restrict__ fw1m, unsigned short* __restrict__ fw1l,
    unsigned short* __restrict__ cw2h, unsigned short* __restrict__ cw2m,
    unsigned short* __restrict__ cw2l,
    const float* __restrict__ W8, unsigned short* __restrict__ fw2h,
    unsigned short* __restrict__ fw2m, unsigned short* __restrict__ fw2l,
    const float* __restrict__ W16, float* __restrict__ MdC,
    const float* __restrict__ W20, float* __restrict__ MdD) {
  int blk = blockIdx.x, t = threadIdx.x;
  if (blk < 768) { cvtT_j(W22, c1wT, 1024, 192, 1024, 0, blk * 256 + t); return; }
  blk -= 768;
  if (blk < 384) { cvtT_j(W24, c2wT, 512, 192, 512, 1024, blk * 256 + t); return; }
  blk -= 384;
  if (blk < 512) { cvtT_j(W26, c3wT, 256, 512, 256, 0, blk * 256 + t); return; }
  blk -= 512;
  if (blk < 512) { cvtT3_j(W4, w3Th, w3Tm, w3Tl, 1024, 128, 1024, blk * 256 + t); return; }
  blk -= 512;
  if (blk < 32) { cvtT3_j(W2, tw2h, tw2m, tw2l, 128, 64, 128, blk * 256 + t); return; }
  blk -= 32;
  if (blk < 16) { cvtT3_j(W14, e1h, e1m, e1l, 64, 64, 64, blk * 256 + t); return; }
  blk -= 16;
  if (blk < 16) { cvtT3_j(W18, e2h, e2m, e2l, 64, 64, 64, blk * 256 + t); return; }
  blk -= 16;
  if (blk < 2048) { cvtT3_j(W6, fw1h, fw1m, fw1l, 512, 1024, 512, blk * 256 + t); return; }
  blk -= 2048;
  if (blk < 2048) { cvtT3_j(W24, cw2h, cw2m, cw2l, 512, 1024, 512, blk * 256 + t); return; }
  blk -= 2048;
  if (blk < 512) { cvtT3_j(W8, fw2h, fw2m, fw2l, 256, 512, 256, blk * 256 + t); return; }
  blk -= 512;
  if (blk < 32) { prepD_j(W16, MdC, blk * 256 + t); return; }
  blk -= 32;
  if (blk < 32) { prepD_j(W20, MdD, blk * 256 + t); return; }
  blk -= 32;
  { // pts extract: 192 blocks
    int i = blk * 256 + t;
    if (i < BN * 3) {
      int pt = i / 3, c = i - 3 * pt;
      pts[i] = xin[pt * 6 + c];
    }
  }
}

// ---------------- maxreduce(32)+bias+relu -> 3-split, rows 4..15 zero -----
__global__ void k_tv3(const float* __restrict__ part, const float* __restrict__ bias,
                      unsigned short* __restrict__ h, unsigned short* __restrict__ m,
                      unsigned short* __restrict__ l) {
  int i = blockIdx.x * 256 + threadIdx.x;   // < 16*1024
  if (i >= 16 * 1024) return;
  int row = i >> 10, col = i & 1023;
  float v = 0.f;
  if (row < 4) {
    float mx = -INFINITY;
#pragma unroll 8
    for (int s = 0; s < 32; ++s) mx = fmaxf(mx, part[((size_t)row * 32 + s) * 1024 + col]);
    v = fmaxf(mx + bias[col], 0.f);
  }
  unsigned short hh = f2bf(v); float xh = bf2f(hh);
  unsigned short mm = f2bf(v - xh); float xm = bf2f(mm);
  unsigned short ll = f2bf(v - xh - xm);
  h[i] = hh; m[i] = mm; l[i] = ll;
}

// ---------------- zero-padded 3-split of [rows][cols] to [16][cols] -------
__global__ void k_pad3(const float* __restrict__ src, int rows, int cols,
                       unsigned short* __restrict__ h, unsigned short* __restrict__ m,
                       unsigned short* __restrict__ l) {
  int i = blockIdx.x * 256 + threadIdx.x;
  if (i >= 16 * cols) return;
  int row = i / cols, col = i - row * cols;
  float v = (row < rows) ? src[(size_t)row * cols + col] : 0.f;
  unsigned short hh = f2bf(v); float xh = bf2f(hh);
  unsigned short mm = f2bf(v - xh); float xm = bf2f(mm);
  unsigned short ll = f2bf(v - xh - xm);
  h[i] = hh; m[i] = mm; l[i] = ll;
}

// ---------------- split-K small MFMA GEMM: partial[seg][4][N] -------------
template <int N, int K, int SEG>
__global__ __launch_bounds__(256) void k_gemmSK(const unsigned short* __restrict__ Ah,
                                                const unsigned short* __restrict__ Am,
                                                const unsigned short* __restrict__ Al,
                                                const unsigned short* __restrict__ Bh,
                                                const unsigned short* __restrict__ Bm,
                                                const unsigned short* __restrict__ Bl,
                                                float* __restrict__ partial) {
  constexpr int KSEG = K / SEG;
  constexpr int KS = KSEG / 32;
  int t = threadIdx.x;
  int wv = t >> 6, lane = t & 63;
  int quad = lane >> 4, l16 = lane & 15;
  int bx = blockIdx.x;
  int nb = bx / SEG, seg = bx - nb * SEG;
  int col = nb * 64 + wv * 16 + l16;
  int k0 = seg * KSEG;
  size_t wo = (size_t)col * K + k0 + quad * 8;
  size_t ao = (size_t)l16 * K + k0 + quad * 8;
  f32x4 acc = {0.f, 0.f, 0.f, 0.f};
#pragma unroll
  for (int s = 0; s < KS; ++s) {
    bf16x8 xh = *(const bf16x8*)(Ah + ao + s * 32);
    bf16x8 xm = *(const bf16x8*)(Am + ao + s * 32);
    bf16x8 xl = *(const bf16x8*)(Al + ao + s * 32);
    bf16x8 wh = *(const bf16x8*)(Bh + wo + s * 32);
    bf16x8 wm = *(const bf16x8*)(Bm + wo + s * 32);
    bf16x8 wl = *(const bf16x8*)(Bl + wo + s * 32);
    acc = __builtin_amdgcn_mfma_f32_16x16x32_bf16(xh, wh, acc, 0, 0, 0);
    acc = __builtin_amdgcn_mfma_f32_16x16x32_bf16(xh, wm, acc, 0, 0, 0);
    acc = __builtin_amdgcn_mfma_f32_16x16x32_bf16(xm, wh, acc, 0, 0, 0);
    acc = __builtin_amdgcn_mfma_f32_16x16x32_bf16(xh, wl, acc, 0, 0, 0);
    acc = __builtin_amdgcn_mfma_f32_16x16x32_bf16(xl, wh, acc, 0, 0, 0);
    acc = __builtin_amdgcn_mfma_f32_16x16x32_bf16(xm, wm, acc, 0, 0, 0);
  }
  if (quad == 0) {
#pragma unroll
    for (int r = 0; r < 4; ++r)
      partial[((size_t)seg * 4 + r) * N + col] = acc[r];
  }
}

// ---------------- split-K reduce + bias + relu ----------------------------
__global__ void k_redS(const float* __restrict__ partial, const float* __restrict__ bias,
                       float* __restrict__ outp, int N, int SEG, int relu) {
  int i = blockIdx.x * 256 + threadIdx.x;
  if (i >= 4 * N) return;
  int r = i / N, c = i - r * N;
  float s = 0.f;
  for (int seg = 0; seg < SEG; ++seg) s += partial[((size_t)seg * 4 + r) * N + c];
  if (bias) s += bias[c];
  if (relu) s = fmaxf(s, 0.f);
  outp[(size_t)r * N + c] = s;
}

// ---------------- fc3 (256->9) + apply p = pts @ xf -----------------------
__global__ __launch_bounds__(256) void k_fc3p(const float* __restrict__ h2, const float* __restrict__ txw,
                                              const float* __restrict__ txb, const float* __restrict__ pts,
                                              float* __restrict__ p) {
  __shared__ float sh2[256];
  __shared__ float sxf[9];
  int t = threadIdx.x;
  int b = blockIdx.x;
  sh2[t] = h2[(size_t)b * 256 + t];
  __syncthreads();
  if (t < 9) {
    float acc = txb[t];
    for (int j = 0; j < 256; ++j) acc = fmaf(sh2[j], txw[j * 9 + t], acc);
    sxf[t] = acc;
  }
  __syncthreads();
  for (int n = t; n < Nn; n += 256) {
    const float* pr = pts + ((size_t)b * Nn + n) * 3;
    float a0 = pr[0], a1 = pr[1], a2 = pr[2];
    float* po = p + ((size_t)b * Nn + n) * 3;
#pragma unroll
    for (int d = 0; d < 3; ++d) po[d] = a0 * sxf[d] + a1 * sxf[3 + d] + a2 * sxf[6 + d];
  }
}

// ---------------- shared distance helper ----------------------------------
__device__ __forceinline__ float dist4(const float4* __restrict__ tile4, int c,
                                       float qx, float qy, float qz, float qsq) {
  float4 v = tile4[c];
  float dot = fmaf(qx, v.x, fmaf(qy, v.y, qz * v.z));
  return 2.0f * dot - qsq - v.w;
}

// ---------------- kNN, C=3: 1024 thr = 16 waves = 16 queries --------------
__global__ __launch_bounds__(1024) void k_knn3(const float* __restrict__ src, int* __restrict__ idx) {
  __shared__ float4 tile4[Nn];   // 64 KB
  int t = threadIdx.x;
  int wave = t >> 6, lane = t & 63;
  int g = blockIdx.x * 16 + wave;
  int b = g >> 12, n = g & (Nn - 1);
  const float* base = src + (size_t)b * Nn * 3;
  for (int e = t; e < Nn; e += 1024) {
    float x = base[e * 3], y = base[e * 3 + 1], z = base[e * 3 + 2];
    tile4[e] = make_float4(x, y, z, fmaf(x, x, fmaf(y, y, z * z)));
  }
  __syncthreads();
  float4 q4 = tile4[n];
  float qx = q4.x, qy = q4.y, qz = q4.z, qsq = q4.w;
  float m1 = -INFINITY, m2 = -INFINITY, m3 = -INFINITY, m4 = -INFINITY, m5 = -INFINITY;
  int t1 = 0, t2 = 0, t3 = 0, t4 = 0, t5 = 0;
#pragma unroll 4
  for (int tt = 0; tt < 64; ++tt) {
    float dd = dist4(tile4, (tt << 6) + lane, qx, qy, qz, qsq);
    INS5(dd, tt)
  }
  unsigned long long removed = 0ull;
  int cnt = 5;
  int sel = 0;
#pragma unroll 1
  for (int k = 0; k < 20; ++k) {
    float v = m1; int ci = (t1 << 6) | lane;
    float mx = v;
#pragma unroll
    for (int off = 32; off; off >>= 1) mx = fmaxf(mx, __shfl_xor(mx, off, 64));
    int cand = (v == mx) ? ci : 0x7FFFFFFF;
#pragma unroll
    for (int off = 32; off; off >>= 1) cand = min(cand, __shfl_xor(cand, off, 64));
    if (k == lane) sel = cand;
    if (cand == ci) {
      removed |= 1ull << t1;
      if (cnt > 1) { m1 = m2; t1 = t2; m2 = m3; t2 = t3; m3 = m4; t3 = t4; m4 = m5; t4 = t5; --cnt; }
      else {
        m1 = -INFINITY; m2 = -INFINITY; m3 = -INFINITY; m4 = -INFINITY; m5 = -INFINITY;
        t1 = 0; t2 = 0; t3 = 0; t4 = 0; t5 = 0;
#pragma unroll 1
        for (int tt = 0; tt < 64; ++tt) {
          if ((removed >> tt) & 1ull) continue;
          float dd = dist4(tile4, (tt << 6) + lane, qx, qy, qz, qsq);
          INS5(dd, tt)
        }
        cnt = 5;
      }
    }
  }
  if (lane < 20) idx[(size_t)g * KK + lane] = sel;
}

// ---------------- sq norms ------------------------------------------------
__global__ void k_sqnorm(const float* __restrict__ src, float* __restrict__ out) {
  int g = blockIdx.x * 256 + threadIdx.x;
  if (g >= BN) return;
  const float4* r = (const float4*)(src + (size_t)g * 64);
  float s = 0.f;
#pragma unroll
  for (int j = 0; j < 16; ++j) { float4 v = r[j]; s += v.x * v.x + v.y * v.y + v.z * v.z + v.w * v.w; }
  out[g] = s;
}

// ---------------- top-20 from d[64] (top-5 + rare rescan) -----------------
// Rescan fully unrolled: compile-time subscripts -> d[64] lives in AGPRs
// (unified file; R8/R11 VGPR_Count=64, zero spill traffic).
__device__ __forceinline__ void topk_d5(const float (&d)[64],
                                        float m1, int t1, float m2, int t2, float m3, int t3,
                                        float m4, int t4, float m5, int t5,
                                        int lane, int* __restrict__ op) {
  unsigned long long removed = 0ull;
  int cnt = 5;
  int sel = 0;
#pragma unroll 1
  for (int k = 0; k < 20; ++k) {
    float v = m1; int ci = (t1 << 6) | lane;
    float mx = v;
#pragma unroll
    for (int off = 32; off; off >>= 1) mx = fmaxf(mx, __shfl_xor(mx, off, 64));
    int cand = (v == mx) ? ci : 0x7FFFFFFF;
#pragma unroll
    for (int off = 32; off; off >>= 1) cand = min(cand, __shfl_xor(cand, off, 64));
    if (k == lane) sel = cand;
    if (cand == ci) {
      removed |= 1ull << t1;
      if (cnt > 1) { m1 = m2; t1 = t2; m2 = m3; t2 = t3; m3 = m4; t3 = t4; m4 = m5; t4 = t5; --cnt; }
      else {
        m1 = -INFINITY; m2 = -INFINITY; m3 = -INFINITY; m4 = -INFINITY; m5 = -INFINITY;
        t1 = 0; t2 = 0; t3 = 0; t4 = 0; t5 = 0;
#pragma unroll
        for (int tt = 0; tt < 64; ++tt) {
          if (!((removed >> tt) & 1ull)) {
            float dd = d[tt];
            INS5(dd, tt)
          }
        }
        cnt = 5;
      }
    }
  }
  if (lane < 20) op[lane] = sel;
}

// ---------------- fused distance GEMM + top-20, chunk-pipelined -----------
// 16 waves own a 16-row strip; 8 chunks of 512 cols, DOUBLE-BUFFERED LDS
// sD[2][16*644] = 82432 B (exact R8-proven size: 1 block/CU -> d[64] in
// AGPRs). One barrier per chunk; compute of chunk c+1 (independent global
// loads + MFMA into buf B) sits in the same unrolled block as selection of
// chunk c (LDS reads from buf A) -> L2 latency hides under selection VALU.
// Slot map tt = col/64 unchanged; same MFMA chain -> bit-identical output.
// Banks at stride 644 (=4 mod 32): writes 2 lanes/bank, reads 2 lanes/bank
// (both free per m136).
__global__ __launch_bounds__(1024) void k_dsel(const unsigned short* __restrict__ Xh,
                                               const unsigned short* __restrict__ Xm,
                                               const unsigned short* __restrict__ Xl,
                                               const float* __restrict__ sq,
                                               int* __restrict__ idx) {
  __shared__ float sD[2][16 * 644];   // 82432 B
  int t = threadIdx.x;
  int wave = t >> 6, lane = t & 63;
  int quad = lane >> 4, l16 = lane & 15;
  int blk = blockIdx.x;             // 1024 = 4 batches * 256 strips
  int b = blk >> 8, rs = blk & 255;
  int r0 = rs * 16;
  const size_t base = (size_t)b * Nn * 64;
  const float* sqb = sq + b * Nn;
  bf16x8 ah[2], am[2], al[2];
#pragma unroll
  for (int ks = 0; ks < 2; ++ks) {
    size_t ra = base + (size_t)(r0 + l16) * 64 + ks * 32 + quad * 8;
    ah[ks] = *(const bf16x8*)(Xh + ra);
    am[ks] = *(const bf16x8*)(Xm + ra);
    al[ks] = *(const bf16x8*)(Xl + ra);
  }
  float sqr[4];
#pragma unroll
  for (int r = 0; r < 4; ++r) sqr[r] = sqb[r0 + quad * 4 + r];

  auto COMPUTE = [&](int ch, int half) {
#pragma unroll
    for (int t2 = 0; t2 < 2; ++t2) {
      int cc = wave * 32 + t2 * 16;        // col within chunk
      int cb = ch * 512 + cc;              // global col
      f32x4 acc = {0.f, 0.f, 0.f, 0.f};
#pragma unroll
      for (int ks = 0; ks < 2; ++ks) {
        size_t rb = base + (size_t)(cb + l16) * 64 + ks * 32 + quad * 8;
        bf16x8 bh = *(const bf16x8*)(Xh + rb);
        bf16x8 bm = *(const bf16x8*)(Xm + rb);
        bf16x8 bl = *(const bf16x8*)(Xl + rb);
        acc = __builtin_amdgcn_mfma_f32_16x16x32_bf16(ah[ks], bh, acc, 0, 0, 0);
        acc = __builtin_amdgcn_mfma_f32_16x16x32_bf16(ah[ks], bm, acc, 0, 0, 0);
        acc = __builtin_amdgcn_mfma_f32_16x16x32_bf16(am[ks], bh, acc, 0, 0, 0);
        acc = __builtin_amdgcn_mfma_f32_16x16x32_bf16(ah[ks], bl, acc, 0, 0, 0);
        acc = __builtin_amdgcn_mfma_f32_16x16x32_bf16(al[ks], bh, acc, 0, 0, 0);
        acc = __builtin_amdgcn_mfma_f32_16x16x32_bf16(am[ks], bm, acc, 0, 0, 0);
      }
      float sqc = sqb[cb + l16];
#pragma unroll
      for (int r = 0; r < 4; ++r)
        sD[half][(quad * 4 + r) * 644 + cc + l16] = 2.0f * acc[r] - sqr[r] - sqc;
    }
  };

  float d[64];
  float m1 = -INFINITY, m2 = -INFINITY, m3 = -INFINITY, m4 = -INFINITY, m5 = -INFINITY;
  int t1 = 0, t2 = 0, t3 = 0, t4 = 0, t5 = 0;

  COMPUTE(0, 0);
  __syncthreads();
#pragma unroll
  for (int ch = 0; ch < 8; ++ch) {
    if (ch < 7) COMPUTE(ch + 1, (ch + 1) & 1);
#pragma unroll
    for (int jj = 0; jj < 8; ++jj) {
      int tt = ch * 8 + jj;
      float dd = sD[ch & 1][wave * 644 + jj * 64 + lane];
      d[tt] = dd;
      INS5(dd, tt)
    }
    __syncthreads();
  }
  topk_d5(d, m1, t1, m2, t2, m3, t3, m4, t4, m5, t5, lane,
          idx + (size_t)(b * Nn + r0 + wave) * KK);
}

// ---------------- u/v from pts (6->64 conv1 factorized) -------------------
__global__ __launch_bounds__(256) void k_uv3(const float* __restrict__ pts, const float* __restrict__ w1,
                                             const float* __restrict__ b1, float* __restrict__ uvb) {
  __shared__ float sw[384];
  __shared__ float sb[64];
  int t = threadIdx.x;
  for (int e = t; e < 384; e += 256) sw[e] = w1[e];
  if (t < 64) sb[t] = b1[t];
  __syncthreads();
  int pl = t >> 6, c = t & 63;
  int p = blockIdx.x * 4 + pl;
  const float* pr = pts + (size_t)p * 3;
  float x0 = pr[0], x1 = pr[1], x2 = pr[2];
  float wb0 = sw[192 + c], wb1 = sw[256 + c], wb2 = sw[320 + c];
  float v = x0 * wb0 + x1 * wb1 + x2 * wb2;
  float u = sb[c] + x0 * (sw[c] - wb0) + x1 * (sw[64 + c] - wb1) + x2 * (sw[128 + c] - wb2);
  uvb[(size_t)p * 128 + c] = u;
  uvb[(size_t)p * 128 + 64 + c] = v;
}

// ---------------- uv = x @ Md (+bias on u half), 32 rows/block ------------
__global__ __launch_bounds__(256) void k_uv(const float* __restrict__ x2, const float* __restrict__ Md,
                                            const float* __restrict__ bias, float* __restrict__ uv) {
  __shared__ float sM[8192];     // 64x128
  __shared__ float sx[32 * 68];
  int t = threadIdx.x;
  for (int e = t; e < 8192; e += 256) sM[e] = Md[e];
  int p0 = blockIdx.x * 32;
  for (int e = t; e < 512; e += 256) {
    int r = e >> 4, c4 = e & 15;
    *(float4*)(sx + r * 68 + c4 * 4) = *(const float4*)(x2 + (size_t)(p0 + r) * 64 + c4 * 4);
  }
  __syncthreads();
  int c = t & 127, rg = t >> 7;
  float badd = (c < 64) ? bias[c] : 0.f;
  float accv[16];
#pragma unroll
  for (int r = 0; r < 16; ++r) accv[r] = 0.f;
#pragma unroll
  for (int jc = 0; jc < 8; ++jc) {
    float mreg[8];
#pragma unroll
    for (int q = 0; q < 8; ++q) mreg[q] = sM[(jc * 8 + q) * 128 + c];
#pragma unroll
    for (int r = 0; r < 16; ++r) {
      const float* xr = sx + (rg * 16 + r) * 68 + jc * 8;
      float4 a = *(const float4*)xr, bb = *(const float4*)(xr + 4);
      float s = accv[r];
      s = fmaf(a.x, mreg[0], s); s = fmaf(a.y, mreg[1], s);
      s = fmaf(a.z, mreg[2], s); s = fmaf(a.w, mreg[3], s);
      s = fmaf(bb.x, mreg[4], s); s = fmaf(bb.y, mreg[5], s);
      s = fmaf(bb.z, mreg[6], s); s = fmaf(bb.w, mreg[7], s);
      accv[r] = s;
    }
  }
#pragma unroll
  for (int r = 0; r < 16; ++r)
    uv[(size_t)(p0 + rg * 16 + r) * 128 + c] = accv[r] + badd;
}

// ---------------- per-edge conv2: column-owning waves, weights in regs ----
template <int NOUT, bool WRITEF, bool SPLIT3, bool CAT>
__global__ __launch_bounds__(256, 4) void k_econv(const float* __restrict__ uv,
                                                  const int* __restrict__ idx,
                                                  const unsigned short* __restrict__ W2h,
                                                  const unsigned short* __restrict__ W2m,
                                                  const unsigned short* __restrict__ W2l,
                                                  const float* __restrict__ b2,
                                                  float* __restrict__ outF,
                                                  unsigned short* __restrict__ oh,
                                                  unsigned short* __restrict__ om,
                                                  unsigned short* __restrict__ ol,
                                                  unsigned short* __restrict__ ocat,
                                                  int catoff) {
  __shared__ unsigned short y3[4][3][20 * 72];        // 34560 B
  int t = threadIdx.x;
  int wv = t >> 6, lane = t & 63;
  int quad = lane >> 4, l16 = lane & 15;
  int p0 = blockIdx.x * 4;
  int p = p0 + wv;
  size_t nbase = (size_t)(p >> 12) * Nn;
  constexpr int CT = NOUT / 64;   // col-tiles owned per wave
  bf16x8 wfh[CT][2], wfm[CT][2], wfl[CT][2];
#pragma unroll
  for (int ct = 0; ct < CT; ++ct)
#pragma unroll
    for (int ks = 0; ks < 2; ++ks) {
      size_t wo = (size_t)(wv * (CT * 16) + ct * 16 + l16) * 64 + ks * 32 + quad * 8;
      wfh[ct][ks] = *(const bf16x8*)(W2h + wo);
      wfm[ct][ks] = *(const bf16x8*)(W2m + wo);
      wfl[ct][ks] = *(const bf16x8*)(W2l + wo);
    }
  const int* ip = idx + (size_t)p * KK;
  float u = uv[(size_t)p * 128 + lane];
  unsigned short* yh = y3[wv][0];
  unsigned short* ym = y3[wv][1];
  unsigned short* yl = y3[wv][2];
  float vv[20];
#pragma unroll
  for (int k = 0; k < 20; ++k) {
    int nb = ip[k];
    vv[k] = uv[(nbase + nb) * 128 + 64 + lane];
  }
#pragma unroll
  for (int k = 0; k < 20; ++k) {
    float y = fmaxf(u + vv[k], 0.f);
    unsigned short hh = f2bf(y); float fh = bf2f(hh);
    unsigned short mm = f2bf(y - fh); float fm = bf2f(mm);
    unsigned short ll = f2bf(y - fh - fm);
    yh[k * 72 + lane] = hh;
    ym[k * 72 + lane] = mm;
    yl[k * 72 + lane] = ll;
  }
  __syncthreads();
#pragma unroll 1
  for (int pp = 0; pp < 4; ++pp) {
    const unsigned short* ph0 = y3[pp][0];
    const unsigned short* pm0 = y3[pp][1];
    const unsigned short* pl0 = y3[pp][2];
    f32x4 acc[CT][2];
#pragma unroll
    for (int ct = 0; ct < CT; ++ct) {
      acc[ct][0] = (f32x4){0.f, 0.f, 0.f, 0.f};
      acc[ct][1] = (f32x4){0.f, 0.f, 0.f, 0.f};
    }
#pragma unroll
    for (int ks = 0; ks < 2; ++ks) {
      bf16x8 ah[2], am[2], al[2];
#pragma unroll
      for (int mt = 0; mt < 2; ++mt) {
        int row = mt * 16 + l16;
        int rr = (row < 20) ? row : 0;     // clamped; lands in dead regs
        int aoff = rr * 72 + ks * 32 + quad * 8;
        ah[mt] = *(const bf16x8*)(ph0 + aoff);
        am[mt] = *(const bf16x8*)(pm0 + aoff);
        al[mt] = *(const bf16x8*)(pl0 + aoff);
      }
#pragma unroll
      for (int ct = 0; ct < CT; ++ct)
#pragma unroll
        for (int mt = 0; mt < 2; ++mt) {
          f32x4 a = acc[ct][mt];
          a = __builtin_amdgcn_mfma_f32_16x16x32_bf16(ah[mt], wfh[ct][ks], a, 0, 0, 0);
          a = __builtin_amdgcn_mfma_f32_16x16x32_bf16(ah[mt], wfm[ct][ks], a, 0, 0, 0);
          a = __builtin_amdgcn_mfma_f32_16x16x32_bf16(am[mt], wfh[ct][ks], a, 0, 0, 0);
          a = __builtin_amdgcn_mfma_f32_16x16x32_bf16(ah[mt], wfl[ct][ks], a, 0, 0, 0);
          a = __builtin_amdgcn_mfma_f32_16x16x32_bf16(al[mt], wfh[ct][ks], a, 0, 0, 0);
          a = __builtin_amdgcn_mfma_f32_16x16x32_bf16(am[mt], wfm[ct][ks], a, 0, 0, 0);
          acc[ct][mt] = a;
        }
    }
    int pt = p0 + pp;
#pragma unroll
    for (int ct = 0; ct < CT; ++ct) {
      int col = wv * (CT * 16) + ct * 16 + l16;
      float m0 = fmaxf(fmaxf(acc[ct][0][0], acc[ct][0][1]), fmaxf(acc[ct][0][2], acc[ct][0][3]));
      float m1v = (quad == 0)
                      ? fmaxf(fmaxf(acc[ct][1][0], acc[ct][1][1]), fmaxf(acc[ct][1][2], acc[ct][1][3]))
                      : -INFINITY;
      float m = fmaxf(m0, m1v);
      m = fmaxf(m, __shfl_xor(m, 16, 64));
      m = fmaxf(m, __shfl_xor(m, 32, 64));
      if (quad == 0) {
        float v = fmaxf(m + b2[col], 0.f);
        if (WRITEF) outF[(size_t)pt * NOUT + col] = v;
        if (SPLIT3) {
          unsigned short hh = f2bf(v); float fh = bf2f(hh);
          unsigned short mm2 = f2bf(v - fh); float fm = bf2f(mm2);
          unsigned short ll = f2bf(v - fh - fm);
          oh[(size_t)pt * NOUT + col] = hh;
          om[(size_t)pt * NOUT + col] = mm2;
          ol[(size_t)pt * NOUT + col] = ll;
        }
        if (CAT) ocat[(size_t)pt * 192 + catoff + col] = f2bf(v);
      }
    }
  }
}

// ---------------- x3 = relu(u + max_k v_nk) -> xcat cols 128..191 ---------
__global__ __launch_bounds__(256) void k_gmax(const float* __restrict__ uv, const int* __restrict__ idx,
                                              unsigned short* __restrict__ ocat) {
  __shared__ int sidx[4][20];
  int t = threadIdx.x;
  int pl = t >> 6, c = t & 63;
  int p0 = blockIdx.x * 4;
  if (t < 80) sidx[t / 20][t % 20] = idx[(size_t)(p0 + t / 20) * KK + (t % 20)];
  __syncthreads();
  int p = p0 + pl;
  size_t nbase = (size_t)(p >> 12) * Nn;
  float u = uv[(size_t)p * 128 + c];
  float m = -INFINITY;
#pragma unroll
  for (int k = 0; k < 20; ++k) m = fmaxf(m, uv[(nbase + sidx[pl][k]) * 128 + 64 + c]);
  ocat[(size_t)p * 192 + 128 + c] = f2bf(fmaxf(u + m, 0.f));
}

// ---------------- MFMA max-GEMM (bf16, post-kNN path), 32 row-segments ----
template <int K>
__global__ __launch_bounds__(256) void k_mgemm(const unsigned short* __restrict__ A,
                                               const unsigned short* __restrict__ WT,
                                               float* __restrict__ outp) {
  constexpr int KS = K / 32;
  int t = threadIdx.x;
  int wv = t >> 6, lane = t & 63;
  int quad = lane >> 4, l16 = lane & 15;
  int blk = blockIdx.x;                    // 4 * 16 * 32 = 2048 blocks
  int b = blk >> 9, cb = (blk >> 5) & 15, ns = blk & 31;
  int n0 = cb * 64 + wv * 16;
  bf16x8 bfr[KS];
  const unsigned short* wrow = WT + (size_t)(n0 + l16) * K + quad * 8;
#pragma unroll
  for (int s = 0; s < KS; ++s) bfr[s] = *(const bf16x8*)(wrow + s * 32);
  const unsigned short* Ab = A + ((size_t)b * Nn + ns * 128 + l16) * K + quad * 8;
  float rmax = -INFINITY;
#pragma unroll 2
  for (int mt = 0; mt < 8; ++mt) {
    const unsigned short* ar = Ab + (size_t)mt * 16 * K;
    f32x4 acc = {0.f, 0.f, 0.f, 0.f};
#pragma unroll
    for (int s = 0; s < KS; ++s) {
      bf16x8 af = *(const bf16x8*)(ar + s * 32);
      acc = __builtin_amdgcn_mfma_f32_16x16x32_bf16(af, bfr[s], acc, 0, 0, 0);
    }
    rmax = fmaxf(rmax, fmaxf(fmaxf(acc[0], acc[1]), fmaxf(acc[2], acc[3])));
  }
  rmax = fmaxf(rmax, __shfl_xor(rmax, 16, 64));
  rmax = fmaxf(rmax, __shfl_xor(rmax, 32, 64));
  if (quad == 0) outp[((size_t)b * 32 + ns) * 1024 + n0 + l16] = rmax;
}

// ---------------- MFMA max-GEMM, 3-split exact, 32 row-segments -----------
template <int K>
__global__ __launch_bounds__(256) void k_mgemm3s(const unsigned short* __restrict__ Ah,
                                                 const unsigned short* __restrict__ Am,
                                                 const unsigned short* __restrict__ Al,
                                                 const unsigned short* __restrict__ Bh,
                                                 const unsigned short* __restrict__ Bm,
                                                 const unsigned short* __restrict__ Bl,
                                                 float* __restrict__ outp) {
  constexpr int KS = K / 32;
  int t = threadIdx.x;
  int wv = t >> 6, lane = t & 63;
  int quad = lane >> 4, l16 = lane & 15;
  int blk = blockIdx.x;                    // 2048 blocks
  int b = blk >> 9, cb = (blk >> 5) & 15, ns = blk & 31;
  int n0 = cb * 64 + wv * 16;
  bf16x8 wh[KS], wm[KS], wl[KS];
  size_t wo = (size_t)(n0 + l16) * K + quad * 8;
#pragma unroll
  for (int s = 0; s < KS; ++s) {
    wh[s] = *(const bf16x8*)(Bh + wo + s * 32);
    wm[s] = *(const bf16x8*)(Bm + wo + s * 32);
    wl[s] = *(const bf16x8*)(Bl + wo + s * 32);
  }
  size_t ao = ((size_t)b * Nn + ns * 128 + l16) * K + quad * 8;
  float rmax = -INFINITY;
#pragma unroll 1
  for (int mt = 0; mt < 8; ++mt) {
    size_t ar = ao + (size_t)mt * 16 * K;
    f32x4 acc = {0.f, 0.f, 0.f, 0.f};
#pragma unroll
    for (int s = 0; s < KS; ++s) {
      bf16x8 xh = *(const bf16x8*)(Ah + ar + s * 32);
      bf16x8 xm = *(const bf16x8*)(Am + ar + s * 32);
      bf16x8 xl = *(const bf16x8*)(Al + ar + s * 32);
      acc = __builtin_amdgcn_mfma_f32_16x16x32_bf16(xh, wh[s], acc, 0, 0, 0);
      acc = __builtin_amdgcn_mfma_f32_16x16x32_bf16(xh, wm[s], acc, 0, 0, 0);
      acc = __builtin_amdgcn_mfma_f32_16x16x32_bf16(xm, wh[s], acc, 0, 0, 0);
      acc = __builtin_amdgcn_mfma_f32_16x16x32_bf16(xh, wl[s], acc, 0, 0, 0);
      acc = __builtin_amdgcn_mfma_f32_16x16x32_bf16(xl, wh[s], acc, 0, 0, 0);
      acc = __builtin_amdgcn_mfma_f32_16x16x32_bf16(xm, wm[s], acc, 0, 0, 0);
    }
    rmax = fmaxf(rmax, fmaxf(fmaxf(acc[0], acc[1]), fmaxf(acc[2], acc[3])));
  }
  rmax = fmaxf(rmax, __shfl_xor(rmax, 16, 64));
  rmax = fmaxf(rmax, __shfl_xor(rmax, 32, 64));
  if (quad == 0) outp[((size_t)b * 32 + ns) * 1024 + n0 + l16] = rmax;
}

// ---------------- fused MFMA head: 192->512->256->2 per 16 points ---------
__global__ __launch_bounds__(256) void k_final(const unsigned short* __restrict__ xcat,
                                               const float* __restrict__ gc,
                                               const float* __restrict__ c2b,
                                               const unsigned short* __restrict__ c2wT,
                                               const unsigned short* __restrict__ c3wT,
                                               const float* __restrict__ c3b,
                                               const float* __restrict__ c4w, const float* __restrict__ c4b,
                                               float* __restrict__ out) {
  __shared__ unsigned short z5[16 * 520];
  __shared__ float z2[16 * 260];
  int t = threadIdx.x;
  int wv = t >> 6, lane = t & 63;
  int quad = lane >> 4, l16 = lane & 15;
  int p0 = blockIdx.x * 16;
  int b = p0 >> 12;
  bf16x8 a1[6];
  const unsigned short* ar = xcat + (size_t)(p0 + l16) * 192 + quad * 8;
#pragma unroll
  for (int s = 0; s < 6; ++s) a1[s] = *(const bf16x8*)(ar + s * 32);
#pragma unroll 1
  for (int ntw = 0; ntw < 8; ++ntw) {
    int col = wv * 128 + ntw * 16 + l16;
    float bias = gc[(size_t)b * 512 + col] + c2b[col];
    f32x4 acc = {bias, bias, bias, bias};
    const unsigned short* wr = c2wT + (size_t)col * 192 + quad * 8;
#pragma unroll
    for (int s = 0; s < 6; ++s) {
      bf16x8 bfr = *(const bf16x8*)(wr + s * 32);
      acc = __builtin_amdgcn_mfma_f32_16x16x32_bf16(a1[s], bfr, acc, 0, 0, 0);
    }
#pragma unroll
    for (int r = 0; r < 4; ++r)
      z5[(quad * 4 + r) * 520 + col] = f2bf(fmaxf(acc[r], 0.f));
  }
  __syncthreads();
  bf16x8 a2[16];
#pragma unroll
  for (int s = 0; s < 16; ++s) a2[s] = *(const bf16x8*)(z5 + l16 * 520 + s * 32 + quad * 8);
#pragma unroll 1
  for (int ntw = 0; ntw < 4; ++ntw) {
    int col = wv * 64 + ntw * 16 + l16;
    float bias = c3b[col];
    f32x4 acc = {bias, bias, bias, bias};
    const unsigned short* wr = c3wT + (size_t)col * 512 + quad * 8;
#pragma unroll
    for (int s = 0; s < 16; ++s) {
      bf16x8 bfr = *(const bf16x8*)(wr + s * 32);
      acc = __builtin_amdgcn_mfma_f32_16x16x32_bf16(a2[s], bfr, acc, 0, 0, 0);
    }
#pragma unroll
    for (int r = 0; r < 4; ++r)
      z2[(quad * 4 + r) * 260 + col] = fmaxf(acc[r], 0.f);
  }
  __syncthreads();
  if (t < 32) {
    int m = t >> 1, e = t & 1;
    float acc = c4b[e];
    const float* zr = z2 + m * 260;
    for (int j = 0; j < 256; ++j) acc = fmaf(zr[j], c4w[j * 2 + e], acc);
    out[(size_t)(p0 + m) * 2 + e] = acc;
  }
}

// ===========================================================================
extern "C" void kernel_launch(void* const* d_in, const int* in_sizes, int n_in,
                              void* d_out, int out_size, void* d_ws, size_t ws_size,
                              hipStream_t stream) {
  const float* xin = (const float*)d_in[0];
  const float* W[30];
  for (int i = 0; i < 30; ++i) W[i] = (const float*)d_in[i + 1];

  float* ws = (float*)d_ws;
  size_t off = 0;
  float* pts   = ws + off; off += (size_t)BN * 3;
  float* p     = ws + off; off += (size_t)BN * 3;
  int*   idx   = (int*)(ws + off); off += (size_t)BN * KK;
  float* sq    = ws + off; off += BN;
  float* dpart = ws + off; off += 4 * 32 * 1024;
  float* h1    = ws + off; off += 4 * 512;
  float* h2b   = ws + off; off += 4 * 256;
  float* x1    = ws + off; off += (size_t)BN * 64;
  float* x2    = ws + off; off += (size_t)BN * 64;
  float* gpart = ws + off; off += 4 * 32 * 1024;
  float* gc    = ws + off; off += 4 * 512;
  float* uvb   = ws + off; off += (size_t)BN * 128;
  float* partial = ws + off; off += 16 * 4 * 512;
  unsigned short* xcat = (unsigned short*)(ws + off); off += (size_t)BN * 96;
  unsigned short* c1wT = (unsigned short*)(ws + off); off += 98304;
  unsigned short* c2wT = (unsigned short*)(ws + off); off += 49152;
  unsigned short* c3wT = (unsigned short*)(ws + off); off += 65536;
  unsigned short* w3Th = (unsigned short*)(ws + off); off += 65536;
  unsigned short* w3Tm = (unsigned short*)(ws + off); off += 65536;
  unsigned short* w3Tl = (unsigned short*)(ws + off); off += 65536;
  unsigned short* tw2h = (unsigned short*)(ws + off); off += 4096;
  unsigned short* tw2m = (unsigned short*)(ws + off); off += 4096;
  unsigned short* tw2l = (unsigned short*)(ws + off); off += 4096;
  unsigned short* e1h  = (unsigned short*)(ws + off); off += 2048;
  unsigned short* e1m  = (unsigned short*)(ws + off); off += 2048;
  unsigned short* e1l  = (unsigned short*)(ws + off); off += 2048;
  unsigned short* e2h  = (unsigned short*)(ws + off); off += 2048;
  unsigned short* e2m  = (unsigned short*)(ws + off); off += 2048;
  unsigned short* e2l  = (unsigned short*)(ws + off); off += 2048;
  unsigned short* xsh  = (unsigned short*)(ws + off); off += 524288;
  unsigned short* xsm  = (unsigned short*)(ws + off); off += 524288;
  unsigned short* xsl  = (unsigned short*)(ws + off); off += 524288;
  float* MdC   = ws + off; off += 8192;
  float* MdD   = ws + off; off += 8192;
  unsigned short* fw1h = (unsigned short*)(ws + off); off += 262144;  // 512x1024 bf16
  unsigned short* fw1m = (unsigned short*)(ws + off); off += 262144;
  unsigned short* fw1l = (unsigned short*)(ws + off); off += 262144;
  unsigned short* cw2h = (unsigned short*)(ws + off); off += 262144;  // 512x1024 (c2w[:1024])
  unsigned short* cw2m = (unsigned short*)(ws + off); off += 262144;
  unsigned short* cw2l = (unsigned short*)(ws + off); off += 262144;
  unsigned short* fw2h = (unsigned short*)(ws + off); off += 65536;   // 256x512 bf16
  unsigned short* fw2m = (unsigned short*)(ws + off); off += 65536;
  unsigned short* fw2l = (unsigned short*)(ws + off); off += 65536;
  unsigned short* tvh  = (unsigned short*)(ws + off); off += 8192;    // 16x1024 bf16
  unsigned short* tvm  = (unsigned short*)(ws + off); off += 8192;
  unsigned short* tvl  = (unsigned short*)(ws + off); off += 8192;
  unsigned short* h13h = (unsigned short*)(ws + off); off += 4096;    // 16x512 bf16
  unsigned short* h13m = (unsigned short*)(ws + off); off += 4096;
  unsigned short* h13l = (unsigned short*)(ws + off); off += 4096;
  float* Dbuf  = ws + off; off += (size_t)Nn * Nn;   // kept: t3h/m/l alias
  unsigned short* t3h = (unsigned short*)Dbuf;       // stage-1 only
  unsigned short* t3m = t3h + (size_t)BN * 128;
  unsigned short* t3l = t3m + (size_t)BN * 128;

  // fused weight prep + pts (13 launches -> 1)
  k_prepAll<<<dim3(7104), dim3(256), 0, stream>>>(
      xin, pts,
      W[22], c1wT, W[24], c2wT, W[26], c3wT,
      W[4], w3Th, w3Tm, w3Tl,
      W[2], tw2h, tw2m, tw2l,
      W[14], e1h, e1m, e1l,
      W[18], e2h, e2m, e2l,
      W[6], fw1h, fw1m, fw1l,
      cw2h, cw2m, cw2l,
      W[8], fw2h, fw2m, fw2l,
      W[16], MdC, W[20], MdD);

  // stage 1: transform branch
  k_knn3<<<dim3(1024), dim3(1024), 0, stream>>>(pts, idx);
  k_uv3<<<dim3(4096), dim3(256), 0, stream>>>(pts, W[0], W[1], uvb);
  k_econv<128, false, true, false><<<dim3(4096), dim3(256), 0, stream>>>(
      uvb, idx, tw2h, tw2m, tw2l, W[3], nullptr, t3h, t3m, t3l, nullptr, 0);
  k_mgemm3s<128><<<dim3(2048), dim3(256), 0, stream>>>(t3h, t3m, t3l, w3Th, w3Tm, w3Tl, dpart);
  // fc1 via small MFMA: tv = relu(max+tb3) -> h1 = relu(tv@tfw1+tfb1)
  k_tv3<<<dim3(64), dim3(256), 0, stream>>>(dpart, W[5], tvh, tvm, tvl);
  k_gemmSK<512, 1024, 16><<<dim3(128), dim3(256), 0, stream>>>(tvh, tvm, tvl, fw1h, fw1m, fw1l, partial);
  k_redS<<<dim3(8), dim3(256), 0, stream>>>(partial, W[7], h1, 512, 16, 1);
  // fc2 via small MFMA, then fc3+apply
  k_pad3<<<dim3(32), dim3(256), 0, stream>>>(h1, 4, 512, h13h, h13m, h13l);
  k_gemmSK<256, 512, 8><<<dim3(32), dim3(256), 0, stream>>>(h13h, h13m, h13l, fw2h, fw2m, fw2l, partial);
  k_redS<<<dim3(4), dim3(256), 0, stream>>>(partial, W[9], h2b, 256, 8, 1);
  k_fc3p<<<dim3(4), dim3(256), 0, stream>>>(h2b, W[10], W[11], pts, p);

  // stage 2
  k_knn3<<<dim3(1024), dim3(1024), 0, stream>>>(p, idx);
  k_uv3<<<dim3(4096), dim3(256), 0, stream>>>(p, W[12], W[13], uvb);
  k_econv<64, true, true, true><<<dim3(4096), dim3(256), 0, stream>>>(
      uvb, idx, e1h, e1m, e1l, W[15], x1, xsh, xsm, xsl, xcat, 0);
  k_sqnorm<<<dim3(64), dim3(256), 0, stream>>>(x1, sq);
  k_dsel<<<dim3(1024), dim3(1024), 0, stream>>>(xsh, xsm, xsl, sq, idx);
  k_uv<<<dim3(512), dim3(256), 0, stream>>>(x1, MdC, W[17], uvb);
  k_econv<64, true, true, true><<<dim3(4096), dim3(256), 0, stream>>>(
      uvb, idx, e2h, e2m, e2l, W[19], x2, xsh, xsm, xsl, xcat, 64);
  k_sqnorm<<<dim3(64), dim3(256), 0, stream>>>(x2, sq);
  k_dsel<<<dim3(1024), dim3(1024), 0, stream>>>(xsh, xsm, xsl, sq, idx);
  // edgeD via u/v factorization (bias folded into u); writes xcat[128:192]
  k_uv<<<dim3(512), dim3(256), 0, stream>>>(x2, MdD, W[21], uvb);
  k_gmax<<<dim3(4096), dim3(256), 0, stream>>>(uvb, idx, xcat);

  // stage 3
  k_mgemm<192><<<dim3(2048), dim3(256), 0, stream>>>(xcat, c1wT, gpart);
  // j2 via small MFMA: g = relu(max+c1b) -> gc = g @ c2w[:1024]
  k_tv3<<<dim3(64), dim3(256), 0, stream>>>(gpart, W[23], tvh, tvm, tvl);
  k_gemmSK<512, 1024, 16><<<dim3(128), dim3(256), 0, stream>>>(tvh, tvm, tvl, cw2h, cw2m, cw2l, partial);
  k_redS<<<dim3(8), dim3(256), 0, stream>>>(partial, nullptr, gc, 512, 16, 0);
  k_final<<<dim3(1024), dim3(256), 0, stream>>>(xcat, gc, W[25], c2wT, c3wT,
                                                W[27], W[28], W[29], (float*)d_out);
}